// Round 13
// baseline (289.481 us; speedup 1.0000x reference)
//
#include <hip/hip_runtime.h>
#include <cmath>

constexpr int B = 2, L = 4096, D = 256, H = 8, NC = 3;
constexpr int TOP_N = 8, R = 32;
constexpr int LS = 1000, LE = 3000;
constexpr int NL = 2;
constexpr int FF = 4 * D;                        // 1024
constexpr int Q_MAX = 2 * TOP_N * (2 * R + 1);   // 1040
constexpr int HD = D / H;                        // 32
constexpr int QROWS = B * Q_MAX;                 // 2080
constexpr int KVROWS = B * L;                    // 8192
constexpr int NQT = (Q_MAX + 31) / 32;           // 33 q-tiles of 32
constexpr int NREG = LE - LS;                    // 2000
constexpr int NSPLIT = 8;                        // split-K waves per block
constexpr int KCHUNK = L / NSPLIT;               // 512 keys per wave
constexpr int NT = KCHUNK / 32;                  // 16 iterations
constexpr int KVBLK = 8 * (KVROWS / 64);         // 1024 blocks (KV part)
constexpr int QRB = (QROWS + 63) / 64;           // 33 row-blocks (Q part)
constexpr int TRBLK = NL * 192;                  // 384 transpose blocks

typedef __attribute__((ext_vector_type(8))) short bf16x8;
typedef __attribute__((ext_vector_type(4))) float f32x4;
typedef __attribute__((ext_vector_type(4))) int i32x4;
typedef unsigned short u16;

union fr {
  bf16x8 h;
  i32x4 i;
};

__device__ __forceinline__ u16 f2bs(float f) {
  unsigned int u = __float_as_uint(f);
  unsigned int r = u + 0x7fffu + ((u >> 16) & 1u);
  return (u16)(r >> 16);
}
__device__ __forceinline__ float bs2f(u16 s) {
  return __uint_as_float(((unsigned int)s) << 16);
}
__device__ __forceinline__ float gelu_exact(float x) {
  return 0.5f * x * (1.f + erff(x * 0.70710678118654752440f));
}
__device__ __forceinline__ unsigned cvt_pk(float lo, float hi) {
  unsigned r;
  asm("v_cvt_pk_bf16_f32 %0, %1, %2" : "=v"(r) : "v"(lo), "v"(hi));
  return r;
}

#define GLL16(gsrc, ldst)                                                   \
  __builtin_amdgcn_global_load_lds(                                         \
      (const __attribute__((address_space(1))) unsigned int*)(gsrc),        \
      (__attribute__((address_space(3))) unsigned int*)(ldst), 16, 0, 0)

// ---------------------------------------------------------------------------
// Merged setup dispatch (256 threads/block):
//   blocks [0, KVROWS)            : dual-layer LayerNorm of enc -> kvl0/kvl1
//   blocks [KVROWS, KVROWS+TRBLK) : LDS-tiled weight transpose+bf16 -> WT
//   blocks [KVROWS+TRBLK, +B)     : vicinity selection (one block per batch)
// All three parts are mutually independent.
// ---------------------------------------------------------------------------
__global__ __launch_bounds__(256) void setup_kernel(
    const float* __restrict__ enc, const float* __restrict__ logits,
    const float* __restrict__ lnkvg, const float* __restrict__ lnkvb,
    const float* __restrict__ Wq_, const float* __restrict__ Wk_,
    const float* __restrict__ Wv_, const float* __restrict__ Wo_,
    const float* __restrict__ W1_, const float* __restrict__ W2_,
    u16* __restrict__ WT, u16* __restrict__ o0, u16* __restrict__ o1,
    int* __restrict__ idx_out, int* __restrict__ mask_out) {
  int bid = blockIdx.x;
  int tid = threadIdx.x;
  const long DD = (long)D * D, DFF = (long)D * FF;
  const long LSTR = 4 * DD + 2 * DFF;

  if (bid < KVROWS) {
    // ---- ln_kv2 part
    long row = bid;
    float x = enc[row * D + tid];
    float s1 = x, s2 = x * x;
#pragma unroll
    for (int off = 32; off; off >>= 1) {
      s1 += __shfl_xor(s1, off, 64);
      s2 += __shfl_xor(s2, off, 64);
    }
    __shared__ float p1[4], p2[4];
    int w = tid >> 6;
    if ((tid & 63) == 0) { p1[w] = s1; p2[w] = s2; }
    __syncthreads();
    s1 = p1[0] + p1[1] + p1[2] + p1[3];
    s2 = p2[0] + p2[1] + p2[2] + p2[3];
    float mean = s1 * (1.f / D);
    float var = fmaxf(s2 * (1.f / D) - mean * mean, 0.f);
    float r = rsqrtf(var + 1e-5f);
    float xn = (x - mean) * r;
    o0[row * D + tid] = f2bs(xn * lnkvg[tid] + lnkvb[tid]);
    o1[row * D + tid] = f2bs(xn * lnkvg[D + tid] + lnkvb[D + tid]);
    return;
  }

  if (bid < KVROWS + TRBLK) {
    // ---- transpose part
    __shared__ u16 T[64][65];
    int t = bid - KVROWS;
    int l = t / 192, r = t % 192;
    const float* src;
    long dbase;
    int K_, N_, kt, nt;
    if (r < 64) {
      int which = r >> 4, sub = r & 15;
      kt = sub >> 2;
      nt = sub & 3;
      K_ = 256;
      N_ = 256;
      src = (which == 0 ? Wk_ : which == 1 ? Wv_ : which == 2 ? Wq_ : Wo_) +
            (long)l * DD;
      dbase = (long)l * LSTR + (long)which * DD;
    } else if (r < 128) {
      int sub = r - 64;
      kt = sub >> 4;
      nt = sub & 15;
      K_ = 256;
      N_ = 1024;
      src = W1_ + (long)l * DFF;
      dbase = (long)l * LSTR + 4 * DD;
    } else {
      int sub = r - 128;
      kt = sub >> 2;
      nt = sub & 3;
      K_ = 1024;
      N_ = 256;
      src = W2_ + (long)l * DFF;
      dbase = (long)l * LSTR + 4 * DD + DFF;
    }
    int k0 = kt * 64, n0 = nt * 64;
    {
      int kr = tid >> 2, c16 = (tid & 3) * 16;
      const float* sp = src + (long)(k0 + kr) * N_ + n0 + c16;
#pragma unroll
      for (int i = 0; i < 4; ++i) {
        float4 v = *reinterpret_cast<const float4*>(sp + 4 * i);
        T[kr][c16 + 4 * i + 0] = f2bs(v.x);
        T[kr][c16 + 4 * i + 1] = f2bs(v.y);
        T[kr][c16 + 4 * i + 2] = f2bs(v.z);
        T[kr][c16 + 4 * i + 3] = f2bs(v.w);
      }
    }
    __syncthreads();
    {
      int nr = tid >> 2, kc = (tid & 3) * 16;
      u16 tmp[16];
#pragma unroll
      for (int j = 0; j < 16; ++j) tmp[j] = T[kc + j][nr];
      u16* dp = WT + dbase + (long)(n0 + nr) * K_ + k0 + kc;
      *reinterpret_cast<bf16x8*>(dp) = *reinterpret_cast<const bf16x8*>(&tmp[0]);
      *reinterpret_cast<bf16x8*>(dp + 8) =
          *reinterpret_cast<const bf16x8*>(&tmp[8]);
    }
    return;
  }

  // ---- select part (one block per batch), 256 threads = 4 waves
  {
    int b = bid - KVROWS - TRBLK;
    int w = tid >> 6, lane = tid & 63;
    __shared__ float candv[4][8];
    __shared__ int candi[4][8];
    __shared__ int centers[2 * TOP_N];
    __shared__ unsigned present[L / 32];
    __shared__ int offs[128];
    __shared__ int wtot[2];

    float vd[8], va[8];
#pragma unroll
    for (int j = 0; j < 8; ++j) {
      int p = tid + j * 256;
      if (p < NREG) {
        const float* lg = logits + ((long)b * L + LS + p) * NC;
        float x0 = lg[0], x1 = lg[1], x2 = lg[2];
        float m = fmaxf(x0, fmaxf(x1, x2));
        float lse = m + logf(expf(x0 - m) + expf(x1 - m) + expf(x2 - m));
        vd[j] = x2 - lse;
        va[j] = x1 - lse;
      } else {
        vd[j] = -INFINITY;
        va[j] = -INFINITY;
      }
    }
    if (tid < 128) present[tid] = 0;

    for (int sel = 0; sel < 2; ++sel) {
      float v[8];
#pragma unroll
      for (int j = 0; j < 8; ++j) v[j] = (sel == 0) ? vd[j] : va[j];
      // stage 1: each wave extracts local top-8 (register-only)
#pragma unroll
      for (int r = 0; r < TOP_N; ++r) {
        float mv = v[0];
        int mp = tid;
#pragma unroll
        for (int j = 1; j < 8; ++j) {
          int pj = tid + j * 256;
          if (v[j] > mv) { mv = v[j]; mp = pj; }
        }
#pragma unroll
        for (int off = 32; off; off >>= 1) {
          float ov = __shfl_xor(mv, off, 64);
          int oi = __shfl_xor(mp, off, 64);
          if (ov > mv || (ov == mv && oi < mp)) { mv = ov; mp = oi; }
        }
#pragma unroll
        for (int j = 0; j < 8; ++j)
          if (tid + j * 256 == mp) v[j] = -INFINITY;
        if (lane == 0) { candv[w][r] = mv; candi[w][r] = mp; }
      }
      __syncthreads();
      // stage 2: wave 0 reduces 32 candidates
      if (tid < 64) {
        float c = (tid < 32) ? candv[tid >> 3][tid & 7] : -INFINITY;
        int ci = (tid < 32) ? candi[tid >> 3][tid & 7] : 0x7fffffff;
#pragma unroll
        for (int r = 0; r < TOP_N; ++r) {
          float mv = c;
          int mi = ci;
#pragma unroll
          for (int off = 32; off; off >>= 1) {
            float ov = __shfl_xor(mv, off, 64);
            int oi = __shfl_xor(mi, off, 64);
            if (ov > mv || (ov == mv && oi < mi)) { mv = ov; mi = oi; }
          }
          if (ci == mi) c = -INFINITY;
          if (tid == 0) centers[sel * TOP_N + r] = LS + mi;
        }
      }
      __syncthreads();
    }

    for (int j = tid; j < Q_MAX; j += 256) {
      int c = centers[j / (2 * R + 1)];
      int off = j % (2 * R + 1) - R;
      int v2 = c + off;
      v2 = v2 < 0 ? 0 : (v2 > L - 1 ? L - 1 : v2);
      atomicOr(&present[v2 >> 5], 1u << (v2 & 31));
    }
    __syncthreads();

    int cnt = (tid < 128) ? __popc(present[tid]) : 0;
    if (tid < 128) {
      int x = cnt;
#pragma unroll
      for (int off = 1; off < 64; off <<= 1) {
        int o = __shfl_up(x, off, 64);
        if ((tid & 63) >= off) x += o;
      }
      if ((tid & 63) == 63) wtot[tid >> 6] = x;
      offs[tid] = x - cnt;
    }
    __syncthreads();
    int total = wtot[0] + wtot[1];
    if (tid < 128) {
      int base = offs[tid] + ((tid >= 64) ? wtot[0] : 0);
      unsigned mword = present[tid];
      while (mword) {
        int i = __ffs(mword) - 1;
        mword &= mword - 1;
        idx_out[b * Q_MAX + base] = tid * 32 + i;
        mask_out[b * Q_MAX + base] = 1;
        ++base;
      }
    }
    for (int j = total + tid; j < Q_MAX; j += 256) {
      idx_out[b * Q_MAX + j] = L;
      mask_out[b * Q_MAX + j] = 0;
    }
  }
}

// ---------------------------------------------------------------------------
__global__ __launch_bounds__(256) void gather_kernel(
    const float* __restrict__ enc, const int* __restrict__ idx,
    float* __restrict__ q_stream) {
  int row = blockIdx.x;
  int b = row / Q_MAX;
  int p = idx[row];
  float v = 0.f;
  if (p < L) v = enc[((long)b * L + p) * D + threadIdx.x];
  q_stream[(long)row * D + threadIdx.x] = v;
}

// ---------------------------------------------------------------------------
// LN-staging helper: LayerNorm 64 fp32 rows of A into bf16 LDS tile [64][264].
// 4 threads per row (tid>>2 = row, tid&3 = quarter). Rows clamped to M-1.
// ---------------------------------------------------------------------------
__device__ __forceinline__ void ln_stage(
    const float* __restrict__ A, int bm, int M, const float* __restrict__ lng,
    const float* __restrict__ lnb, u16 (*As)[264], int tid) {
  int r = tid >> 2, qd = tid & 3;
  int grow = bm + r;
  if (grow >= M) grow = M - 1;
  const float* ap = A + ((long)grow) * D + qd * 64;
  float sum = 0.f, ss = 0.f;
#pragma unroll
  for (int i = 0; i < 16; ++i) {
    float4 v = *reinterpret_cast<const float4*>(ap + i * 4);
    sum += v.x + v.y + v.z + v.w;
    ss += v.x * v.x + v.y * v.y + v.z * v.z + v.w * v.w;
  }
  sum += __shfl_xor(sum, 1, 64);
  sum += __shfl_xor(sum, 2, 64);
  ss += __shfl_xor(ss, 1, 64);
  ss += __shfl_xor(ss, 2, 64);
  float mean = sum * (1.f / D);
  float var = fmaxf(ss * (1.f / D) - mean * mean, 0.f);
  float rstd = rsqrtf(var + 1e-5f);
#pragma unroll
  for (int i = 0; i < 8; ++i) {
    int k = qd * 64 + i * 8;
    float4 xa = *reinterpret_cast<const float4*>(ap + i * 8);
    float4 xb = *reinterpret_cast<const float4*>(ap + i * 8 + 4);
    float4 ga = *reinterpret_cast<const float4*>(lng + k);
    float4 gb = *reinterpret_cast<const float4*>(lng + k + 4);
    float4 ba = *reinterpret_cast<const float4*>(lnb + k);
    float4 bb = *reinterpret_cast<const float4*>(lnb + k + 4);
    fr v;
    v.i[0] = (int)cvt_pk((xa.x - mean) * rstd * ga.x + ba.x,
                         (xa.y - mean) * rstd * ga.y + ba.y);
    v.i[1] = (int)cvt_pk((xa.z - mean) * rstd * ga.z + ba.z,
                         (xa.w - mean) * rstd * ga.w + ba.w);
    v.i[2] = (int)cvt_pk((xb.x - mean) * rstd * gb.x + bb.x,
                         (xb.y - mean) * rstd * gb.y + bb.y);
    v.i[3] = (int)cvt_pk((xb.z - mean) * rstd * gb.z + bb.z,
                         (xb.w - mean) * rstd * gb.w + bb.w);
    *reinterpret_cast<bf16x8*>(&As[r][k]) = v.h;
  }
}

// ---------------------------------------------------------------------------
// bf16 MFMA GEMM (64x64 tile, BK=32, 4 waves).
// EPI 1: gelu->bf16; 2: resid+mask->f32
// ---------------------------------------------------------------------------
template <int EPI>
__global__ __launch_bounds__(256) void gemm_mfma(
    const u16* __restrict__ A, const u16* __restrict__ BT,
    const float* __restrict__ bias, void* __restrict__ Cv,
    const float* __restrict__ resid, const int* __restrict__ mask, int M,
    int N, int K) {
  __shared__ short As[64][40];
  __shared__ short Bs[64][40];
  int bm = blockIdx.y * 64, bn = blockIdx.x * 64;
  int tid = threadIdx.x;
  int lane = tid & 63, w = tid >> 6;
  int g = lane >> 4, li = lane & 15;
  int wr = w >> 1, wc = w & 1;
  f32x4 acc[2][2] = {};

  int srow = tid >> 2, skc = (tid & 3) * 8;
  for (int k0 = 0; k0 < K; k0 += 32) {
    {
      int grow = bm + srow;
      bf16x8 av = {};
      if (grow < M)
        av = *reinterpret_cast<const bf16x8*>(A + (long)grow * K + k0 + skc);
      *reinterpret_cast<bf16x8*>(&As[srow][skc]) = av;
      bf16x8 bv = *reinterpret_cast<const bf16x8*>(
          BT + (long)(bn + srow) * K + k0 + skc);
      *reinterpret_cast<bf16x8*>(&Bs[srow][skc]) = bv;
    }
    __syncthreads();
    bf16x8 a0 = *reinterpret_cast<const bf16x8*>(&As[wr * 32 + li][g * 8]);
    bf16x8 a1 = *reinterpret_cast<const bf16x8*>(&As[wr * 32 + 16 + li][g * 8]);
    bf16x8 b0 = *reinterpret_cast<const bf16x8*>(&Bs[wc * 32 + li][g * 8]);
    bf16x8 b1 = *reinterpret_cast<const bf16x8*>(&Bs[wc * 32 + 16 + li][g * 8]);
    acc[0][0] = __builtin_amdgcn_mfma_f32_16x16x32_bf16(a0, b0, acc[0][0], 0, 0, 0);
    acc[0][1] = __builtin_amdgcn_mfma_f32_16x16x32_bf16(a0, b1, acc[0][1], 0, 0, 0);
    acc[1][0] = __builtin_amdgcn_mfma_f32_16x16x32_bf16(a1, b0, acc[1][0], 0, 0, 0);
    acc[1][1] = __builtin_amdgcn_mfma_f32_16x16x32_bf16(a1, b1, acc[1][1], 0, 0, 0);
    __syncthreads();
  }

#pragma unroll
  for (int mr = 0; mr < 2; ++mr)
#pragma unroll
    for (int nr = 0; nr < 2; ++nr)
#pragma unroll
      for (int r = 0; r < 4; ++r) {
        int row = bm + wr * 32 + mr * 16 + g * 4 + r;
        int col = bn + wc * 32 + nr * 16 + li;
        if (row >= M) continue;
        float v = acc[mr][nr][r] + bias[col];
        if (EPI == 1) v = gelu_exact(v);
        if (EPI == 2) {
          v += resid[(long)row * N + col];
          v = mask[row] ? v : 0.f;
          ((float*)Cv)[(long)row * N + col] = v;
        } else {
          ((u16*)Cv)[(long)row * N + col] = f2bs(v);
        }
      }
}

// ---------------------------------------------------------------------------
// Combined projection dispatch:
//   bid < KVBLK : KV GEMM tile (A=kv_ln bf16), epilogues -> swizzled Kh / Vh
//   else        : Q row-block with FUSED LayerNorm of fp32 q_stream; loops
//                 the 4 n-tiles in-block (LN computed once) -> Qbuf.
// ---------------------------------------------------------------------------
__global__ __launch_bounds__(256) void gemm_proj(
    const u16* __restrict__ Akv, const float* __restrict__ Aqf,
    const u16* __restrict__ WTbase, const float* __restrict__ lnqg,
    const float* __restrict__ lnqb, const float* __restrict__ biasK,
    const float* __restrict__ biasV, const float* __restrict__ biasQ,
    u16* __restrict__ Kh, u16* __restrict__ Vh, u16* __restrict__ Qb) {
  __shared__ alignas(16) char pool[64 * 264 * 2 + 64 * 40 * 2];  // 38.9 KB
  int bid = blockIdx.x;
  int tid = threadIdx.x;
  int lane = tid & 63, w = tid >> 6;
  int g = lane >> 4, li = lane & 15;
  int wr = w >> 1, wc = w & 1;
  const long DD = (long)D * D;

  if (bid >= KVBLK) {
    // ---------------- Q path: fused-LN row block ----------------
    u16(*As)[264] = (u16(*)[264])pool;
    u16(*Bs)[40] = (u16(*)[40])(pool + 64 * 264 * 2);
    int bm = (bid - KVBLK) * 64;
    ln_stage(Aqf, bm, QROWS, lnqg, lnqb, As, tid);
    __syncthreads();
    const u16* BT = WTbase + 2 * DD;  // WqT
    int srow = tid >> 2, skc = (tid & 3) * 8;
    for (int nt = 0; nt < 4; ++nt) {
      int bn = nt * 64;
      f32x4 acc[2][2] = {};
      for (int k0 = 0; k0 < D; k0 += 32) {
        *reinterpret_cast<bf16x8*>(&Bs[srow][skc]) =
            *reinterpret_cast<const bf16x8*>(BT + (long)(bn + srow) * D + k0 + skc);
        __syncthreads();
        bf16x8 a0 = *reinterpret_cast<const bf16x8*>(&As[wr * 32 + li][k0 + g * 8]);
        bf16x8 a1 =
            *reinterpret_cast<const bf16x8*>(&As[wr * 32 + 16 + li][k0 + g * 8]);
        bf16x8 b0 = *reinterpret_cast<const bf16x8*>(&Bs[wc * 32 + li][g * 8]);
        bf16x8 b1 = *reinterpret_cast<const bf16x8*>(&Bs[wc * 32 + 16 + li][g * 8]);
        acc[0][0] = __builtin_amdgcn_mfma_f32_16x16x32_bf16(a0, b0, acc[0][0], 0, 0, 0);
        acc[0][1] = __builtin_amdgcn_mfma_f32_16x16x32_bf16(a0, b1, acc[0][1], 0, 0, 0);
        acc[1][0] = __builtin_amdgcn_mfma_f32_16x16x32_bf16(a1, b0, acc[1][0], 0, 0, 0);
        acc[1][1] = __builtin_amdgcn_mfma_f32_16x16x32_bf16(a1, b1, acc[1][1], 0, 0, 0);
        __syncthreads();
      }
#pragma unroll
      for (int mr = 0; mr < 2; ++mr)
#pragma unroll
        for (int nr = 0; nr < 2; ++nr)
#pragma unroll
          for (int r = 0; r < 4; ++r) {
            int row = bm + wr * 32 + mr * 16 + g * 4 + r;
            int col = bn + wc * 32 + nr * 16 + li;
            if (row >= QROWS) continue;
            Qb[(long)row * D + col] = f2bs(acc[mr][nr][r] + biasQ[col]);
          }
    }
    return;
  }

  // ---------------- KV path (R12-proven) ----------------
  short(*As)[40] = (short(*)[40])pool;
  short(*Bs)[40] = (short(*)[40])(pool + 64 * 40 * 2);
  u16(*Ct)[72] = (u16(*)[72])(pool + 2 * 64 * 40 * 2);
  int bn = (bid & 7) * 64;
  int bm = (bid >> 3) * 64;
  f32x4 acc[2][2] = {};

  int srow = tid >> 2, skc = (tid & 3) * 8;
  for (int k0 = 0; k0 < D; k0 += 32) {
    {
      bf16x8 av = *reinterpret_cast<const bf16x8*>(
          Akv + (long)(bm + srow) * D + k0 + skc);
      *reinterpret_cast<bf16x8*>(&As[srow][skc]) = av;
      bf16x8 bv = *reinterpret_cast<const bf16x8*>(
          WTbase + (long)(bn + srow) * D + k0 + skc);
      *reinterpret_cast<bf16x8*>(&Bs[srow][skc]) = bv;
    }
    __syncthreads();
    bf16x8 a0 = *reinterpret_cast<const bf16x8*>(&As[wr * 32 + li][g * 8]);
    bf16x8 a1 = *reinterpret_cast<const bf16x8*>(&As[wr * 32 + 16 + li][g * 8]);
    bf16x8 b0 = *reinterpret_cast<const bf16x8*>(&Bs[wc * 32 + li][g * 8]);
    bf16x8 b1 = *reinterpret_cast<const bf16x8*>(&Bs[wc * 32 + 16 + li][g * 8]);
    acc[0][0] = __builtin_amdgcn_mfma_f32_16x16x32_bf16(a0, b0, acc[0][0], 0, 0, 0);
    acc[0][1] = __builtin_amdgcn_mfma_f32_16x16x32_bf16(a0, b1, acc[0][1], 0, 0, 0);
    acc[1][0] = __builtin_amdgcn_mfma_f32_16x16x32_bf16(a1, b0, acc[1][0], 0, 0, 0);
    acc[1][1] = __builtin_amdgcn_mfma_f32_16x16x32_bf16(a1, b1, acc[1][1], 0, 0, 0);
    __syncthreads();
  }

  if (bn < 256) {
    // K epilogue: Kh[b][h][key][dchunk ^ ((key>>1)&3)]
#pragma unroll
    for (int mr = 0; mr < 2; ++mr)
#pragma unroll
      for (int nr = 0; nr < 2; ++nr)
#pragma unroll
        for (int r = 0; r < 4; ++r) {
          int rowL = wr * 32 + mr * 16 + g * 4 + r;
          int colL = wc * 32 + nr * 16 + li;
          Ct[rowL][colL] = f2bs(acc[mr][nr][r] + biasK[bn + colL]);
        }
    __syncthreads();
#pragma unroll
    for (int p = 0; p < 2; ++p) {
      int rowL = (tid >> 3) + p * 32;
      int c8 = (tid & 7) * 8;
      int grow = bm + rowL;
      int b2 = grow >> 12, key = grow & (L - 1);
      int gcol = bn + c8;
      int hh = gcol >> 5, dd = gcol & (HD - 1);
      int cst = (dd >> 3) ^ ((key >> 1) & 3);
      u16* dst = Kh + (((long)(b2 * H + hh) * L + key) * 32 + (cst << 3));
      *reinterpret_cast<bf16x8*>(dst) =
          *reinterpret_cast<const bf16x8*>(&Ct[rowL][c8]);
    }
  } else {
    // V epilogue: Vh[b][h][key/32][d][kchunk ^ ((d>>1)&6)]
    int vbn = bn - 256;
#pragma unroll
    for (int mr = 0; mr < 2; ++mr)
#pragma unroll
      for (int nr = 0; nr < 2; ++nr)
#pragma unroll
        for (int r = 0; r < 4; ++r) {
          int rowL = wr * 32 + mr * 16 + g * 4 + r;
          int colL = wc * 32 + nr * 16 + li;
          Ct[colL][rowL] = f2bs(acc[mr][nr][r] + biasV[vbn + colL]);
        }
    __syncthreads();
    int b2 = bm >> 12;
#pragma unroll
    for (int p = 0; p < 2; ++p) {
      int colL = (tid >> 3) + p * 32;
      int rem = tid & 7;
      int kb = rem >> 2, k8 = (rem & 3) * 8;
      int gcol = vbn + colL;
      int hh = gcol >> 5, dd = gcol & (HD - 1);
      int kb32 = ((bm & (L - 1)) >> 5) + kb;
      int j = (k8 >> 2) ^ ((dd >> 1) & 6);
      u16* dst = Vh + (((long)(b2 * H + hh) * (L / 32) + kb32) * 1024 +
                       dd * 32 + (j << 2));
      *reinterpret_cast<bf16x8*>(dst) =
          *reinterpret_cast<const bf16x8*>(&Ct[colL][kb * 32 + k8]);
    }
  }
}

// ---------------------------------------------------------------------------
// FFN1 with fused LayerNorm: grid (4, QRB). Each block LN-stages its 64-row
// fp32 tile once, then loops 4 n-tiles of W1 (256 cols), gelu -> bf16 H1.
// ---------------------------------------------------------------------------
__global__ __launch_bounds__(256) void gemm_ffn1(
    const float* __restrict__ A, const u16* __restrict__ BT,
    const float* __restrict__ lng, const float* __restrict__ lnb,
    const float* __restrict__ bias, u16* __restrict__ H1) {
  __shared__ alignas(16) char pool[64 * 264 * 2 + 64 * 40 * 2];
  u16(*As)[264] = (u16(*)[264])pool;
  u16(*Bs)[40] = (u16(*)[40])(pool + 64 * 264 * 2);
  int tid = threadIdx.x;
  int lane = tid & 63, w = tid >> 6;
  int g = lane >> 4, li = lane & 15;
  int wr = w >> 1, wc = w & 1;
  int bm = blockIdx.y * 64;

  ln_stage(A, bm, QROWS, lng, lnb, As, tid);
  __syncthreads();

  int srow = tid >> 2, skc = (tid & 3) * 8;
  for (int nt = 0; nt < 4; ++nt) {
    int bn = blockIdx.x * 256 + nt * 64;
    f32x4 acc[2][2] = {};
    for (int k0 = 0; k0 < D; k0 += 32) {
      *reinterpret_cast<bf16x8*>(&Bs[srow][skc]) =
          *reinterpret_cast<const bf16x8*>(BT + (long)(bn + srow) * D + k0 + skc);
      __syncthreads();
      bf16x8 a0 = *reinterpret_cast<const bf16x8*>(&As[wr * 32 + li][k0 + g * 8]);
      bf16x8 a1 =
          *reinterpret_cast<const bf16x8*>(&As[wr * 32 + 16 + li][k0 + g * 8]);
      bf16x8 b0 = *reinterpret_cast<const bf16x8*>(&Bs[wc * 32 + li][g * 8]);
      bf16x8 b1 = *reinterpret_cast<const bf16x8*>(&Bs[wc * 32 + 16 + li][g * 8]);
      acc[0][0] = __builtin_amdgcn_mfma_f32_16x16x32_bf16(a0, b0, acc[0][0], 0, 0, 0);
      acc[0][1] = __builtin_amdgcn_mfma_f32_16x16x32_bf16(a0, b1, acc[0][1], 0, 0, 0);
      acc[1][0] = __builtin_amdgcn_mfma_f32_16x16x32_bf16(a1, b0, acc[1][0], 0, 0, 0);
      acc[1][1] = __builtin_amdgcn_mfma_f32_16x16x32_bf16(a1, b1, acc[1][1], 0, 0, 0);
      __syncthreads();
    }
#pragma unroll
    for (int mr = 0; mr < 2; ++mr)
#pragma unroll
      for (int nr = 0; nr < 2; ++nr)
#pragma unroll
        for (int r = 0; r < 4; ++r) {
          int row = bm + wr * 32 + mr * 16 + g * 4 + r;
          int col = bn + wc * 32 + nr * 16 + li;
          if (row >= QROWS) continue;
          H1[(long)row * FF + col] = f2bs(gelu_exact(acc[mr][nr][r] + bias[col]));
        }
  }
}

// ---------------------------------------------------------------------------
// Fused flash attention (R12-proven): 512 threads = 8 split-K waves per
// (b,h,32-q tile). Single 4KB wave-private LDS buffer via global_load_lds;
// Kh/Vh XOR-swizzled in global. No-max exp2 softmax. XCD swizzle.
// ---------------------------------------------------------------------------
constexpr int POOLSZ = NSPLIT * 32 * 33 * 4 + NSPLIT * 32 * 4;  // 34816

__global__ __launch_bounds__(512) void attn_mfma(
    const u16* __restrict__ Qb, const u16* __restrict__ Kh,
    const u16* __restrict__ Vh, u16* __restrict__ AO) {
  __shared__ alignas(16) char pool[POOLSZ];
  int i = blockIdx.x;
  int xcd = i & 7, slot = i >> 3;          // 66 slots per XCD
  int bh = (xcd << 1) | (slot >= NQT ? 1 : 0);
  int qt = (slot >= NQT) ? slot - NQT : slot;
  int h = bh & 7;
  int b = bh >> 3;
  int tid = threadIdx.x, w = tid >> 6, lane = tid & 63;
  int g = lane >> 4, li = lane & 15;

  fr qf0, qf1;
  {
    const float QSC = 0.25509836048f;  // (1/sqrt(32)) * log2(e)
#pragma unroll
    for (int qb = 0; qb < 2; ++qb) {
      int qrow = qt * 32 + qb * 16 + li;
      if (qrow >= Q_MAX) qrow = Q_MAX - 1;
      bf16x8 raw = *reinterpret_cast<const bf16x8*>(
          Qb + ((long)(b * Q_MAX + qrow)) * D + h * HD + g * 8);
      fr& qf = qb ? qf1 : qf0;
#pragma unroll
      for (int j = 0; j < 4; ++j)
        qf.i[j] = (int)cvt_pk(bs2f((u16)raw[2 * j]) * QSC,
                              bs2f((u16)raw[2 * j + 1]) * QSC);
    }
  }

  f32x4 acc00 = {}, acc01 = {}, acc10 = {}, acc11 = {};
  float den0 = 0.f, den1 = 0.f;
  const f32x4 z = {};

  const u16* kbase = Kh + ((long)(b * H + h) * L) * HD;
  const u16* vbase = Vh + ((long)(b * H + h) * L) * HD;
  int kstart = w * KCHUNK;
  char* wbase = pool + w * 4096;  // wave-private single buffer (2KB K + 2KB V)

  int s_li = (li >> 1) & 3;
  int t_li = (li >> 1) & 6;
  int kof0 = li * 32 + ((g ^ s_li) << 3);
  int kof1 = (16 + li) * 32 + ((g ^ s_li) << 3);
  int va0o = li * 32 + ((g ^ t_li) << 2);
  int vb0o = li * 32 + (((4 + g) ^ t_li) << 2);
  int va1o = (16 + li) * 32 + ((g ^ t_li) << 2);
  int vb1o = (16 + li) * 32 + (((4 + g) ^ t_li) << 2);

  for (int t = 0; t < NT; ++t) {
    {
      const u16* ks = kbase + (long)(kstart + t * 32) * HD + lane * 8;
      const u16* vs = vbase + (long)(kstart + t * 32) * HD + lane * 8;
      u16* lk = (u16*)wbase;
      asm volatile("s_waitcnt lgkmcnt(0)" ::: "memory");
      GLL16(ks, lk);
      GLL16(ks + 512, lk + 512);
      GLL16(vs, lk + 1024);
      GLL16(vs + 512, lk + 1536);
      asm volatile("s_waitcnt vmcnt(0)" ::: "memory");
      __builtin_amdgcn_sched_barrier(0);
    }

    const u16* kl = (const u16*)wbase;
    const u16* vl = kl + 1024;
    bf16x8 kf0 = *reinterpret_cast<const bf16x8*>(kl + kof0);
    bf16x8 kf1 = *reinterpret_cast<const bf16x8*>(kl + kof1);
    uint2 va0 = *reinterpret_cast<const uint2*>(vl + va0o);
    uint2 vb0 = *reinterpret_cast<const uint2*>(vl + vb0o);
    uint2 va1 = *reinterpret_cast<const uint2*>(vl + va1o);
    uint2 vb1 = *reinterpret_cast<const uint2*>(vl + vb1o);

    f32x4 s00 = __builtin_amdgcn_mfma_f32_16x16x32_bf16(kf0, qf0.h, z, 0, 0, 0);
    f32x4 s10 = __builtin_amdgcn_mfma_f32_16x16x32_bf16(kf1, qf0.h, z, 0, 0, 0);
    f32x4 s01 = __builtin_amdgcn_mfma_f32_16x16x32_bf16(kf0, qf1.h, z, 0, 0, 0);
    f32x4 s11 = __builtin_amdgcn_mfma_f32_16x16x32_bf16(kf1, qf1.h, z, 0, 0, 0);

    float p00[4], p10[4], p01[4], p11[4];
#pragma unroll
    for (int r = 0; r < 4; ++r) {
      p00[r] = exp2f(s00[r]);
      p10[r] = exp2f(s10[r]);
      p01[r] = exp2f(s01[r]);
      p11[r] = exp2f(s11[r]);
      den0 += p00[r] + p10[r];
      den1 += p01[r] + p11[r];
    }
    fr pf0, pf1;
    pf0.i[0] = (int)cvt_pk(p00[0], p00[1]);
    pf0.i[1] = (int)cvt_pk(p00[2], p00[3]);
    pf0.i[2] = (int)cvt_pk(p10[0], p10[1]);
    pf0.i[3] = (int)cvt_pk(p10[2], p10[3]);
    pf1.i[0] = (int)cvt_pk(p01[0], p01[1]);
    pf1.i[1] = (int)cvt_pk(p01[2], p01[3]);
    pf1.i[2] = (int)cvt_pk(p11[0], p11[1]);
    pf1.i[3] = (int)cvt_pk(p11[2], p11[3]);

    fr v0, v1;
    v0.i = (i32x4){(int)va0.x, (int)va0.y, (int)vb0.x, (int)vb0.y};
    v1.i = (i32x4){(int)va1.x, (int)va1.y, (int)vb1.x, (int)vb1.y};
    acc00 = __builtin_amdgcn_mfma_f32_16x16x32_bf16(v0.h, pf0.h, acc00, 0, 0, 0);
    acc01 = __builtin_amdgcn_mfma_f32_16x16x32_bf16(v0.h, pf1.h, acc01, 0, 0, 0);
    acc10 = __builtin_amdgcn_mfma_f32_16x16x32_bf16(v1.h, pf0.h, acc10, 0, 0, 0);
    acc11 = __builtin_amdgcn_mfma_f32_16x16x32_bf16(v1.h, pf1.h, acc11, 0, 0, 0);
  }

  den0 += __shfl_xor(den0, 16, 64);
  den0 += __shfl_xor(den0, 32, 64);
  den1 += __shfl_xor(den1, 16, 64);
  den1 += __shfl_xor(den1, 32, 64);

  __syncthreads();
  float(*accs)[32][33] = (float(*)[32][33])pool;
  float(*dsh)[32] = (float(*)[32])(pool + NSPLIT * 32 * 33 * 4);
#pragma unroll
  for (int r = 0; r < 4; ++r) {
    accs[w][g * 4 + r][li] = acc00[r];
    accs[w][g * 4 + r][16 + li] = acc01[r];
    accs[w][16 + g * 4 + r][li] = acc10[r];
    accs[w][16 + g * 4 + r][16 + li] = acc11[r];
  }
  if (g == 0) {
    dsh[w][li] = den0;
    dsh[w][16 + li] = den1;
  }
  __syncthreads();

  int q = tid >> 4, dp = tid & 15;
  float Den = 0.f, o0 = 0.f, o1 = 0.f;
#pragma unroll
  for (int ww = 0; ww < NSPLIT; ++ww) {
    Den += dsh[ww][q];
    o0 += accs[ww][2 * dp][q];
    o1 += accs[ww][2 * dp + 1][q];
  }
  float inv = 1.f / Den;
  int qrow = qt * 32 + q;
  if (qrow < Q_MAX) {
    unsigned pk = cvt_pk(o0 * inv, o1 * inv);
    *reinterpret_cast<unsigned*>(
        AO + ((long)(b * Q_MAX + qrow)) * D + h * HD + 2 * dp) = pk;
  }
}

// ---------------------------------------------------------------------------
__global__ __launch_bounds__(256) void head_kernel(
    const float* __restrict__ enc, const float* __restrict__ hW,
    const float* __restrict__ hb, float* __restrict__ out) {
  int row = blockIdx.x * 4 + (threadIdx.x >> 6);
  int lane = threadIdx.x & 63;
  const float4 a = *reinterpret_cast<const float4*>(enc + (long)row * D + lane * 4);
  float c0 = 0.f, c1 = 0.f, c2 = 0.f;
  const float av[4] = {a.x, a.y, a.z, a.w};
#pragma unroll
  for (int i = 0; i < 4; ++i) {
    int k = lane * 4 + i;
    c0 += av[i] * hW[k * 3];
    c1 += av[i] * hW[k * 3 + 1];
    c2 += av[i] * hW[k * 3 + 2];
  }
#pragma unroll
  for (int off = 32; off; off >>= 1) {
    c0 += __shfl_down(c0, off, 64);
    c1 += __shfl_down(c1, off, 64);
    c2 += __shfl_down(c2, off, 64);
  }
  if (lane == 0) {
    out[(long)row * 3] = c0 + hb[0];
    out[(long)row * 3 + 1] = c1 + hb[1];
    out[(long)row * 3 + 2] = c2 + hb[2];
  }
}

// ---------------------------------------------------------------------------
__global__ __launch_bounds__(64) void overwrite_kernel(
    const float* __restrict__ q_stream, const int* __restrict__ idx,
    const int* __restrict__ mask, const float* __restrict__ hW,
    const float* __restrict__ hb, float* __restrict__ out) {
  int j = blockIdx.x;
  if (!mask[j]) return;
  int b = j / Q_MAX;
  int p = idx[j];
  int lane = threadIdx.x;
  const float* a = q_stream + (long)j * D;
  float a0 = a[lane], a1 = a[lane + 64], a2 = a[lane + 128],
        a3 = a[lane + 192];
  for (int c = 0; c < 3; ++c) {
    float s = a0 * hW[lane * 3 + c] + a1 * hW[(lane + 64) * 3 + c] +
              a2 * hW[(lane + 128) * 3 + c] + a3 * hW[(lane + 192) * 3 + c];
    for (int off = 32; off > 0; off >>= 1) s += __shfl_down(s, off, 64);
    if (lane == 0) out[((long)b * L + p) * 3 + c] = s + hb[c];
  }
}

// ---------------------------------------------------------------------------
extern "C" void kernel_launch(void* const* d_in, const int* in_sizes, int n_in,
                              void* d_out, int out_size, void* d_ws,
                              size_t ws_size, hipStream_t stream) {
  const float* enc = (const float*)d_in[0];
  const float* clog = (const float*)d_in[1];
  const float* ln_q_g = (const float*)d_in[2];
  const float* ln_q_b = (const float*)d_in[3];
  const float* ln_kv_g = (const float*)d_in[4];
  const float* ln_kv_b = (const float*)d_in[5];
  const float* Wq = (const float*)d_in[6];
  const float* bq = (const float*)d_in[7];
  const float* Wk = (const float*)d_in[8];
  const float* bk = (const float*)d_in[9];
  const float* Wv = (const float*)d_in[10];
  const float* bv = (const float*)d_in[11];
  const float* Wo = (const float*)d_in[12];
  const float* bo = (const float*)d_in[13];
  const float* ffn_g = (const float*)d_in[14];
  const float* ffn_b = (const float*)d_in[15];
  const float* W1 = (const float*)d_in[16];
  const float* b1 = (const float*)d_in[17];
  const float* W2 = (const float*)d_in[18];
  const float* b2 = (const float*)d_in[19];
  const float* head_W = (const float*)d_in[20];
  const float* head_b = (const float*)d_in[21];
  float* out = (float*)d_out;

  char* ws = (char*)d_ws;
  float* q_stream = (float*)ws;            ws += (long)QROWS * D * 4;
  u16* kvl0 = (u16*)ws;                    ws += (long)KVROWS * D * 2;
  u16* kvl1 = (u16*)ws;                    ws += (long)KVROWS * D * 2;
  u16* Khbuf = (u16*)ws;                   ws += (long)B * H * L * HD * 2;
  u16* Vhbuf = (u16*)ws;                   ws += (long)B * H * L * HD * 2;
  u16* Qbuf = (u16*)ws;                    ws += (long)QROWS * D * 2;
  u16* AObuf = (u16*)ws;                   ws += (long)QROWS * D * 2;
  u16* H1buf = (u16*)ws;                   ws += (long)QROWS * FF * 2;
  u16* WT = (u16*)ws;                      ws += (long)NL * (4 * D * D + 2 * D * FF) * 2;
  int* idxbuf = (int*)ws;                  ws += QROWS * 4;
  int* maskbuf = (int*)ws;

  const long DD = (long)D * D, DFF = (long)D * FF;
  const long LSTR = 4 * DD + 2 * DFF;

  setup_kernel<<<KVROWS + TRBLK + B, 256, 0, stream>>>(
      enc, clog, ln_kv_g, ln_kv_b, Wq, Wk, Wv, Wo, W1, W2, WT, kvl0, kvl1,
      idxbuf, maskbuf);
  gather_kernel<<<QROWS, 256, 0, stream>>>(enc, idxbuf, q_stream);

  for (int l = 0; l < NL; ++l) {
    u16* base = WT + l * LSTR;
    u16* kv_ln = (l == 0) ? kvl0 : kvl1;

    gemm_proj<<<KVBLK + QRB, 256, 0, stream>>>(
        kv_ln, q_stream, base, ln_q_g + l * D, ln_q_b + l * D, bk + l * D,
        bv + l * D, bq + l * D, Khbuf, Vhbuf, Qbuf);

    attn_mfma<<<B * H * NQT, 512, 0, stream>>>(Qbuf, Khbuf, Vhbuf, AObuf);

    dim3 gQ(D / 64, (QROWS + 63) / 64);
    gemm_mfma<2><<<gQ, 256, 0, stream>>>(AObuf, base + 3 * DD, bo + l * D,
                                         (void*)q_stream, q_stream, maskbuf,
                                         QROWS, D, D);

    gemm_ffn1<<<dim3(4, QRB), 256, 0, stream>>>(
        q_stream, base + 4 * DD, ffn_g + l * D, ffn_b + l * D, b1 + l * FF,
        H1buf);

    dim3 gF2(D / 64, (QROWS + 63) / 64);
    gemm_mfma<2><<<gF2, 256, 0, stream>>>(H1buf, base + 4 * DD + DFF,
                                          b2 + l * D, (void*)q_stream,
                                          q_stream, maskbuf, QROWS, D, FF);
  }

  head_kernel<<<KVROWS / 4, 256, 0, stream>>>(enc, head_W, head_b, out);
  overwrite_kernel<<<QROWS, 64, 0, stream>>>(q_stream, idxbuf, maskbuf, head_W,
                                             head_b, out);
}

// Round 14
// 225.172 us; speedup vs baseline: 1.2856x; 1.2856x over previous
//
#include <hip/hip_runtime.h>
#include <cmath>

constexpr int B = 2, L = 4096, D = 256, H = 8, NC = 3;
constexpr int TOP_N = 8, R = 32;
constexpr int LS = 1000, LE = 3000;
constexpr int NL = 2;
constexpr int FF = 4 * D;                        // 1024
constexpr int Q_MAX = 2 * TOP_N * (2 * R + 1);   // 1040
constexpr int HD = D / H;                        // 32
constexpr int QROWS = B * Q_MAX;                 // 2080
constexpr int KVROWS = B * L;                    // 8192
constexpr int NQT = (Q_MAX + 31) / 32;           // 33 q-tiles of 32
constexpr int NREG = LE - LS;                    // 2000
constexpr int NSPLIT = 8;                        // split-K waves per block
constexpr int KCHUNK = L / NSPLIT;               // 512 keys per wave
constexpr int NT = KCHUNK / 32;                  // 16 iterations
constexpr int KVBLK = 8 * (KVROWS / 64);         // 1024 blocks (KV part)
constexpr int QBLK = 4 * ((QROWS + 63) / 64);    // 132 blocks (Q part)
constexpr int TRBLK = NL * 192;                  // 384 transpose blocks

typedef __attribute__((ext_vector_type(8))) short bf16x8;
typedef __attribute__((ext_vector_type(4))) float f32x4;
typedef __attribute__((ext_vector_type(4))) int i32x4;
typedef unsigned short u16;

union fr {
  bf16x8 h;
  i32x4 i;
};

__device__ __forceinline__ u16 f2bs(float f) {
  unsigned int u = __float_as_uint(f);
  unsigned int r = u + 0x7fffu + ((u >> 16) & 1u);
  return (u16)(r >> 16);
}
__device__ __forceinline__ float bs2f(u16 s) {
  return __uint_as_float(((unsigned int)s) << 16);
}
__device__ __forceinline__ float gelu_exact(float x) {
  return 0.5f * x * (1.f + erff(x * 0.70710678118654752440f));
}
__device__ __forceinline__ unsigned cvt_pk(float lo, float hi) {
  unsigned r;
  asm("v_cvt_pk_bf16_f32 %0, %1, %2" : "=v"(r) : "v"(lo), "v"(hi));
  return r;
}

#define GLL16(gsrc, ldst)                                                   \
  __builtin_amdgcn_global_load_lds(                                         \
      (const __attribute__((address_space(1))) unsigned int*)(gsrc),        \
      (__attribute__((address_space(3))) unsigned int*)(ldst), 16, 0, 0)

// ---------------------------------------------------------------------------
// Merged setup dispatch (256 threads/block):
//   blocks [0, KVROWS)            : dual-layer LayerNorm of enc -> kvl0/kvl1
//   blocks [KVROWS, KVROWS+TRBLK) : LDS-tiled weight transpose+bf16 -> WT
//   blocks [KVROWS+TRBLK, +B)     : vicinity selection (one block per batch)
// ---------------------------------------------------------------------------
__global__ __launch_bounds__(256) void setup_kernel(
    const float* __restrict__ enc, const float* __restrict__ logits,
    const float* __restrict__ lnkvg, const float* __restrict__ lnkvb,
    const float* __restrict__ Wq_, const float* __restrict__ Wk_,
    const float* __restrict__ Wv_, const float* __restrict__ Wo_,
    const float* __restrict__ W1_, const float* __restrict__ W2_,
    u16* __restrict__ WT, u16* __restrict__ o0, u16* __restrict__ o1,
    int* __restrict__ idx_out, int* __restrict__ mask_out) {
  int bid = blockIdx.x;
  int tid = threadIdx.x;
  const long DD = (long)D * D, DFF = (long)D * FF;
  const long LSTR = 4 * DD + 2 * DFF;

  if (bid < KVROWS) {
    long row = bid;
    float x = enc[row * D + tid];
    float s1 = x, s2 = x * x;
#pragma unroll
    for (int off = 32; off; off >>= 1) {
      s1 += __shfl_xor(s1, off, 64);
      s2 += __shfl_xor(s2, off, 64);
    }
    __shared__ float p1[4], p2[4];
    int w = tid >> 6;
    if ((tid & 63) == 0) { p1[w] = s1; p2[w] = s2; }
    __syncthreads();
    s1 = p1[0] + p1[1] + p1[2] + p1[3];
    s2 = p2[0] + p2[1] + p2[2] + p2[3];
    float mean = s1 * (1.f / D);
    float var = fmaxf(s2 * (1.f / D) - mean * mean, 0.f);
    float r = rsqrtf(var + 1e-5f);
    float xn = (x - mean) * r;
    o0[row * D + tid] = f2bs(xn * lnkvg[tid] + lnkvb[tid]);
    o1[row * D + tid] = f2bs(xn * lnkvg[D + tid] + lnkvb[D + tid]);
    return;
  }

  if (bid < KVROWS + TRBLK) {
    __shared__ u16 T[64][65];
    int t = bid - KVROWS;
    int l = t / 192, r = t % 192;
    const float* src;
    long dbase;
    int K_, N_, kt, nt;
    if (r < 64) {
      int which = r >> 4, sub = r & 15;
      kt = sub >> 2;
      nt = sub & 3;
      K_ = 256;
      N_ = 256;
      src = (which == 0 ? Wk_ : which == 1 ? Wv_ : which == 2 ? Wq_ : Wo_) +
            (long)l * DD;
      dbase = (long)l * LSTR + (long)which * DD;
    } else if (r < 128) {
      int sub = r - 64;
      kt = sub >> 4;
      nt = sub & 15;
      K_ = 256;
      N_ = 1024;
      src = W1_ + (long)l * DFF;
      dbase = (long)l * LSTR + 4 * DD;
    } else {
      int sub = r - 128;
      kt = sub >> 2;
      nt = sub & 3;
      K_ = 1024;
      N_ = 256;
      src = W2_ + (long)l * DFF;
      dbase = (long)l * LSTR + 4 * DD + DFF;
    }
    int k0 = kt * 64, n0 = nt * 64;
    {
      int kr = tid >> 2, c16 = (tid & 3) * 16;
      const float* sp = src + (long)(k0 + kr) * N_ + n0 + c16;
#pragma unroll
      for (int i = 0; i < 4; ++i) {
        float4 v = *reinterpret_cast<const float4*>(sp + 4 * i);
        T[kr][c16 + 4 * i + 0] = f2bs(v.x);
        T[kr][c16 + 4 * i + 1] = f2bs(v.y);
        T[kr][c16 + 4 * i + 2] = f2bs(v.z);
        T[kr][c16 + 4 * i + 3] = f2bs(v.w);
      }
    }
    __syncthreads();
    {
      int nr = tid >> 2, kc = (tid & 3) * 16;
      u16 tmp[16];
#pragma unroll
      for (int j = 0; j < 16; ++j) tmp[j] = T[kc + j][nr];
      u16* dp = WT + dbase + (long)(n0 + nr) * K_ + k0 + kc;
      *reinterpret_cast<bf16x8*>(dp) = *reinterpret_cast<const bf16x8*>(&tmp[0]);
      *reinterpret_cast<bf16x8*>(dp + 8) =
          *reinterpret_cast<const bf16x8*>(&tmp[8]);
    }
    return;
  }

  // ---- select part (one block per batch), 256 threads = 4 waves
  {
    int b = bid - KVROWS - TRBLK;
    int w = tid >> 6, lane = tid & 63;
    __shared__ float candv[4][8];
    __shared__ int candi[4][8];
    __shared__ int centers[2 * TOP_N];
    __shared__ unsigned present[L / 32];
    __shared__ int offs[128];
    __shared__ int wtot[2];

    float vd[8], va[8];
#pragma unroll
    for (int j = 0; j < 8; ++j) {
      int p = tid + j * 256;
      if (p < NREG) {
        const float* lg = logits + ((long)b * L + LS + p) * NC;
        float x0 = lg[0], x1 = lg[1], x2 = lg[2];
        float m = fmaxf(x0, fmaxf(x1, x2));
        float lse = m + logf(expf(x0 - m) + expf(x1 - m) + expf(x2 - m));
        vd[j] = x2 - lse;
        va[j] = x1 - lse;
      } else {
        vd[j] = -INFINITY;
        va[j] = -INFINITY;
      }
    }
    if (tid < 128) present[tid] = 0;

    for (int sel = 0; sel < 2; ++sel) {
      float v[8];
#pragma unroll
      for (int j = 0; j < 8; ++j) v[j] = (sel == 0) ? vd[j] : va[j];
#pragma unroll
      for (int r = 0; r < TOP_N; ++r) {
        float mv = v[0];
        int mp = tid;
#pragma unroll
        for (int j = 1; j < 8; ++j) {
          int pj = tid + j * 256;
          if (v[j] > mv) { mv = v[j]; mp = pj; }
        }
#pragma unroll
        for (int off = 32; off; off >>= 1) {
          float ov = __shfl_xor(mv, off, 64);
          int oi = __shfl_xor(mp, off, 64);
          if (ov > mv || (ov == mv && oi < mp)) { mv = ov; mp = oi; }
        }
#pragma unroll
        for (int j = 0; j < 8; ++j)
          if (tid + j * 256 == mp) v[j] = -INFINITY;
        if (lane == 0) { candv[w][r] = mv; candi[w][r] = mp; }
      }
      __syncthreads();
      if (tid < 64) {
        float c = (tid < 32) ? candv[tid >> 3][tid & 7] : -INFINITY;
        int ci = (tid < 32) ? candi[tid >> 3][tid & 7] : 0x7fffffff;
#pragma unroll
        for (int r = 0; r < TOP_N; ++r) {
          float mv = c;
          int mi = ci;
#pragma unroll
          for (int off = 32; off; off >>= 1) {
            float ov = __shfl_xor(mv, off, 64);
            int oi = __shfl_xor(mi, off, 64);
            if (ov > mv || (ov == mv && oi < mi)) { mv = ov; mi = oi; }
          }
          if (ci == mi) c = -INFINITY;
          if (tid == 0) centers[sel * TOP_N + r] = LS + mi;
        }
      }
      __syncthreads();
    }

    for (int j = tid; j < Q_MAX; j += 256) {
      int c = centers[j / (2 * R + 1)];
      int off = j % (2 * R + 1) - R;
      int v2 = c + off;
      v2 = v2 < 0 ? 0 : (v2 > L - 1 ? L - 1 : v2);
      atomicOr(&present[v2 >> 5], 1u << (v2 & 31));
    }
    __syncthreads();

    int cnt = (tid < 128) ? __popc(present[tid]) : 0;
    if (tid < 128) {
      int x = cnt;
#pragma unroll
      for (int off = 1; off < 64; off <<= 1) {
        int o = __shfl_up(x, off, 64);
        if ((tid & 63) >= off) x += o;
      }
      if ((tid & 63) == 63) wtot[tid >> 6] = x;
      offs[tid] = x - cnt;
    }
    __syncthreads();
    int total = wtot[0] + wtot[1];
    if (tid < 128) {
      int base = offs[tid] + ((tid >= 64) ? wtot[0] : 0);
      unsigned mword = present[tid];
      while (mword) {
        int i = __ffs(mword) - 1;
        mword &= mword - 1;
        idx_out[b * Q_MAX + base] = tid * 32 + i;
        mask_out[b * Q_MAX + base] = 1;
        ++base;
      }
    }
    for (int j = total + tid; j < Q_MAX; j += 256) {
      idx_out[b * Q_MAX + j] = L;
      mask_out[b * Q_MAX + j] = 0;
    }
  }
}

// ---------------------------------------------------------------------------
__global__ __launch_bounds__(256) void gather_kernel(
    const float* __restrict__ enc, const int* __restrict__ idx,
    float* __restrict__ q_stream) {
  int row = blockIdx.x;
  int b = row / Q_MAX;
  int p = idx[row];
  float v = 0.f;
  if (p < L) v = enc[((long)b * L + p) * D + threadIdx.x];
  q_stream[(long)row * D + threadIdx.x] = v;
}

// ---------------------------------------------------------------------------
__global__ __launch_bounds__(256) void ln_bf16(
    const float* __restrict__ in, u16* __restrict__ out,
    const float* __restrict__ gg, const float* __restrict__ bb) {
  long row = blockIdx.x;
  int tid = threadIdx.x;
  float x = in[row * D + tid];
  float s1 = x, s2 = x * x;
#pragma unroll
  for (int off = 32; off; off >>= 1) {
    s1 += __shfl_xor(s1, off, 64);
    s2 += __shfl_xor(s2, off, 64);
  }
  __shared__ float p1[4], p2[4];
  int w = tid >> 6;
  if ((tid & 63) == 0) { p1[w] = s1; p2[w] = s2; }
  __syncthreads();
  s1 = p1[0] + p1[1] + p1[2] + p1[3];
  s2 = p2[0] + p2[1] + p2[2] + p2[3];
  float mean = s1 * (1.f / D);
  float var = fmaxf(s2 * (1.f / D) - mean * mean, 0.f);
  float r = rsqrtf(var + 1e-5f);
  out[row * D + tid] = f2bs((x - mean) * r * gg[tid] + bb[tid]);
}

// ---------------------------------------------------------------------------
// bf16 MFMA GEMM (64x64 tile, BK=32, 4 waves).
// EPI 1: gelu->bf16; 2: resid+mask->f32
// ---------------------------------------------------------------------------
template <int EPI>
__global__ __launch_bounds__(256) void gemm_mfma(
    const u16* __restrict__ A, const u16* __restrict__ BT,
    const float* __restrict__ bias, void* __restrict__ Cv,
    const float* __restrict__ resid, const int* __restrict__ mask, int M,
    int N, int K) {
  __shared__ short As[64][40];
  __shared__ short Bs[64][40];
  int bm = blockIdx.y * 64, bn = blockIdx.x * 64;
  int tid = threadIdx.x;
  int lane = tid & 63, w = tid >> 6;
  int g = lane >> 4, li = lane & 15;
  int wr = w >> 1, wc = w & 1;
  f32x4 acc[2][2] = {};

  int srow = tid >> 2, skc = (tid & 3) * 8;
  for (int k0 = 0; k0 < K; k0 += 32) {
    {
      int grow = bm + srow;
      bf16x8 av = {};
      if (grow < M)
        av = *reinterpret_cast<const bf16x8*>(A + (long)grow * K + k0 + skc);
      *reinterpret_cast<bf16x8*>(&As[srow][skc]) = av;
      bf16x8 bv = *reinterpret_cast<const bf16x8*>(
          BT + (long)(bn + srow) * K + k0 + skc);
      *reinterpret_cast<bf16x8*>(&Bs[srow][skc]) = bv;
    }
    __syncthreads();
    bf16x8 a0 = *reinterpret_cast<const bf16x8*>(&As[wr * 32 + li][g * 8]);
    bf16x8 a1 = *reinterpret_cast<const bf16x8*>(&As[wr * 32 + 16 + li][g * 8]);
    bf16x8 b0 = *reinterpret_cast<const bf16x8*>(&Bs[wc * 32 + li][g * 8]);
    bf16x8 b1 = *reinterpret_cast<const bf16x8*>(&Bs[wc * 32 + 16 + li][g * 8]);
    acc[0][0] = __builtin_amdgcn_mfma_f32_16x16x32_bf16(a0, b0, acc[0][0], 0, 0, 0);
    acc[0][1] = __builtin_amdgcn_mfma_f32_16x16x32_bf16(a0, b1, acc[0][1], 0, 0, 0);
    acc[1][0] = __builtin_amdgcn_mfma_f32_16x16x32_bf16(a1, b0, acc[1][0], 0, 0, 0);
    acc[1][1] = __builtin_amdgcn_mfma_f32_16x16x32_bf16(a1, b1, acc[1][1], 0, 0, 0);
    __syncthreads();
  }

#pragma unroll
  for (int mr = 0; mr < 2; ++mr)
#pragma unroll
    for (int nr = 0; nr < 2; ++nr)
#pragma unroll
      for (int r = 0; r < 4; ++r) {
        int row = bm + wr * 32 + mr * 16 + g * 4 + r;
        int col = bn + wc * 32 + nr * 16 + li;
        if (row >= M) continue;
        float v = acc[mr][nr][r] + bias[col];
        if (EPI == 1) v = gelu_exact(v);
        if (EPI == 2) {
          v += resid[(long)row * N + col];
          v = mask[row] ? v : 0.f;
          ((float*)Cv)[(long)row * N + col] = v;
        } else {
          ((u16*)Cv)[(long)row * N + col] = f2bs(v);
        }
      }
}

// ---------------------------------------------------------------------------
// Combined projection dispatch (R12-proven): KV tiles + Q tiles, bf16 A.
// ---------------------------------------------------------------------------
__global__ __launch_bounds__(256) void gemm_proj(
    const u16* __restrict__ Akv, const u16* __restrict__ Aq,
    const u16* __restrict__ WTbase, const float* __restrict__ biasK,
    const float* __restrict__ biasV, const float* __restrict__ biasQ,
    u16* __restrict__ Kh, u16* __restrict__ Vh, u16* __restrict__ Qb) {
  __shared__ short As[64][40];
  __shared__ short Bs[64][40];
  __shared__ u16 Ct[64][72];
  int bid = blockIdx.x;
  int tid = threadIdx.x;
  int lane = tid & 63, w = tid >> 6;
  int g = lane >> 4, li = lane & 15;
  int wr = w >> 1, wc = w & 1;
  f32x4 acc[2][2] = {};
  const long DD = (long)D * D;

  bool isKV = bid < KVBLK;
  int bm, bn, M;
  const u16* A;
  const u16* BT;
  if (isKV) {
    bn = (bid & 7) * 64;
    bm = (bid >> 3) * 64;
    M = KVROWS;
    A = Akv;
    BT = WTbase;
  } else {
    int qb = bid - KVBLK;
    bn = (qb & 3) * 64;
    bm = (qb >> 2) * 64;
    M = QROWS;
    A = Aq;
    BT = WTbase + 2 * DD;
  }

  int srow = tid >> 2, skc = (tid & 3) * 8;
  for (int k0 = 0; k0 < D; k0 += 32) {
    {
      int grow = bm + srow;
      bf16x8 av = {};
      if (grow < M)
        av = *reinterpret_cast<const bf16x8*>(A + (long)grow * D + k0 + skc);
      *reinterpret_cast<bf16x8*>(&As[srow][skc]) = av;
      bf16x8 bv = *reinterpret_cast<const bf16x8*>(
          BT + (long)(bn + srow) * D + k0 + skc);
      *reinterpret_cast<bf16x8*>(&Bs[srow][skc]) = bv;
    }
    __syncthreads();
    bf16x8 a0 = *reinterpret_cast<const bf16x8*>(&As[wr * 32 + li][g * 8]);
    bf16x8 a1 = *reinterpret_cast<const bf16x8*>(&As[wr * 32 + 16 + li][g * 8]);
    bf16x8 b0 = *reinterpret_cast<const bf16x8*>(&Bs[wc * 32 + li][g * 8]);
    bf16x8 b1 = *reinterpret_cast<const bf16x8*>(&Bs[wc * 32 + 16 + li][g * 8]);
    acc[0][0] = __builtin_amdgcn_mfma_f32_16x16x32_bf16(a0, b0, acc[0][0], 0, 0, 0);
    acc[0][1] = __builtin_amdgcn_mfma_f32_16x16x32_bf16(a0, b1, acc[0][1], 0, 0, 0);
    acc[1][0] = __builtin_amdgcn_mfma_f32_16x16x32_bf16(a1, b0, acc[1][0], 0, 0, 0);
    acc[1][1] = __builtin_amdgcn_mfma_f32_16x16x32_bf16(a1, b1, acc[1][1], 0, 0, 0);
    __syncthreads();
  }

  if (!isKV) {
#pragma unroll
    for (int mr = 0; mr < 2; ++mr)
#pragma unroll
      for (int nr = 0; nr < 2; ++nr)
#pragma unroll
        for (int r = 0; r < 4; ++r) {
          int row = bm + wr * 32 + mr * 16 + g * 4 + r;
          int col = bn + wc * 32 + nr * 16 + li;
          if (row >= M) continue;
          Qb[(long)row * D + col] = f2bs(acc[mr][nr][r] + biasQ[col]);
        }
  } else if (bn < 256) {
#pragma unroll
    for (int mr = 0; mr < 2; ++mr)
#pragma unroll
      for (int nr = 0; nr < 2; ++nr)
#pragma unroll
        for (int r = 0; r < 4; ++r) {
          int rowL = wr * 32 + mr * 16 + g * 4 + r;
          int colL = wc * 32 + nr * 16 + li;
          Ct[rowL][colL] = f2bs(acc[mr][nr][r] + biasK[bn + colL]);
        }
    __syncthreads();
#pragma unroll
    for (int p = 0; p < 2; ++p) {
      int rowL = (tid >> 3) + p * 32;
      int c8 = (tid & 7) * 8;
      int grow = bm + rowL;
      int b2 = grow >> 12, key = grow & (L - 1);
      int gcol = bn + c8;
      int hh = gcol >> 5, dd = gcol & (HD - 1);
      int cst = (dd >> 3) ^ ((key >> 1) & 3);
      u16* dst = Kh + (((long)(b2 * H + hh) * L + key) * 32 + (cst << 3));
      *reinterpret_cast<bf16x8*>(dst) =
          *reinterpret_cast<const bf16x8*>(&Ct[rowL][c8]);
    }
  } else {
    int vbn = bn - 256;
#pragma unroll
    for (int mr = 0; mr < 2; ++mr)
#pragma unroll
      for (int nr = 0; nr < 2; ++nr)
#pragma unroll
        for (int r = 0; r < 4; ++r) {
          int rowL = wr * 32 + mr * 16 + g * 4 + r;
          int colL = wc * 32 + nr * 16 + li;
          Ct[colL][rowL] = f2bs(acc[mr][nr][r] + biasV[vbn + colL]);
        }
    __syncthreads();
    int b2 = bm >> 12;
#pragma unroll
    for (int p = 0; p < 2; ++p) {
      int colL = (tid >> 3) + p * 32;
      int rem = tid & 7;
      int kb = rem >> 2, k8 = (rem & 3) * 8;
      int gcol = vbn + colL;
      int hh = gcol >> 5, dd = gcol & (HD - 1);
      int kb32 = ((bm & (L - 1)) >> 5) + kb;
      int j = (k8 >> 2) ^ ((dd >> 1) & 6);
      u16* dst = Vh + (((long)(b2 * H + hh) * (L / 32) + kb32) * 1024 +
                       dd * 32 + (j << 2));
      *reinterpret_cast<bf16x8*>(dst) =
          *reinterpret_cast<const bf16x8*>(&Ct[colL][kb * 32 + k8]);
    }
  }
}

// ---------------------------------------------------------------------------
// Fused flash attention (R12-proven): 512 threads = 8 split-K waves per
// (b,h,32-q tile). Single 4KB wave-private LDS buffer via global_load_lds;
// Kh/Vh XOR-swizzled in global. No-max exp2 softmax. XCD swizzle.
// ---------------------------------------------------------------------------
constexpr int POOLSZ = NSPLIT * 32 * 33 * 4 + NSPLIT * 32 * 4;  // 34816

__global__ __launch_bounds__(512) void attn_mfma(
    const u16* __restrict__ Qb, const u16* __restrict__ Kh,
    const u16* __restrict__ Vh, u16* __restrict__ AO) {
  __shared__ alignas(16) char pool[POOLSZ];
  int i = blockIdx.x;
  int xcd = i & 7, slot = i >> 3;          // 66 slots per XCD
  int bh = (xcd << 1) | (slot >= NQT ? 1 : 0);
  int qt = (slot >= NQT) ? slot - NQT : slot;
  int h = bh & 7;
  int b = bh >> 3;
  int tid = threadIdx.x, w = tid >> 6, lane = tid & 63;
  int g = lane >> 4, li = lane & 15;

  fr qf0, qf1;
  {
    const float QSC = 0.25509836048f;  // (1/sqrt(32)) * log2(e)
#pragma unroll
    for (int qb = 0; qb < 2; ++qb) {
      int qrow = qt * 32 + qb * 16 + li;
      if (qrow >= Q_MAX) qrow = Q_MAX - 1;
      bf16x8 raw = *reinterpret_cast<const bf16x8*>(
          Qb + ((long)(b * Q_MAX + qrow)) * D + h * HD + g * 8);
      fr& qf = qb ? qf1 : qf0;
#pragma unroll
      for (int j = 0; j < 4; ++j)
        qf.i[j] = (int)cvt_pk(bs2f((u16)raw[2 * j]) * QSC,
                              bs2f((u16)raw[2 * j + 1]) * QSC);
    }
  }

  f32x4 acc00 = {}, acc01 = {}, acc10 = {}, acc11 = {};
  float den0 = 0.f, den1 = 0.f;
  const f32x4 z = {};

  const u16* kbase = Kh + ((long)(b * H + h) * L) * HD;
  const u16* vbase = Vh + ((long)(b * H + h) * L) * HD;
  int kstart = w * KCHUNK;
  char* wbase = pool + w * 4096;  // wave-private single buffer (2KB K + 2KB V)

  int s_li = (li >> 1) & 3;
  int t_li = (li >> 1) & 6;
  int kof0 = li * 32 + ((g ^ s_li) << 3);
  int kof1 = (16 + li) * 32 + ((g ^ s_li) << 3);
  int va0o = li * 32 + ((g ^ t_li) << 2);
  int vb0o = li * 32 + (((4 + g) ^ t_li) << 2);
  int va1o = (16 + li) * 32 + ((g ^ t_li) << 2);
  int vb1o = (16 + li) * 32 + (((4 + g) ^ t_li) << 2);

  for (int t = 0; t < NT; ++t) {
    {
      const u16* ks = kbase + (long)(kstart + t * 32) * HD + lane * 8;
      const u16* vs = vbase + (long)(kstart + t * 32) * HD + lane * 8;
      u16* lk = (u16*)wbase;
      asm volatile("s_waitcnt lgkmcnt(0)" ::: "memory");
      GLL16(ks, lk);
      GLL16(ks + 512, lk + 512);
      GLL16(vs, lk + 1024);
      GLL16(vs + 512, lk + 1536);
      asm volatile("s_waitcnt vmcnt(0)" ::: "memory");
      __builtin_amdgcn_sched_barrier(0);
    }

    const u16* kl = (const u16*)wbase;
    const u16* vl = kl + 1024;
    bf16x8 kf0 = *reinterpret_cast<const bf16x8*>(kl + kof0);
    bf16x8 kf1 = *reinterpret_cast<const bf16x8*>(kl + kof1);
    uint2 va0 = *reinterpret_cast<const uint2*>(vl + va0o);
    uint2 vb0 = *reinterpret_cast<const uint2*>(vl + vb0o);
    uint2 va1 = *reinterpret_cast<const uint2*>(vl + va1o);
    uint2 vb1 = *reinterpret_cast<const uint2*>(vl + vb1o);

    f32x4 s00 = __builtin_amdgcn_mfma_f32_16x16x32_bf16(kf0, qf0.h, z, 0, 0, 0);
    f32x4 s10 = __builtin_amdgcn_mfma_f32_16x16x32_bf16(kf1, qf0.h, z, 0, 0, 0);
    f32x4 s01 = __builtin_amdgcn_mfma_f32_16x16x32_bf16(kf0, qf1.h, z, 0, 0, 0);
    f32x4 s11 = __builtin_amdgcn_mfma_f32_16x16x32_bf16(kf1, qf1.h, z, 0, 0, 0);

    float p00[4], p10[4], p01[4], p11[4];
#pragma unroll
    for (int r = 0; r < 4; ++r) {
      p00[r] = exp2f(s00[r]);
      p10[r] = exp2f(s10[r]);
      p01[r] = exp2f(s01[r]);
      p11[r] = exp2f(s11[r]);
      den0 += p00[r] + p10[r];
      den1 += p01[r] + p11[r];
    }
    fr pf0, pf1;
    pf0.i[0] = (int)cvt_pk(p00[0], p00[1]);
    pf0.i[1] = (int)cvt_pk(p00[2], p00[3]);
    pf0.i[2] = (int)cvt_pk(p10[0], p10[1]);
    pf0.i[3] = (int)cvt_pk(p10[2], p10[3]);
    pf1.i[0] = (int)cvt_pk(p01[0], p01[1]);
    pf1.i[1] = (int)cvt_pk(p01[2], p01[3]);
    pf1.i[2] = (int)cvt_pk(p11[0], p11[1]);
    pf1.i[3] = (int)cvt_pk(p11[2], p11[3]);

    fr v0, v1;
    v0.i = (i32x4){(int)va0.x, (int)va0.y, (int)vb0.x, (int)vb0.y};
    v1.i = (i32x4){(int)va1.x, (int)va1.y, (int)vb1.x, (int)vb1.y};
    acc00 = __builtin_amdgcn_mfma_f32_16x16x32_bf16(v0.h, pf0.h, acc00, 0, 0, 0);
    acc01 = __builtin_amdgcn_mfma_f32_16x16x32_bf16(v0.h, pf1.h, acc01, 0, 0, 0);
    acc10 = __builtin_amdgcn_mfma_f32_16x16x32_bf16(v1.h, pf0.h, acc10, 0, 0, 0);
    acc11 = __builtin_amdgcn_mfma_f32_16x16x32_bf16(v1.h, pf1.h, acc11, 0, 0, 0);
  }

  den0 += __shfl_xor(den0, 16, 64);
  den0 += __shfl_xor(den0, 32, 64);
  den1 += __shfl_xor(den1, 16, 64);
  den1 += __shfl_xor(den1, 32, 64);

  __syncthreads();
  float(*accs)[32][33] = (float(*)[32][33])pool;
  float(*dsh)[32] = (float(*)[32])(pool + NSPLIT * 32 * 33 * 4);
#pragma unroll
  for (int r = 0; r < 4; ++r) {
    accs[w][g * 4 + r][li] = acc00[r];
    accs[w][g * 4 + r][16 + li] = acc01[r];
    accs[w][16 + g * 4 + r][li] = acc10[r];
    accs[w][16 + g * 4 + r][16 + li] = acc11[r];
  }
  if (g == 0) {
    dsh[w][li] = den0;
    dsh[w][16 + li] = den1;
  }
  __syncthreads();

  int q = tid >> 4, dp = tid & 15;
  float Den = 0.f, o0 = 0.f, o1 = 0.f;
#pragma unroll
  for (int ww = 0; ww < NSPLIT; ++ww) {
    Den += dsh[ww][q];
    o0 += accs[ww][2 * dp][q];
    o1 += accs[ww][2 * dp + 1][q];
  }
  float inv = 1.f / Den;
  int qrow = qt * 32 + q;
  if (qrow < Q_MAX) {
    unsigned pk = cvt_pk(o0 * inv, o1 * inv);
    *reinterpret_cast<unsigned*>(
        AO + ((long)(b * Q_MAX + qrow)) * D + h * HD + 2 * dp) = pk;
  }
}

// ---------------------------------------------------------------------------
__global__ __launch_bounds__(256) void head_kernel(
    const float* __restrict__ enc, const float* __restrict__ hW,
    const float* __restrict__ hb, float* __restrict__ out) {
  int row = blockIdx.x * 4 + (threadIdx.x >> 6);
  int lane = threadIdx.x & 63;
  const float4 a = *reinterpret_cast<const float4*>(enc + (long)row * D + lane * 4);
  float c0 = 0.f, c1 = 0.f, c2 = 0.f;
  const float av[4] = {a.x, a.y, a.z, a.w};
#pragma unroll
  for (int i = 0; i < 4; ++i) {
    int k = lane * 4 + i;
    c0 += av[i] * hW[k * 3];
    c1 += av[i] * hW[k * 3 + 1];
    c2 += av[i] * hW[k * 3 + 2];
  }
#pragma unroll
  for (int off = 32; off; off >>= 1) {
    c0 += __shfl_down(c0, off, 64);
    c1 += __shfl_down(c1, off, 64);
    c2 += __shfl_down(c2, off, 64);
  }
  if (lane == 0) {
    out[(long)row * 3] = c0 + hb[0];
    out[(long)row * 3 + 1] = c1 + hb[1];
    out[(long)row * 3 + 2] = c2 + hb[2];
  }
}

// ---------------------------------------------------------------------------
__global__ __launch_bounds__(64) void overwrite_kernel(
    const float* __restrict__ q_stream, const int* __restrict__ idx,
    const int* __restrict__ mask, const float* __restrict__ hW,
    const float* __restrict__ hb, float* __restrict__ out) {
  int j = blockIdx.x;
  if (!mask[j]) return;
  int b = j / Q_MAX;
  int p = idx[j];
  int lane = threadIdx.x;
  const float* a = q_stream + (long)j * D;
  float a0 = a[lane], a1 = a[lane + 64], a2 = a[lane + 128],
        a3 = a[lane + 192];
  for (int c = 0; c < 3; ++c) {
    float s = a0 * hW[lane * 3 + c] + a1 * hW[(lane + 64) * 3 + c] +
              a2 * hW[(lane + 128) * 3 + c] + a3 * hW[(lane + 192) * 3 + c];
    for (int off = 32; off > 0; off >>= 1) s += __shfl_down(s, off, 64);
    if (lane == 0) out[((long)b * L + p) * 3 + c] = s + hb[c];
  }
}

// ---------------------------------------------------------------------------
extern "C" void kernel_launch(void* const* d_in, const int* in_sizes, int n_in,
                              void* d_out, int out_size, void* d_ws,
                              size_t ws_size, hipStream_t stream) {
  const float* enc = (const float*)d_in[0];
  const float* clog = (const float*)d_in[1];
  const float* ln_q_g = (const float*)d_in[2];
  const float* ln_q_b = (const float*)d_in[3];
  const float* ln_kv_g = (const float*)d_in[4];
  const float* ln_kv_b = (const float*)d_in[5];
  const float* Wq = (const float*)d_in[6];
  const float* bq = (const float*)d_in[7];
  const float* Wk = (const float*)d_in[8];
  const float* bk = (const float*)d_in[9];
  const float* Wv = (const float*)d_in[10];
  const float* bv = (const float*)d_in[11];
  const float* Wo = (const float*)d_in[12];
  const float* bo = (const float*)d_in[13];
  const float* ffn_g = (const float*)d_in[14];
  const float* ffn_b = (const float*)d_in[15];
  const float* W1 = (const float*)d_in[16];
  const float* b1 = (const float*)d_in[17];
  const float* W2 = (const float*)d_in[18];
  const float* b2 = (const float*)d_in[19];
  const float* head_W = (const float*)d_in[20];
  const float* head_b = (const float*)d_in[21];
  float* out = (float*)d_out;

  char* ws = (char*)d_ws;
  float* q_stream = (float*)ws;            ws += (long)QROWS * D * 4;
  u16* kvl0 = (u16*)ws;                    ws += (long)KVROWS * D * 2;
  u16* kvl1 = (u16*)ws;                    ws += (long)KVROWS * D * 2;
  u16* Khbuf = (u16*)ws;                   ws += (long)B * H * L * HD * 2;
  u16* Vhbuf = (u16*)ws;                   ws += (long)B * H * L * HD * 2;
  u16* q_ln = (u16*)ws;                    ws += (long)QROWS * D * 2;
  u16* Qbuf = (u16*)ws;                    ws += (long)QROWS * D * 2;
  u16* AObuf = (u16*)ws;                   ws += (long)QROWS * D * 2;
  u16* H1buf = (u16*)ws;                   ws += (long)QROWS * FF * 2;
  u16* WT = (u16*)ws;                      ws += (long)NL * (4 * D * D + 2 * D * FF) * 2;
  int* idxbuf = (int*)ws;                  ws += QROWS * 4;
  int* maskbuf = (int*)ws;

  const long DD = (long)D * D, DFF = (long)D * FF;
  const long LSTR = 4 * DD + 2 * DFF;

  setup_kernel<<<KVROWS + TRBLK + B, 256, 0, stream>>>(
      enc, clog, ln_kv_g, ln_kv_b, Wq, Wk, Wv, Wo, W1, W2, WT, kvl0, kvl1,
      idxbuf, maskbuf);
  gather_kernel<<<QROWS, 256, 0, stream>>>(enc, idxbuf, q_stream);

  for (int l = 0; l < NL; ++l) {
    u16* base = WT + l * LSTR;
    u16* kv_ln = (l == 0) ? kvl0 : kvl1;

    ln_bf16<<<QROWS, 256, 0, stream>>>(q_stream, q_ln, ln_q_g + l * D, ln_q_b + l * D);

    gemm_proj<<<KVBLK + QBLK, 256, 0, stream>>>(
        kv_ln, q_ln, base, bk + l * D, bv + l * D, bq + l * D, Khbuf, Vhbuf,
        Qbuf);

    attn_mfma<<<B * H * NQT, 512, 0, stream>>>(Qbuf, Khbuf, Vhbuf, AObuf);

    dim3 gQ(D / 64, (QROWS + 63) / 64);
    gemm_mfma<2><<<gQ, 256, 0, stream>>>(AObuf, base + 3 * DD, bo + l * D,
                                         (void*)q_stream, q_stream, maskbuf,
                                         QROWS, D, D);

    ln_bf16<<<QROWS, 256, 0, stream>>>(q_stream, q_ln, ffn_g + l * D, ffn_b + l * D);
    dim3 gF1(FF / 64, (QROWS + 63) / 64);
    gemm_mfma<1><<<gF1, 256, 0, stream>>>(q_ln, base + 4 * DD, b1 + l * FF,
                                          (void*)H1buf, nullptr, nullptr,
                                          QROWS, FF, D);
    dim3 gF2(D / 64, (QROWS + 63) / 64);
    gemm_mfma<2><<<gF2, 256, 0, stream>>>(H1buf, base + 4 * DD + DFF,
                                          b2 + l * D, (void*)q_stream,
                                          q_stream, maskbuf, QROWS, D, FF);
  }

  head_kernel<<<KVROWS / 4, 256, 0, stream>>>(enc, head_W, head_b, out);
  overwrite_kernel<<<QROWS, 64, 0, stream>>>(q_stream, idxbuf, maskbuf, head_W,
                                             head_b, out);
}

// Round 15
// 222.172 us; speedup vs baseline: 1.3030x; 1.0135x over previous
//
#include <hip/hip_runtime.h>
#include <cmath>

constexpr int B = 2, L = 4096, D = 256, H = 8, NC = 3;
constexpr int TOP_N = 8, R = 32;
constexpr int LS = 1000, LE = 3000;
constexpr int NL = 2;
constexpr int FF = 4 * D;                        // 1024
constexpr int Q_MAX = 2 * TOP_N * (2 * R + 1);   // 1040
constexpr int HD = D / H;                        // 32
constexpr int QROWS = B * Q_MAX;                 // 2080
constexpr int KVROWS = B * L;                    // 8192
constexpr int NQT = (Q_MAX + 31) / 32;           // 33 q-tiles of 32
constexpr int NREG = LE - LS;                    // 2000
constexpr int NSPLIT = 8;                        // split-K waves per block
constexpr int KCHUNK = L / NSPLIT;               // 512 keys per wave
constexpr int NT = KCHUNK / 32;                  // 16 iterations
constexpr int KVBLK = 8 * (KVROWS / 64);         // 1024 blocks (KV part)
constexpr int QBLK = 4 * ((QROWS + 63) / 64);    // 132 blocks (Q part)
constexpr int TRBLK = NL * 192;                  // 384 transpose blocks

typedef __attribute__((ext_vector_type(8))) short bf16x8;
typedef __attribute__((ext_vector_type(4))) float f32x4;
typedef __attribute__((ext_vector_type(4))) int i32x4;
typedef unsigned short u16;

union fr {
  bf16x8 h;
  i32x4 i;
};

__device__ __forceinline__ u16 f2bs(float f) {
  unsigned int u = __float_as_uint(f);
  unsigned int r = u + 0x7fffu + ((u >> 16) & 1u);
  return (u16)(r >> 16);
}
__device__ __forceinline__ float bs2f(u16 s) {
  return __uint_as_float(((unsigned int)s) << 16);
}
__device__ __forceinline__ float gelu_exact(float x) {
  return 0.5f * x * (1.f + erff(x * 0.70710678118654752440f));
}
__device__ __forceinline__ unsigned cvt_pk(float lo, float hi) {
  unsigned r;
  asm("v_cvt_pk_bf16_f32 %0, %1, %2" : "=v"(r) : "v"(lo), "v"(hi));
  return r;
}

#define GLL16(gsrc, ldst)                                                   \
  __builtin_amdgcn_global_load_lds(                                         \
      (const __attribute__((address_space(1))) unsigned int*)(gsrc),        \
      (__attribute__((address_space(3))) unsigned int*)(ldst), 16, 0, 0)

// ---------------------------------------------------------------------------
// Merged setup dispatch (256 threads/block):
//   blocks [0, KVROWS)            : dual-layer LayerNorm of enc -> kvl0/kvl1
//   blocks [KVROWS, KVROWS+TRBLK) : LDS-tiled weight transpose+bf16 -> WT
//   blocks [KVROWS+TRBLK, +B)     : vicinity selection (one block per batch)
//     also emits inv[b*L+pos] = global slot (or -1) for the merged head.
// ---------------------------------------------------------------------------
__global__ __launch_bounds__(256) void setup_kernel(
    const float* __restrict__ enc, const float* __restrict__ logits,
    const float* __restrict__ lnkvg, const float* __restrict__ lnkvb,
    const float* __restrict__ Wq_, const float* __restrict__ Wk_,
    const float* __restrict__ Wv_, const float* __restrict__ Wo_,
    const float* __restrict__ W1_, const float* __restrict__ W2_,
    u16* __restrict__ WT, u16* __restrict__ o0, u16* __restrict__ o1,
    int* __restrict__ idx_out, int* __restrict__ mask_out,
    int* __restrict__ inv_out) {
  int bid = blockIdx.x;
  int tid = threadIdx.x;
  const long DD = (long)D * D, DFF = (long)D * FF;
  const long LSTR = 4 * DD + 2 * DFF;

  if (bid < KVROWS) {
    long row = bid;
    float x = enc[row * D + tid];
    float s1 = x, s2 = x * x;
#pragma unroll
    for (int off = 32; off; off >>= 1) {
      s1 += __shfl_xor(s1, off, 64);
      s2 += __shfl_xor(s2, off, 64);
    }
    __shared__ float p1[4], p2[4];
    int w = tid >> 6;
    if ((tid & 63) == 0) { p1[w] = s1; p2[w] = s2; }
    __syncthreads();
    s1 = p1[0] + p1[1] + p1[2] + p1[3];
    s2 = p2[0] + p2[1] + p2[2] + p2[3];
    float mean = s1 * (1.f / D);
    float var = fmaxf(s2 * (1.f / D) - mean * mean, 0.f);
    float r = rsqrtf(var + 1e-5f);
    float xn = (x - mean) * r;
    o0[row * D + tid] = f2bs(xn * lnkvg[tid] + lnkvb[tid]);
    o1[row * D + tid] = f2bs(xn * lnkvg[D + tid] + lnkvb[D + tid]);
    return;
  }

  if (bid < KVROWS + TRBLK) {
    __shared__ u16 T[64][65];
    int t = bid - KVROWS;
    int l = t / 192, r = t % 192;
    const float* src;
    long dbase;
    int K_, N_, kt, nt;
    if (r < 64) {
      int which = r >> 4, sub = r & 15;
      kt = sub >> 2;
      nt = sub & 3;
      K_ = 256;
      N_ = 256;
      src = (which == 0 ? Wk_ : which == 1 ? Wv_ : which == 2 ? Wq_ : Wo_) +
            (long)l * DD;
      dbase = (long)l * LSTR + (long)which * DD;
    } else if (r < 128) {
      int sub = r - 64;
      kt = sub >> 4;
      nt = sub & 15;
      K_ = 256;
      N_ = 1024;
      src = W1_ + (long)l * DFF;
      dbase = (long)l * LSTR + 4 * DD;
    } else {
      int sub = r - 128;
      kt = sub >> 2;
      nt = sub & 3;
      K_ = 1024;
      N_ = 256;
      src = W2_ + (long)l * DFF;
      dbase = (long)l * LSTR + 4 * DD + DFF;
    }
    int k0 = kt * 64, n0 = nt * 64;
    {
      int kr = tid >> 2, c16 = (tid & 3) * 16;
      const float* sp = src + (long)(k0 + kr) * N_ + n0 + c16;
#pragma unroll
      for (int i = 0; i < 4; ++i) {
        float4 v = *reinterpret_cast<const float4*>(sp + 4 * i);
        T[kr][c16 + 4 * i + 0] = f2bs(v.x);
        T[kr][c16 + 4 * i + 1] = f2bs(v.y);
        T[kr][c16 + 4 * i + 2] = f2bs(v.z);
        T[kr][c16 + 4 * i + 3] = f2bs(v.w);
      }
    }
    __syncthreads();
    {
      int nr = tid >> 2, kc = (tid & 3) * 16;
      u16 tmp[16];
#pragma unroll
      for (int j = 0; j < 16; ++j) tmp[j] = T[kc + j][nr];
      u16* dp = WT + dbase + (long)(n0 + nr) * K_ + k0 + kc;
      *reinterpret_cast<bf16x8*>(dp) = *reinterpret_cast<const bf16x8*>(&tmp[0]);
      *reinterpret_cast<bf16x8*>(dp + 8) =
          *reinterpret_cast<const bf16x8*>(&tmp[8]);
    }
    return;
  }

  // ---- select part (one block per batch), 256 threads = 4 waves
  {
    int b = bid - KVROWS - TRBLK;
    int w = tid >> 6, lane = tid & 63;
    __shared__ float candv[4][8];
    __shared__ int candi[4][8];
    __shared__ int centers[2 * TOP_N];
    __shared__ unsigned present[L / 32];
    __shared__ int offs[128];
    __shared__ int wtot[2];

    float vd[8], va[8];
#pragma unroll
    for (int j = 0; j < 8; ++j) {
      int p = tid + j * 256;
      if (p < NREG) {
        const float* lg = logits + ((long)b * L + LS + p) * NC;
        float x0 = lg[0], x1 = lg[1], x2 = lg[2];
        float m = fmaxf(x0, fmaxf(x1, x2));
        float lse = m + logf(expf(x0 - m) + expf(x1 - m) + expf(x2 - m));
        vd[j] = x2 - lse;
        va[j] = x1 - lse;
      } else {
        vd[j] = -INFINITY;
        va[j] = -INFINITY;
      }
    }
    if (tid < 128) present[tid] = 0;
    // clear inverse map for this batch
    for (int j = tid; j < L; j += 256) inv_out[(long)b * L + j] = -1;

    for (int sel = 0; sel < 2; ++sel) {
      float v[8];
#pragma unroll
      for (int j = 0; j < 8; ++j) v[j] = (sel == 0) ? vd[j] : va[j];
#pragma unroll
      for (int r = 0; r < TOP_N; ++r) {
        float mv = v[0];
        int mp = tid;
#pragma unroll
        for (int j = 1; j < 8; ++j) {
          int pj = tid + j * 256;
          if (v[j] > mv) { mv = v[j]; mp = pj; }
        }
#pragma unroll
        for (int off = 32; off; off >>= 1) {
          float ov = __shfl_xor(mv, off, 64);
          int oi = __shfl_xor(mp, off, 64);
          if (ov > mv || (ov == mv && oi < mp)) { mv = ov; mp = oi; }
        }
#pragma unroll
        for (int j = 0; j < 8; ++j)
          if (tid + j * 256 == mp) v[j] = -INFINITY;
        if (lane == 0) { candv[w][r] = mv; candi[w][r] = mp; }
      }
      __syncthreads();
      if (tid < 64) {
        float c = (tid < 32) ? candv[tid >> 3][tid & 7] : -INFINITY;
        int ci = (tid < 32) ? candi[tid >> 3][tid & 7] : 0x7fffffff;
#pragma unroll
        for (int r = 0; r < TOP_N; ++r) {
          float mv = c;
          int mi = ci;
#pragma unroll
          for (int off = 32; off; off >>= 1) {
            float ov = __shfl_xor(mv, off, 64);
            int oi = __shfl_xor(mi, off, 64);
            if (ov > mv || (ov == mv && oi < mi)) { mv = ov; mi = oi; }
          }
          if (ci == mi) c = -INFINITY;
          if (tid == 0) centers[sel * TOP_N + r] = LS + mi;
        }
      }
      __syncthreads();
    }

    for (int j = tid; j < Q_MAX; j += 256) {
      int c = centers[j / (2 * R + 1)];
      int off = j % (2 * R + 1) - R;
      int v2 = c + off;
      v2 = v2 < 0 ? 0 : (v2 > L - 1 ? L - 1 : v2);
      atomicOr(&present[v2 >> 5], 1u << (v2 & 31));
    }
    __syncthreads();

    int cnt = (tid < 128) ? __popc(present[tid]) : 0;
    if (tid < 128) {
      int x = cnt;
#pragma unroll
      for (int off = 1; off < 64; off <<= 1) {
        int o = __shfl_up(x, off, 64);
        if ((tid & 63) >= off) x += o;
      }
      if ((tid & 63) == 63) wtot[tid >> 6] = x;
      offs[tid] = x - cnt;
    }
    __syncthreads();
    int total = wtot[0] + wtot[1];
    if (tid < 128) {
      int base = offs[tid] + ((tid >= 64) ? wtot[0] : 0);
      unsigned mword = present[tid];
      while (mword) {
        int i = __ffs(mword) - 1;
        mword &= mword - 1;
        int pos = tid * 32 + i;
        idx_out[b * Q_MAX + base] = pos;
        mask_out[b * Q_MAX + base] = 1;
        inv_out[(long)b * L + pos] = b * Q_MAX + base;
        ++base;
      }
    }
    for (int j = total + tid; j < Q_MAX; j += 256) {
      idx_out[b * Q_MAX + j] = L;
      mask_out[b * Q_MAX + j] = 0;
    }
  }
}

// ---------------------------------------------------------------------------
// Gather + layer-0 Q-LayerNorm fused: writes fp32 q_stream AND bf16 q_ln.
// ---------------------------------------------------------------------------
__global__ __launch_bounds__(256) void gather_ln(
    const float* __restrict__ enc, const int* __restrict__ idx,
    float* __restrict__ q_stream, u16* __restrict__ q_ln,
    const float* __restrict__ gg, const float* __restrict__ bb) {
  int row = blockIdx.x;
  int b = row / Q_MAX;
  int p = idx[row];
  int tid = threadIdx.x;
  float x = 0.f;
  if (p < L) x = enc[((long)b * L + p) * D + tid];
  q_stream[(long)row * D + tid] = x;
  float s1 = x, s2 = x * x;
#pragma unroll
  for (int off = 32; off; off >>= 1) {
    s1 += __shfl_xor(s1, off, 64);
    s2 += __shfl_xor(s2, off, 64);
  }
  __shared__ float p1[4], p2[4];
  int w = tid >> 6;
  if ((tid & 63) == 0) { p1[w] = s1; p2[w] = s2; }
  __syncthreads();
  s1 = p1[0] + p1[1] + p1[2] + p1[3];
  s2 = p2[0] + p2[1] + p2[2] + p2[3];
  float mean = s1 * (1.f / D);
  float var = fmaxf(s2 * (1.f / D) - mean * mean, 0.f);
  float r = rsqrtf(var + 1e-5f);
  q_ln[(long)row * D + tid] = f2bs((x - mean) * r * gg[tid] + bb[tid]);
}

// ---------------------------------------------------------------------------
__global__ __launch_bounds__(256) void ln_bf16(
    const float* __restrict__ in, u16* __restrict__ out,
    const float* __restrict__ gg, const float* __restrict__ bb) {
  long row = blockIdx.x;
  int tid = threadIdx.x;
  float x = in[row * D + tid];
  float s1 = x, s2 = x * x;
#pragma unroll
  for (int off = 32; off; off >>= 1) {
    s1 += __shfl_xor(s1, off, 64);
    s2 += __shfl_xor(s2, off, 64);
  }
  __shared__ float p1[4], p2[4];
  int w = tid >> 6;
  if ((tid & 63) == 0) { p1[w] = s1; p2[w] = s2; }
  __syncthreads();
  s1 = p1[0] + p1[1] + p1[2] + p1[3];
  s2 = p2[0] + p2[1] + p2[2] + p2[3];
  float mean = s1 * (1.f / D);
  float var = fmaxf(s2 * (1.f / D) - mean * mean, 0.f);
  float r = rsqrtf(var + 1e-5f);
  out[row * D + tid] = f2bs((x - mean) * r * gg[tid] + bb[tid]);
}

// ---------------------------------------------------------------------------
// bf16 MFMA GEMM (64x64 tile, BK=32, 4 waves).
// EPI 1: gelu->bf16; 2: resid+mask->f32
// ---------------------------------------------------------------------------
template <int EPI>
__global__ __launch_bounds__(256) void gemm_mfma(
    const u16* __restrict__ A, const u16* __restrict__ BT,
    const float* __restrict__ bias, void* __restrict__ Cv,
    const float* __restrict__ resid, const int* __restrict__ mask, int M,
    int N, int K) {
  __shared__ short As[64][40];
  __shared__ short Bs[64][40];
  int bm = blockIdx.y * 64, bn = blockIdx.x * 64;
  int tid = threadIdx.x;
  int lane = tid & 63, w = tid >> 6;
  int g = lane >> 4, li = lane & 15;
  int wr = w >> 1, wc = w & 1;
  f32x4 acc[2][2] = {};

  int srow = tid >> 2, skc = (tid & 3) * 8;
  for (int k0 = 0; k0 < K; k0 += 32) {
    {
      int grow = bm + srow;
      bf16x8 av = {};
      if (grow < M)
        av = *reinterpret_cast<const bf16x8*>(A + (long)grow * K + k0 + skc);
      *reinterpret_cast<bf16x8*>(&As[srow][skc]) = av;
      bf16x8 bv = *reinterpret_cast<const bf16x8*>(
          BT + (long)(bn + srow) * K + k0 + skc);
      *reinterpret_cast<bf16x8*>(&Bs[srow][skc]) = bv;
    }
    __syncthreads();
    bf16x8 a0 = *reinterpret_cast<const bf16x8*>(&As[wr * 32 + li][g * 8]);
    bf16x8 a1 = *reinterpret_cast<const bf16x8*>(&As[wr * 32 + 16 + li][g * 8]);
    bf16x8 b0 = *reinterpret_cast<const bf16x8*>(&Bs[wc * 32 + li][g * 8]);
    bf16x8 b1 = *reinterpret_cast<const bf16x8*>(&Bs[wc * 32 + 16 + li][g * 8]);
    acc[0][0] = __builtin_amdgcn_mfma_f32_16x16x32_bf16(a0, b0, acc[0][0], 0, 0, 0);
    acc[0][1] = __builtin_amdgcn_mfma_f32_16x16x32_bf16(a0, b1, acc[0][1], 0, 0, 0);
    acc[1][0] = __builtin_amdgcn_mfma_f32_16x16x32_bf16(a1, b0, acc[1][0], 0, 0, 0);
    acc[1][1] = __builtin_amdgcn_mfma_f32_16x16x32_bf16(a1, b1, acc[1][1], 0, 0, 0);
    __syncthreads();
  }

#pragma unroll
  for (int mr = 0; mr < 2; ++mr)
#pragma unroll
    for (int nr = 0; nr < 2; ++nr)
#pragma unroll
      for (int r = 0; r < 4; ++r) {
        int row = bm + wr * 32 + mr * 16 + g * 4 + r;
        int col = bn + wc * 32 + nr * 16 + li;
        if (row >= M) continue;
        float v = acc[mr][nr][r] + bias[col];
        if (EPI == 1) v = gelu_exact(v);
        if (EPI == 2) {
          v += resid[(long)row * N + col];
          v = mask[row] ? v : 0.f;
          ((float*)Cv)[(long)row * N + col] = v;
        } else {
          ((u16*)Cv)[(long)row * N + col] = f2bs(v);
        }
      }
}

// ---------------------------------------------------------------------------
// Combined projection dispatch (R12-proven): KV tiles + Q tiles, bf16 A.
// ---------------------------------------------------------------------------
__global__ __launch_bounds__(256) void gemm_proj(
    const u16* __restrict__ Akv, const u16* __restrict__ Aq,
    const u16* __restrict__ WTbase, const float* __restrict__ biasK,
    const float* __restrict__ biasV, const float* __restrict__ biasQ,
    u16* __restrict__ Kh, u16* __restrict__ Vh, u16* __restrict__ Qb) {
  __shared__ short As[64][40];
  __shared__ short Bs[64][40];
  __shared__ u16 Ct[64][72];
  int bid = blockIdx.x;
  int tid = threadIdx.x;
  int lane = tid & 63, w = tid >> 6;
  int g = lane >> 4, li = lane & 15;
  int wr = w >> 1, wc = w & 1;
  f32x4 acc[2][2] = {};
  const long DD = (long)D * D;

  bool isKV = bid < KVBLK;
  int bm, bn, M;
  const u16* A;
  const u16* BT;
  if (isKV) {
    bn = (bid & 7) * 64;
    bm = (bid >> 3) * 64;
    M = KVROWS;
    A = Akv;
    BT = WTbase;
  } else {
    int qb = bid - KVBLK;
    bn = (qb & 3) * 64;
    bm = (qb >> 2) * 64;
    M = QROWS;
    A = Aq;
    BT = WTbase + 2 * DD;
  }

  int srow = tid >> 2, skc = (tid & 3) * 8;
  for (int k0 = 0; k0 < D; k0 += 32) {
    {
      int grow = bm + srow;
      bf16x8 av = {};
      if (grow < M)
        av = *reinterpret_cast<const bf16x8*>(A + (long)grow * D + k0 + skc);
      *reinterpret_cast<bf16x8*>(&As[srow][skc]) = av;
      bf16x8 bv = *reinterpret_cast<const bf16x8*>(
          BT + (long)(bn + srow) * D + k0 + skc);
      *reinterpret_cast<bf16x8*>(&Bs[srow][skc]) = bv;
    }
    __syncthreads();
    bf16x8 a0 = *reinterpret_cast<const bf16x8*>(&As[wr * 32 + li][g * 8]);
    bf16x8 a1 = *reinterpret_cast<const bf16x8*>(&As[wr * 32 + 16 + li][g * 8]);
    bf16x8 b0 = *reinterpret_cast<const bf16x8*>(&Bs[wc * 32 + li][g * 8]);
    bf16x8 b1 = *reinterpret_cast<const bf16x8*>(&Bs[wc * 32 + 16 + li][g * 8]);
    acc[0][0] = __builtin_amdgcn_mfma_f32_16x16x32_bf16(a0, b0, acc[0][0], 0, 0, 0);
    acc[0][1] = __builtin_amdgcn_mfma_f32_16x16x32_bf16(a0, b1, acc[0][1], 0, 0, 0);
    acc[1][0] = __builtin_amdgcn_mfma_f32_16x16x32_bf16(a1, b0, acc[1][0], 0, 0, 0);
    acc[1][1] = __builtin_amdgcn_mfma_f32_16x16x32_bf16(a1, b1, acc[1][1], 0, 0, 0);
    __syncthreads();
  }

  if (!isKV) {
#pragma unroll
    for (int mr = 0; mr < 2; ++mr)
#pragma unroll
      for (int nr = 0; nr < 2; ++nr)
#pragma unroll
        for (int r = 0; r < 4; ++r) {
          int row = bm + wr * 32 + mr * 16 + g * 4 + r;
          int col = bn + wc * 32 + nr * 16 + li;
          if (row >= M) continue;
          Qb[(long)row * D + col] = f2bs(acc[mr][nr][r] + biasQ[col]);
        }
  } else if (bn < 256) {
#pragma unroll
    for (int mr = 0; mr < 2; ++mr)
#pragma unroll
      for (int nr = 0; nr < 2; ++nr)
#pragma unroll
        for (int r = 0; r < 4; ++r) {
          int rowL = wr * 32 + mr * 16 + g * 4 + r;
          int colL = wc * 32 + nr * 16 + li;
          Ct[rowL][colL] = f2bs(acc[mr][nr][r] + biasK[bn + colL]);
        }
    __syncthreads();
#pragma unroll
    for (int p = 0; p < 2; ++p) {
      int rowL = (tid >> 3) + p * 32;
      int c8 = (tid & 7) * 8;
      int grow = bm + rowL;
      int b2 = grow >> 12, key = grow & (L - 1);
      int gcol = bn + c8;
      int hh = gcol >> 5, dd = gcol & (HD - 1);
      int cst = (dd >> 3) ^ ((key >> 1) & 3);
      u16* dst = Kh + (((long)(b2 * H + hh) * L + key) * 32 + (cst << 3));
      *reinterpret_cast<bf16x8*>(dst) =
          *reinterpret_cast<const bf16x8*>(&Ct[rowL][c8]);
    }
  } else {
    int vbn = bn - 256;
#pragma unroll
    for (int mr = 0; mr < 2; ++mr)
#pragma unroll
      for (int nr = 0; nr < 2; ++nr)
#pragma unroll
        for (int r = 0; r < 4; ++r) {
          int rowL = wr * 32 + mr * 16 + g * 4 + r;
          int colL = wc * 32 + nr * 16 + li;
          Ct[colL][rowL] = f2bs(acc[mr][nr][r] + biasV[vbn + colL]);
        }
    __syncthreads();
    int b2 = bm >> 12;
#pragma unroll
    for (int p = 0; p < 2; ++p) {
      int colL = (tid >> 3) + p * 32;
      int rem = tid & 7;
      int kb = rem >> 2, k8 = (rem & 3) * 8;
      int gcol = vbn + colL;
      int hh = gcol >> 5, dd = gcol & (HD - 1);
      int kb32 = ((bm & (L - 1)) >> 5) + kb;
      int j = (k8 >> 2) ^ ((dd >> 1) & 6);
      u16* dst = Vh + (((long)(b2 * H + hh) * (L / 32) + kb32) * 1024 +
                       dd * 32 + (j << 2));
      *reinterpret_cast<bf16x8*>(dst) =
          *reinterpret_cast<const bf16x8*>(&Ct[colL][kb * 32 + k8]);
    }
  }
}

// ---------------------------------------------------------------------------
// Fused flash attention (R12-proven): 512 threads = 8 split-K waves per
// (b,h,32-q tile). Single 4KB wave-private LDS buffer via global_load_lds;
// Kh/Vh XOR-swizzled in global. No-max exp2 softmax. XCD swizzle.
// ---------------------------------------------------------------------------
constexpr int POOLSZ = NSPLIT * 32 * 33 * 4 + NSPLIT * 32 * 4;  // 34816

__global__ __launch_bounds__(512) void attn_mfma(
    const u16* __restrict__ Qb, const u16* __restrict__ Kh,
    const u16* __restrict__ Vh, u16* __restrict__ AO) {
  __shared__ alignas(16) char pool[POOLSZ];
  int i = blockIdx.x;
  int xcd = i & 7, slot = i >> 3;          // 66 slots per XCD
  int bh = (xcd << 1) | (slot >= NQT ? 1 : 0);
  int qt = (slot >= NQT) ? slot - NQT : slot;
  int h = bh & 7;
  int b = bh >> 3;
  int tid = threadIdx.x, w = tid >> 6, lane = tid & 63;
  int g = lane >> 4, li = lane & 15;

  fr qf0, qf1;
  {
    const float QSC = 0.25509836048f;  // (1/sqrt(32)) * log2(e)
#pragma unroll
    for (int qb = 0; qb < 2; ++qb) {
      int qrow = qt * 32 + qb * 16 + li;
      if (qrow >= Q_MAX) qrow = Q_MAX - 1;
      bf16x8 raw = *reinterpret_cast<const bf16x8*>(
          Qb + ((long)(b * Q_MAX + qrow)) * D + h * HD + g * 8);
      fr& qf = qb ? qf1 : qf0;
#pragma unroll
      for (int j = 0; j < 4; ++j)
        qf.i[j] = (int)cvt_pk(bs2f((u16)raw[2 * j]) * QSC,
                              bs2f((u16)raw[2 * j + 1]) * QSC);
    }
  }

  f32x4 acc00 = {}, acc01 = {}, acc10 = {}, acc11 = {};
  float den0 = 0.f, den1 = 0.f;
  const f32x4 z = {};

  const u16* kbase = Kh + ((long)(b * H + h) * L) * HD;
  const u16* vbase = Vh + ((long)(b * H + h) * L) * HD;
  int kstart = w * KCHUNK;
  char* wbase = pool + w * 4096;  // wave-private single buffer (2KB K + 2KB V)

  int s_li = (li >> 1) & 3;
  int t_li = (li >> 1) & 6;
  int kof0 = li * 32 + ((g ^ s_li) << 3);
  int kof1 = (16 + li) * 32 + ((g ^ s_li) << 3);
  int va0o = li * 32 + ((g ^ t_li) << 2);
  int vb0o = li * 32 + (((4 + g) ^ t_li) << 2);
  int va1o = (16 + li) * 32 + ((g ^ t_li) << 2);
  int vb1o = (16 + li) * 32 + (((4 + g) ^ t_li) << 2);

  for (int t = 0; t < NT; ++t) {
    {
      const u16* ks = kbase + (long)(kstart + t * 32) * HD + lane * 8;
      const u16* vs = vbase + (long)(kstart + t * 32) * HD + lane * 8;
      u16* lk = (u16*)wbase;
      asm volatile("s_waitcnt lgkmcnt(0)" ::: "memory");
      GLL16(ks, lk);
      GLL16(ks + 512, lk + 512);
      GLL16(vs, lk + 1024);
      GLL16(vs + 512, lk + 1536);
      asm volatile("s_waitcnt vmcnt(0)" ::: "memory");
      __builtin_amdgcn_sched_barrier(0);
    }

    const u16* kl = (const u16*)wbase;
    const u16* vl = kl + 1024;
    bf16x8 kf0 = *reinterpret_cast<const bf16x8*>(kl + kof0);
    bf16x8 kf1 = *reinterpret_cast<const bf16x8*>(kl + kof1);
    uint2 va0 = *reinterpret_cast<const uint2*>(vl + va0o);
    uint2 vb0 = *reinterpret_cast<const uint2*>(vl + vb0o);
    uint2 va1 = *reinterpret_cast<const uint2*>(vl + va1o);
    uint2 vb1 = *reinterpret_cast<const uint2*>(vl + vb1o);

    f32x4 s00 = __builtin_amdgcn_mfma_f32_16x16x32_bf16(kf0, qf0.h, z, 0, 0, 0);
    f32x4 s10 = __builtin_amdgcn_mfma_f32_16x16x32_bf16(kf1, qf0.h, z, 0, 0, 0);
    f32x4 s01 = __builtin_amdgcn_mfma_f32_16x16x32_bf16(kf0, qf1.h, z, 0, 0, 0);
    f32x4 s11 = __builtin_amdgcn_mfma_f32_16x16x32_bf16(kf1, qf1.h, z, 0, 0, 0);

    float p00[4], p10[4], p01[4], p11[4];
#pragma unroll
    for (int r = 0; r < 4; ++r) {
      p00[r] = exp2f(s00[r]);
      p10[r] = exp2f(s10[r]);
      p01[r] = exp2f(s01[r]);
      p11[r] = exp2f(s11[r]);
      den0 += p00[r] + p10[r];
      den1 += p01[r] + p11[r];
    }
    fr pf0, pf1;
    pf0.i[0] = (int)cvt_pk(p00[0], p00[1]);
    pf0.i[1] = (int)cvt_pk(p00[2], p00[3]);
    pf0.i[2] = (int)cvt_pk(p10[0], p10[1]);
    pf0.i[3] = (int)cvt_pk(p10[2], p10[3]);
    pf1.i[0] = (int)cvt_pk(p01[0], p01[1]);
    pf1.i[1] = (int)cvt_pk(p01[2], p01[3]);
    pf1.i[2] = (int)cvt_pk(p11[0], p11[1]);
    pf1.i[3] = (int)cvt_pk(p11[2], p11[3]);

    fr v0, v1;
    v0.i = (i32x4){(int)va0.x, (int)va0.y, (int)vb0.x, (int)vb0.y};
    v1.i = (i32x4){(int)va1.x, (int)va1.y, (int)vb1.x, (int)vb1.y};
    acc00 = __builtin_amdgcn_mfma_f32_16x16x32_bf16(v0.h, pf0.h, acc00, 0, 0, 0);
    acc01 = __builtin_amdgcn_mfma_f32_16x16x32_bf16(v0.h, pf1.h, acc01, 0, 0, 0);
    acc10 = __builtin_amdgcn_mfma_f32_16x16x32_bf16(v1.h, pf0.h, acc10, 0, 0, 0);
    acc11 = __builtin_amdgcn_mfma_f32_16x16x32_bf16(v1.h, pf1.h, acc11, 0, 0, 0);
  }

  den0 += __shfl_xor(den0, 16, 64);
  den0 += __shfl_xor(den0, 32, 64);
  den1 += __shfl_xor(den1, 16, 64);
  den1 += __shfl_xor(den1, 32, 64);

  __syncthreads();
  float(*accs)[32][33] = (float(*)[32][33])pool;
  float(*dsh)[32] = (float(*)[32])(pool + NSPLIT * 32 * 33 * 4);
#pragma unroll
  for (int r = 0; r < 4; ++r) {
    accs[w][g * 4 + r][li] = acc00[r];
    accs[w][g * 4 + r][16 + li] = acc01[r];
    accs[w][16 + g * 4 + r][li] = acc10[r];
    accs[w][16 + g * 4 + r][16 + li] = acc11[r];
  }
  if (g == 0) {
    dsh[w][li] = den0;
    dsh[w][16 + li] = den1;
  }
  __syncthreads();

  int q = tid >> 4, dp = tid & 15;
  float Den = 0.f, o0 = 0.f, o1 = 0.f;
#pragma unroll
  for (int ww = 0; ww < NSPLIT; ++ww) {
    Den += dsh[ww][q];
    o0 += accs[ww][2 * dp][q];
    o1 += accs[ww][2 * dp + 1][q];
  }
  float inv = 1.f / Den;
  int qrow = qt * 32 + q;
  if (qrow < Q_MAX) {
    unsigned pk = cvt_pk(o0 * inv, o1 * inv);
    *reinterpret_cast<unsigned*>(
        AO + ((long)(b * Q_MAX + qrow)) * D + h * HD + 2 * dp) = pk;
  }
}

// ---------------------------------------------------------------------------
// Merged head: for each (b,pos) row, input = q_stream[inv] if selected
// (refined stream), else enc row. One pass over all rows, no second dispatch.
// ---------------------------------------------------------------------------
__global__ __launch_bounds__(256) void head_kernel(
    const float* __restrict__ enc, const float* __restrict__ q_stream,
    const int* __restrict__ inv, const float* __restrict__ hW,
    const float* __restrict__ hb, float* __restrict__ out) {
  int row = blockIdx.x * 4 + (threadIdx.x >> 6);
  int lane = threadIdx.x & 63;
  int slot = inv[row];
  const float* src =
      (slot >= 0) ? (q_stream + (long)slot * D) : (enc + (long)row * D);
  const float4 a = *reinterpret_cast<const float4*>(src + lane * 4);
  float c0 = 0.f, c1 = 0.f, c2 = 0.f;
  const float av[4] = {a.x, a.y, a.z, a.w};
#pragma unroll
  for (int i = 0; i < 4; ++i) {
    int k = lane * 4 + i;
    c0 += av[i] * hW[k * 3];
    c1 += av[i] * hW[k * 3 + 1];
    c2 += av[i] * hW[k * 3 + 2];
  }
#pragma unroll
  for (int off = 32; off; off >>= 1) {
    c0 += __shfl_down(c0, off, 64);
    c1 += __shfl_down(c1, off, 64);
    c2 += __shfl_down(c2, off, 64);
  }
  if (lane == 0) {
    out[(long)row * 3] = c0 + hb[0];
    out[(long)row * 3 + 1] = c1 + hb[1];
    out[(long)row * 3 + 2] = c2 + hb[2];
  }
}

// ---------------------------------------------------------------------------
extern "C" void kernel_launch(void* const* d_in, const int* in_sizes, int n_in,
                              void* d_out, int out_size, void* d_ws,
                              size_t ws_size, hipStream_t stream) {
  const float* enc = (const float*)d_in[0];
  const float* clog = (const float*)d_in[1];
  const float* ln_q_g = (const float*)d_in[2];
  const float* ln_q_b = (const float*)d_in[3];
  const float* ln_kv_g = (const float*)d_in[4];
  const float* ln_kv_b = (const float*)d_in[5];
  const float* Wq = (const float*)d_in[6];
  const float* bq = (const float*)d_in[7];
  const float* Wk = (const float*)d_in[8];
  const float* bk = (const float*)d_in[9];
  const float* Wv = (const float*)d_in[10];
  const float* bv = (const float*)d_in[11];
  const float* Wo = (const float*)d_in[12];
  const float* bo = (const float*)d_in[13];
  const float* ffn_g = (const float*)d_in[14];
  const float* ffn_b = (const float*)d_in[15];
  const float* W1 = (const float*)d_in[16];
  const float* b1 = (const float*)d_in[17];
  const float* W2 = (const float*)d_in[18];
  const float* b2 = (const float*)d_in[19];
  const float* head_W = (const float*)d_in[20];
  const float* head_b = (const float*)d_in[21];
  float* out = (float*)d_out;

  char* ws = (char*)d_ws;
  float* q_stream = (float*)ws;            ws += (long)QROWS * D * 4;
  u16* kvl0 = (u16*)ws;                    ws += (long)KVROWS * D * 2;
  u16* kvl1 = (u16*)ws;                    ws += (long)KVROWS * D * 2;
  u16* Khbuf = (u16*)ws;                   ws += (long)B * H * L * HD * 2;
  u16* Vhbuf = (u16*)ws;                   ws += (long)B * H * L * HD * 2;
  u16* q_ln = (u16*)ws;                    ws += (long)QROWS * D * 2;
  u16* Qbuf = (u16*)ws;                    ws += (long)QROWS * D * 2;
  u16* AObuf = (u16*)ws;                   ws += (long)QROWS * D * 2;
  u16* H1buf = (u16*)ws;                   ws += (long)QROWS * FF * 2;
  u16* WT = (u16*)ws;                      ws += (long)NL * (4 * D * D + 2 * D * FF) * 2;
  int* idxbuf = (int*)ws;                  ws += QROWS * 4;
  int* maskbuf = (int*)ws;                 ws += QROWS * 4;
  int* invbuf = (int*)ws;                  ws += (long)B * L * 4;

  const long DD = (long)D * D, DFF = (long)D * FF;
  const long LSTR = 4 * DD + 2 * DFF;

  setup_kernel<<<KVROWS + TRBLK + B, 256, 0, stream>>>(
      enc, clog, ln_kv_g, ln_kv_b, Wq, Wk, Wv, Wo, W1, W2, WT, kvl0, kvl1,
      idxbuf, maskbuf, invbuf);
  gather_ln<<<QROWS, 256, 0, stream>>>(enc, idxbuf, q_stream, q_ln, ln_q_g,
                                       ln_q_b);

  for (int l = 0; l < NL; ++l) {
    u16* base = WT + l * LSTR;
    u16* kv_ln = (l == 0) ? kvl0 : kvl1;

    if (l > 0)
      ln_bf16<<<QROWS, 256, 0, stream>>>(q_stream, q_ln, ln_q_g + l * D,
                                         ln_q_b + l * D);

    gemm_proj<<<KVBLK + QBLK, 256, 0, stream>>>(
        kv_ln, q_ln, base, bk + l * D, bv + l * D, bq + l * D, Khbuf, Vhbuf,
        Qbuf);

    attn_mfma<<<B * H * NQT, 512, 0, stream>>>(Qbuf, Khbuf, Vhbuf, AObuf);

    dim3 gQ(D / 64, (QROWS + 63) / 64);
    gemm_mfma<2><<<gQ, 256, 0, stream>>>(AObuf, base + 3 * DD, bo + l * D,
                                         (void*)q_stream, q_stream, maskbuf,
                                         QROWS, D, D);

    ln_bf16<<<QROWS, 256, 0, stream>>>(q_stream, q_ln, ffn_g + l * D, ffn_b + l * D);
    dim3 gF1(FF / 64, (QROWS + 63) / 64);
    gemm_mfma<1><<<gF1, 256, 0, stream>>>(q_ln, base + 4 * DD, b1 + l * FF,
                                          (void*)H1buf, nullptr, nullptr,
                                          QROWS, FF, D);
    dim3 gF2(D / 64, (QROWS + 63) / 64);
    gemm_mfma<2><<<gF2, 256, 0, stream>>>(H1buf, base + 4 * DD + DFF,
                                          b2 + l * D, (void*)q_stream,
                                          q_stream, maskbuf, QROWS, D, FF);
  }

  head_kernel<<<KVROWS / 4, 256, 0, stream>>>(enc, q_stream, invbuf, head_W,
                                              head_b, out);
}

// Round 16
// 219.265 us; speedup vs baseline: 1.3202x; 1.0133x over previous
//
#include <hip/hip_runtime.h>
#include <cmath>

constexpr int B = 2, L = 4096, D = 256, H = 8, NC = 3;
constexpr int TOP_N = 8, R = 32;
constexpr int LS = 1000, LE = 3000;
constexpr int NL = 2;
constexpr int FF = 4 * D;                        // 1024
constexpr int Q_MAX = 2 * TOP_N * (2 * R + 1);   // 1040
constexpr int HD = D / H;                        // 32
constexpr int QROWS = B * Q_MAX;                 // 2080
constexpr int KVROWS = B * L;                    // 8192
constexpr int NQT = (Q_MAX + 31) / 32;           // 33 q-tiles of 32
constexpr int NREG = LE - LS;                    // 2000
constexpr int NSPLIT = 8;                        // split-K waves per block
constexpr int KCHUNK = L / NSPLIT;               // 512 keys per wave
constexpr int NT = KCHUNK / 32;                  // 16 iterations
constexpr int KVBLK = 8 * (KVROWS / 64);         // 1024 blocks (KV part)
constexpr int QBLK = 4 * ((QROWS + 63) / 64);    // 132 blocks (Q part)
constexpr int TRBLK = NL * 192;                  // 384 transpose blocks

typedef __attribute__((ext_vector_type(8))) short bf16x8;
typedef __attribute__((ext_vector_type(4))) float f32x4;
typedef __attribute__((ext_vector_type(4))) int i32x4;
typedef unsigned short u16;

union fr {
  bf16x8 h;
  i32x4 i;
};

__device__ __forceinline__ u16 f2bs(float f) {
  unsigned int u = __float_as_uint(f);
  unsigned int r = u + 0x7fffu + ((u >> 16) & 1u);
  return (u16)(r >> 16);
}
__device__ __forceinline__ float bs2f(u16 s) {
  return __uint_as_float(((unsigned int)s) << 16);
}
__device__ __forceinline__ float gelu_exact(float x) {
  return 0.5f * x * (1.f + erff(x * 0.70710678118654752440f));
}
__device__ __forceinline__ unsigned cvt_pk(float lo, float hi) {
  unsigned r;
  asm("v_cvt_pk_bf16_f32 %0, %1, %2" : "=v"(r) : "v"(lo), "v"(hi));
  return r;
}

#define GLL16(gsrc, ldst)                                                   \
  __builtin_amdgcn_global_load_lds(                                         \
      (const __attribute__((address_space(1))) unsigned int*)(gsrc),        \
      (__attribute__((address_space(3))) unsigned int*)(ldst), 16, 0, 0)

// ---------------------------------------------------------------------------
// Merged setup dispatch (256 threads/block):
//   blocks [0, KVROWS)            : dual-layer LayerNorm of enc -> kvl0/kvl1
//   blocks [KVROWS, KVROWS+TRBLK) : LDS-tiled weight transpose+bf16 -> WT
//   blocks [KVROWS+TRBLK, +B)     : vicinity selection (one block per batch)
//     also emits inv[b*L+pos] = global slot (or -1) for the merged head.
// ---------------------------------------------------------------------------
__global__ __launch_bounds__(256) void setup_kernel(
    const float* __restrict__ enc, const float* __restrict__ logits,
    const float* __restrict__ lnkvg, const float* __restrict__ lnkvb,
    const float* __restrict__ Wq_, const float* __restrict__ Wk_,
    const float* __restrict__ Wv_, const float* __restrict__ Wo_,
    const float* __restrict__ W1_, const float* __restrict__ W2_,
    u16* __restrict__ WT, u16* __restrict__ o0, u16* __restrict__ o1,
    int* __restrict__ idx_out, int* __restrict__ mask_out,
    int* __restrict__ inv_out) {
  int bid = blockIdx.x;
  int tid = threadIdx.x;
  const long DD = (long)D * D, DFF = (long)D * FF;
  const long LSTR = 4 * DD + 2 * DFF;

  if (bid < KVROWS) {
    long row = bid;
    float x = enc[row * D + tid];
    float s1 = x, s2 = x * x;
#pragma unroll
    for (int off = 32; off; off >>= 1) {
      s1 += __shfl_xor(s1, off, 64);
      s2 += __shfl_xor(s2, off, 64);
    }
    __shared__ float p1[4], p2[4];
    int w = tid >> 6;
    if ((tid & 63) == 0) { p1[w] = s1; p2[w] = s2; }
    __syncthreads();
    s1 = p1[0] + p1[1] + p1[2] + p1[3];
    s2 = p2[0] + p2[1] + p2[2] + p2[3];
    float mean = s1 * (1.f / D);
    float var = fmaxf(s2 * (1.f / D) - mean * mean, 0.f);
    float r = rsqrtf(var + 1e-5f);
    float xn = (x - mean) * r;
    o0[row * D + tid] = f2bs(xn * lnkvg[tid] + lnkvb[tid]);
    o1[row * D + tid] = f2bs(xn * lnkvg[D + tid] + lnkvb[D + tid]);
    return;
  }

  if (bid < KVROWS + TRBLK) {
    __shared__ u16 T[64][65];
    int t = bid - KVROWS;
    int l = t / 192, r = t % 192;
    const float* src;
    long dbase;
    int K_, N_, kt, nt;
    if (r < 64) {
      int which = r >> 4, sub = r & 15;
      kt = sub >> 2;
      nt = sub & 3;
      K_ = 256;
      N_ = 256;
      src = (which == 0 ? Wk_ : which == 1 ? Wv_ : which == 2 ? Wq_ : Wo_) +
            (long)l * DD;
      dbase = (long)l * LSTR + (long)which * DD;
    } else if (r < 128) {
      int sub = r - 64;
      kt = sub >> 4;
      nt = sub & 15;
      K_ = 256;
      N_ = 1024;
      src = W1_ + (long)l * DFF;
      dbase = (long)l * LSTR + 4 * DD;
    } else {
      int sub = r - 128;
      kt = sub >> 2;
      nt = sub & 3;
      K_ = 1024;
      N_ = 256;
      src = W2_ + (long)l * DFF;
      dbase = (long)l * LSTR + 4 * DD + DFF;
    }
    int k0 = kt * 64, n0 = nt * 64;
    {
      int kr = tid >> 2, c16 = (tid & 3) * 16;
      const float* sp = src + (long)(k0 + kr) * N_ + n0 + c16;
#pragma unroll
      for (int i = 0; i < 4; ++i) {
        float4 v = *reinterpret_cast<const float4*>(sp + 4 * i);
        T[kr][c16 + 4 * i + 0] = f2bs(v.x);
        T[kr][c16 + 4 * i + 1] = f2bs(v.y);
        T[kr][c16 + 4 * i + 2] = f2bs(v.z);
        T[kr][c16 + 4 * i + 3] = f2bs(v.w);
      }
    }
    __syncthreads();
    {
      int nr = tid >> 2, kc = (tid & 3) * 16;
      u16 tmp[16];
#pragma unroll
      for (int j = 0; j < 16; ++j) tmp[j] = T[kc + j][nr];
      u16* dp = WT + dbase + (long)(n0 + nr) * K_ + k0 + kc;
      *reinterpret_cast<bf16x8*>(dp) = *reinterpret_cast<const bf16x8*>(&tmp[0]);
      *reinterpret_cast<bf16x8*>(dp + 8) =
          *reinterpret_cast<const bf16x8*>(&tmp[8]);
    }
    return;
  }

  // ---- select part (one block per batch), 256 threads = 4 waves
  {
    int b = bid - KVROWS - TRBLK;
    int w = tid >> 6, lane = tid & 63;
    __shared__ float candv[4][8];
    __shared__ int candi[4][8];
    __shared__ int centers[2 * TOP_N];
    __shared__ unsigned present[L / 32];
    __shared__ int offs[128];
    __shared__ int wtot[2];

    float vd[8], va[8];
#pragma unroll
    for (int j = 0; j < 8; ++j) {
      int p = tid + j * 256;
      if (p < NREG) {
        const float* lg = logits + ((long)b * L + LS + p) * NC;
        float x0 = lg[0], x1 = lg[1], x2 = lg[2];
        float m = fmaxf(x0, fmaxf(x1, x2));
        float lse = m + logf(expf(x0 - m) + expf(x1 - m) + expf(x2 - m));
        vd[j] = x2 - lse;
        va[j] = x1 - lse;
      } else {
        vd[j] = -INFINITY;
        va[j] = -INFINITY;
      }
    }
    if (tid < 128) present[tid] = 0;
    for (int j = tid; j < L; j += 256) inv_out[(long)b * L + j] = -1;

    for (int sel = 0; sel < 2; ++sel) {
      float v[8];
#pragma unroll
      for (int j = 0; j < 8; ++j) v[j] = (sel == 0) ? vd[j] : va[j];
#pragma unroll
      for (int r = 0; r < TOP_N; ++r) {
        float mv = v[0];
        int mp = tid;
#pragma unroll
        for (int j = 1; j < 8; ++j) {
          int pj = tid + j * 256;
          if (v[j] > mv) { mv = v[j]; mp = pj; }
        }
#pragma unroll
        for (int off = 32; off; off >>= 1) {
          float ov = __shfl_xor(mv, off, 64);
          int oi = __shfl_xor(mp, off, 64);
          if (ov > mv || (ov == mv && oi < mp)) { mv = ov; mp = oi; }
        }
#pragma unroll
        for (int j = 0; j < 8; ++j)
          if (tid + j * 256 == mp) v[j] = -INFINITY;
        if (lane == 0) { candv[w][r] = mv; candi[w][r] = mp; }
      }
      __syncthreads();
      if (tid < 64) {
        float c = (tid < 32) ? candv[tid >> 3][tid & 7] : -INFINITY;
        int ci = (tid < 32) ? candi[tid >> 3][tid & 7] : 0x7fffffff;
#pragma unroll
        for (int r = 0; r < TOP_N; ++r) {
          float mv = c;
          int mi = ci;
#pragma unroll
          for (int off = 32; off; off >>= 1) {
            float ov = __shfl_xor(mv, off, 64);
            int oi = __shfl_xor(mi, off, 64);
            if (ov > mv || (ov == mv && oi < mi)) { mv = ov; mi = oi; }
          }
          if (ci == mi) c = -INFINITY;
          if (tid == 0) centers[sel * TOP_N + r] = LS + mi;
        }
      }
      __syncthreads();
    }

    for (int j = tid; j < Q_MAX; j += 256) {
      int c = centers[j / (2 * R + 1)];
      int off = j % (2 * R + 1) - R;
      int v2 = c + off;
      v2 = v2 < 0 ? 0 : (v2 > L - 1 ? L - 1 : v2);
      atomicOr(&present[v2 >> 5], 1u << (v2 & 31));
    }
    __syncthreads();

    int cnt = (tid < 128) ? __popc(present[tid]) : 0;
    if (tid < 128) {
      int x = cnt;
#pragma unroll
      for (int off = 1; off < 64; off <<= 1) {
        int o = __shfl_up(x, off, 64);
        if ((tid & 63) >= off) x += o;
      }
      if ((tid & 63) == 63) wtot[tid >> 6] = x;
      offs[tid] = x - cnt;
    }
    __syncthreads();
    int total = wtot[0] + wtot[1];
    if (tid < 128) {
      int base = offs[tid] + ((tid >= 64) ? wtot[0] : 0);
      unsigned mword = present[tid];
      while (mword) {
        int i = __ffs(mword) - 1;
        mword &= mword - 1;
        int pos = tid * 32 + i;
        idx_out[b * Q_MAX + base] = pos;
        mask_out[b * Q_MAX + base] = 1;
        inv_out[(long)b * L + pos] = b * Q_MAX + base;
        ++base;
      }
    }
    for (int j = total + tid; j < Q_MAX; j += 256) {
      idx_out[b * Q_MAX + j] = L;
      mask_out[b * Q_MAX + j] = 0;
    }
  }
}

// ---------------------------------------------------------------------------
// Gather + layer-0 Q-LayerNorm fused: writes fp32 q_stream AND bf16 q_ln.
// ---------------------------------------------------------------------------
__global__ __launch_bounds__(256) void gather_ln(
    const float* __restrict__ enc, const int* __restrict__ idx,
    float* __restrict__ q_stream, u16* __restrict__ q_ln,
    const float* __restrict__ gg, const float* __restrict__ bb) {
  int row = blockIdx.x;
  int b = row / Q_MAX;
  int p = idx[row];
  int tid = threadIdx.x;
  float x = 0.f;
  if (p < L) x = enc[((long)b * L + p) * D + tid];
  q_stream[(long)row * D + tid] = x;
  float s1 = x, s2 = x * x;
#pragma unroll
  for (int off = 32; off; off >>= 1) {
    s1 += __shfl_xor(s1, off, 64);
    s2 += __shfl_xor(s2, off, 64);
  }
  __shared__ float p1[4], p2[4];
  int w = tid >> 6;
  if ((tid & 63) == 0) { p1[w] = s1; p2[w] = s2; }
  __syncthreads();
  s1 = p1[0] + p1[1] + p1[2] + p1[3];
  s2 = p2[0] + p2[1] + p2[2] + p2[3];
  float mean = s1 * (1.f / D);
  float var = fmaxf(s2 * (1.f / D) - mean * mean, 0.f);
  float r = rsqrtf(var + 1e-5f);
  q_ln[(long)row * D + tid] = f2bs((x - mean) * r * gg[tid] + bb[tid]);
}

// ---------------------------------------------------------------------------
__global__ __launch_bounds__(256) void ln_bf16(
    const float* __restrict__ in, u16* __restrict__ out,
    const float* __restrict__ gg, const float* __restrict__ bb) {
  long row = blockIdx.x;
  int tid = threadIdx.x;
  float x = in[row * D + tid];
  float s1 = x, s2 = x * x;
#pragma unroll
  for (int off = 32; off; off >>= 1) {
    s1 += __shfl_xor(s1, off, 64);
    s2 += __shfl_xor(s2, off, 64);
  }
  __shared__ float p1[4], p2[4];
  int w = tid >> 6;
  if ((tid & 63) == 0) { p1[w] = s1; p2[w] = s2; }
  __syncthreads();
  s1 = p1[0] + p1[1] + p1[2] + p1[3];
  s2 = p2[0] + p2[1] + p2[2] + p2[3];
  float mean = s1 * (1.f / D);
  float var = fmaxf(s2 * (1.f / D) - mean * mean, 0.f);
  float r = rsqrtf(var + 1e-5f);
  out[row * D + tid] = f2bs((x - mean) * r * gg[tid] + bb[tid]);
}

// ---------------------------------------------------------------------------
// bf16 MFMA GEMM (64x64 tile, BK=32, 4 waves).
// EPI 1: gelu->bf16; 2: resid+mask->f32
// ---------------------------------------------------------------------------
template <int EPI>
__global__ __launch_bounds__(256) void gemm_mfma(
    const u16* __restrict__ A, const u16* __restrict__ BT,
    const float* __restrict__ bias, void* __restrict__ Cv,
    const float* __restrict__ resid, const int* __restrict__ mask, int M,
    int N, int K) {
  __shared__ short As[64][40];
  __shared__ short Bs[64][40];
  int bm = blockIdx.y * 64, bn = blockIdx.x * 64;
  int tid = threadIdx.x;
  int lane = tid & 63, w = tid >> 6;
  int g = lane >> 4, li = lane & 15;
  int wr = w >> 1, wc = w & 1;
  f32x4 acc[2][2] = {};

  int srow = tid >> 2, skc = (tid & 3) * 8;
  for (int k0 = 0; k0 < K; k0 += 32) {
    {
      int grow = bm + srow;
      bf16x8 av = {};
      if (grow < M)
        av = *reinterpret_cast<const bf16x8*>(A + (long)grow * K + k0 + skc);
      *reinterpret_cast<bf16x8*>(&As[srow][skc]) = av;
      bf16x8 bv = *reinterpret_cast<const bf16x8*>(
          BT + (long)(bn + srow) * K + k0 + skc);
      *reinterpret_cast<bf16x8*>(&Bs[srow][skc]) = bv;
    }
    __syncthreads();
    bf16x8 a0 = *reinterpret_cast<const bf16x8*>(&As[wr * 32 + li][g * 8]);
    bf16x8 a1 = *reinterpret_cast<const bf16x8*>(&As[wr * 32 + 16 + li][g * 8]);
    bf16x8 b0 = *reinterpret_cast<const bf16x8*>(&Bs[wc * 32 + li][g * 8]);
    bf16x8 b1 = *reinterpret_cast<const bf16x8*>(&Bs[wc * 32 + 16 + li][g * 8]);
    acc[0][0] = __builtin_amdgcn_mfma_f32_16x16x32_bf16(a0, b0, acc[0][0], 0, 0, 0);
    acc[0][1] = __builtin_amdgcn_mfma_f32_16x16x32_bf16(a0, b1, acc[0][1], 0, 0, 0);
    acc[1][0] = __builtin_amdgcn_mfma_f32_16x16x32_bf16(a1, b0, acc[1][0], 0, 0, 0);
    acc[1][1] = __builtin_amdgcn_mfma_f32_16x16x32_bf16(a1, b1, acc[1][1], 0, 0, 0);
    __syncthreads();
  }

#pragma unroll
  for (int mr = 0; mr < 2; ++mr)
#pragma unroll
    for (int nr = 0; nr < 2; ++nr)
#pragma unroll
      for (int r = 0; r < 4; ++r) {
        int row = bm + wr * 32 + mr * 16 + g * 4 + r;
        int col = bn + wc * 32 + nr * 16 + li;
        if (row >= M) continue;
        float v = acc[mr][nr][r] + bias[col];
        if (EPI == 1) v = gelu_exact(v);
        if (EPI == 2) {
          v += resid[(long)row * N + col];
          v = mask[row] ? v : 0.f;
          ((float*)Cv)[(long)row * N + col] = v;
        } else {
          ((u16*)Cv)[(long)row * N + col] = f2bs(v);
        }
      }
}

// ---------------------------------------------------------------------------
// Combined projection dispatch (R12-proven): KV tiles + Q tiles, bf16 A.
// ---------------------------------------------------------------------------
__global__ __launch_bounds__(256) void gemm_proj(
    const u16* __restrict__ Akv, const u16* __restrict__ Aq,
    const u16* __restrict__ WTbase, const float* __restrict__ biasK,
    const float* __restrict__ biasV, const float* __restrict__ biasQ,
    u16* __restrict__ Kh, u16* __restrict__ Vh, u16* __restrict__ Qb) {
  __shared__ short As[64][40];
  __shared__ short Bs[64][40];
  __shared__ u16 Ct[64][72];
  int bid = blockIdx.x;
  int tid = threadIdx.x;
  int lane = tid & 63, w = tid >> 6;
  int g = lane >> 4, li = lane & 15;
  int wr = w >> 1, wc = w & 1;
  f32x4 acc[2][2] = {};
  const long DD = (long)D * D;

  bool isKV = bid < KVBLK;
  int bm, bn, M;
  const u16* A;
  const u16* BT;
  if (isKV) {
    bn = (bid & 7) * 64;
    bm = (bid >> 3) * 64;
    M = KVROWS;
    A = Akv;
    BT = WTbase;
  } else {
    int qb = bid - KVBLK;
    bn = (qb & 3) * 64;
    bm = (qb >> 2) * 64;
    M = QROWS;
    A = Aq;
    BT = WTbase + 2 * DD;
  }

  int srow = tid >> 2, skc = (tid & 3) * 8;
  for (int k0 = 0; k0 < D; k0 += 32) {
    {
      int grow = bm + srow;
      bf16x8 av = {};
      if (grow < M)
        av = *reinterpret_cast<const bf16x8*>(A + (long)grow * D + k0 + skc);
      *reinterpret_cast<bf16x8*>(&As[srow][skc]) = av;
      bf16x8 bv = *reinterpret_cast<const bf16x8*>(
          BT + (long)(bn + srow) * D + k0 + skc);
      *reinterpret_cast<bf16x8*>(&Bs[srow][skc]) = bv;
    }
    __syncthreads();
    bf16x8 a0 = *reinterpret_cast<const bf16x8*>(&As[wr * 32 + li][g * 8]);
    bf16x8 a1 = *reinterpret_cast<const bf16x8*>(&As[wr * 32 + 16 + li][g * 8]);
    bf16x8 b0 = *reinterpret_cast<const bf16x8*>(&Bs[wc * 32 + li][g * 8]);
    bf16x8 b1 = *reinterpret_cast<const bf16x8*>(&Bs[wc * 32 + 16 + li][g * 8]);
    acc[0][0] = __builtin_amdgcn_mfma_f32_16x16x32_bf16(a0, b0, acc[0][0], 0, 0, 0);
    acc[0][1] = __builtin_amdgcn_mfma_f32_16x16x32_bf16(a0, b1, acc[0][1], 0, 0, 0);
    acc[1][0] = __builtin_amdgcn_mfma_f32_16x16x32_bf16(a1, b0, acc[1][0], 0, 0, 0);
    acc[1][1] = __builtin_amdgcn_mfma_f32_16x16x32_bf16(a1, b1, acc[1][1], 0, 0, 0);
    __syncthreads();
  }

  if (!isKV) {
#pragma unroll
    for (int mr = 0; mr < 2; ++mr)
#pragma unroll
      for (int nr = 0; nr < 2; ++nr)
#pragma unroll
        for (int r = 0; r < 4; ++r) {
          int row = bm + wr * 32 + mr * 16 + g * 4 + r;
          int col = bn + wc * 32 + nr * 16 + li;
          if (row >= M) continue;
          Qb[(long)row * D + col] = f2bs(acc[mr][nr][r] + biasQ[col]);
        }
  } else if (bn < 256) {
#pragma unroll
    for (int mr = 0; mr < 2; ++mr)
#pragma unroll
      for (int nr = 0; nr < 2; ++nr)
#pragma unroll
        for (int r = 0; r < 4; ++r) {
          int rowL = wr * 32 + mr * 16 + g * 4 + r;
          int colL = wc * 32 + nr * 16 + li;
          Ct[rowL][colL] = f2bs(acc[mr][nr][r] + biasK[bn + colL]);
        }
    __syncthreads();
#pragma unroll
    for (int p = 0; p < 2; ++p) {
      int rowL = (tid >> 3) + p * 32;
      int c8 = (tid & 7) * 8;
      int grow = bm + rowL;
      int b2 = grow >> 12, key = grow & (L - 1);
      int gcol = bn + c8;
      int hh = gcol >> 5, dd = gcol & (HD - 1);
      int cst = (dd >> 3) ^ ((key >> 1) & 3);
      u16* dst = Kh + (((long)(b2 * H + hh) * L + key) * 32 + (cst << 3));
      *reinterpret_cast<bf16x8*>(dst) =
          *reinterpret_cast<const bf16x8*>(&Ct[rowL][c8]);
    }
  } else {
    int vbn = bn - 256;
#pragma unroll
    for (int mr = 0; mr < 2; ++mr)
#pragma unroll
      for (int nr = 0; nr < 2; ++nr)
#pragma unroll
        for (int r = 0; r < 4; ++r) {
          int rowL = wr * 32 + mr * 16 + g * 4 + r;
          int colL = wc * 32 + nr * 16 + li;
          Ct[colL][rowL] = f2bs(acc[mr][nr][r] + biasV[vbn + colL]);
        }
    __syncthreads();
    int b2 = bm >> 12;
#pragma unroll
    for (int p = 0; p < 2; ++p) {
      int colL = (tid >> 3) + p * 32;
      int rem = tid & 7;
      int kb = rem >> 2, k8 = (rem & 3) * 8;
      int gcol = vbn + colL;
      int hh = gcol >> 5, dd = gcol & (HD - 1);
      int kb32 = ((bm & (L - 1)) >> 5) + kb;
      int j = (k8 >> 2) ^ ((dd >> 1) & 6);
      u16* dst = Vh + (((long)(b2 * H + hh) * (L / 32) + kb32) * 1024 +
                       dd * 32 + (j << 2));
      *reinterpret_cast<bf16x8*>(dst) =
          *reinterpret_cast<const bf16x8*>(&Ct[colL][kb * 32 + k8]);
    }
  }
}

// ---------------------------------------------------------------------------
// Fused flash attention with zero-extra-LDS software pipelining (1.5-buffer):
// 512 threads = 8 split-K waves per (b,h,32-q tile). Per iteration the K half
// of the wave-private buffer is reloaded for tile t+1 right after K_t's
// fragments are consumed (before QK MFMAs), and the V half after V_t's
// fragments are consumed (before PV MFMAs). Counted vmcnt: top wait vmcnt(2)
// (K_t ready), mid wait vmcnt(2) (V_t ready; vmcnt(0) on last iter). Loads
// are issued a full iteration ahead. Kh/Vh XOR-swizzled in global.
// ---------------------------------------------------------------------------
constexpr int POOLSZ = NSPLIT * 32 * 33 * 4 + NSPLIT * 32 * 4;  // 34816

__global__ __launch_bounds__(512) void attn_mfma(
    const u16* __restrict__ Qb, const u16* __restrict__ Kh,
    const u16* __restrict__ Vh, u16* __restrict__ AO) {
  __shared__ alignas(16) char pool[POOLSZ];
  int i = blockIdx.x;
  int xcd = i & 7, slot = i >> 3;          // 66 slots per XCD
  int bh = (xcd << 1) | (slot >= NQT ? 1 : 0);
  int qt = (slot >= NQT) ? slot - NQT : slot;
  int h = bh & 7;
  int b = bh >> 3;
  int tid = threadIdx.x, w = tid >> 6, lane = tid & 63;
  int g = lane >> 4, li = lane & 15;

  fr qf0, qf1;
  {
    const float QSC = 0.25509836048f;  // (1/sqrt(32)) * log2(e)
#pragma unroll
    for (int qb = 0; qb < 2; ++qb) {
      int qrow = qt * 32 + qb * 16 + li;
      if (qrow >= Q_MAX) qrow = Q_MAX - 1;
      bf16x8 raw = *reinterpret_cast<const bf16x8*>(
          Qb + ((long)(b * Q_MAX + qrow)) * D + h * HD + g * 8);
      fr& qf = qb ? qf1 : qf0;
#pragma unroll
      for (int j = 0; j < 4; ++j)
        qf.i[j] = (int)cvt_pk(bs2f((u16)raw[2 * j]) * QSC,
                              bs2f((u16)raw[2 * j + 1]) * QSC);
    }
  }

  f32x4 acc00 = {}, acc01 = {}, acc10 = {}, acc11 = {};
  float den0 = 0.f, den1 = 0.f;
  const f32x4 z = {};

  const u16* kbase = Kh + ((long)(b * H + h) * L) * HD;
  const u16* vbase = Vh + ((long)(b * H + h) * L) * HD;
  int kstart = w * KCHUNK;
  char* wbase = pool + w * 4096;  // wave-private single buffer (2KB K + 2KB V)

  int s_li = (li >> 1) & 3;
  int t_li = (li >> 1) & 6;
  int kof0 = li * 32 + ((g ^ s_li) << 3);
  int kof1 = (16 + li) * 32 + ((g ^ s_li) << 3);
  int va0o = li * 32 + ((g ^ t_li) << 2);
  int vb0o = li * 32 + (((4 + g) ^ t_li) << 2);
  int va1o = (16 + li) * 32 + ((g ^ t_li) << 2);
  int vb1o = (16 + li) * 32 + (((4 + g) ^ t_li) << 2);

  // prologue: issue K0 (2 loads) then V0 (2 loads)
  {
    const u16* ks = kbase + (long)kstart * HD + lane * 8;
    const u16* vs = vbase + (long)kstart * HD + lane * 8;
    u16* lk = (u16*)wbase;
    GLL16(ks, lk);
    GLL16(ks + 512, lk + 512);
    GLL16(vs, lk + 1024);
    GLL16(vs + 512, lk + 1536);
  }

  for (int t = 0; t < NT; ++t) {
    const u16* kl = (const u16*)wbase;
    const u16* vl = kl + 1024;

    // K_t ready (oldest 2 of 4 outstanding); V_t still in flight
    asm volatile("s_waitcnt vmcnt(2)" ::: "memory");
    __builtin_amdgcn_sched_barrier(0);
    fr kf0, kf1;
    kf0.h = *reinterpret_cast<const bf16x8*>(kl + kof0);
    kf1.h = *reinterpret_cast<const bf16x8*>(kl + kof1);
    // pin K fragments (ds_reads must complete before K half is overwritten)
    asm volatile("" ::"v"(kf0.i[0]), "v"(kf0.i[1]), "v"(kf0.i[2]),
                 "v"(kf0.i[3]), "v"(kf1.i[0]), "v"(kf1.i[1]), "v"(kf1.i[2]),
                 "v"(kf1.i[3]));
    asm volatile("s_waitcnt lgkmcnt(0)" ::: "memory");
    __builtin_amdgcn_sched_barrier(0);
    if (t + 1 < NT) {
      const u16* ks = kbase + (long)(kstart + (t + 1) * 32) * HD + lane * 8;
      u16* lk = (u16*)wbase;
      GLL16(ks, lk);
      GLL16(ks + 512, lk + 512);
    }

    f32x4 s00 = __builtin_amdgcn_mfma_f32_16x16x32_bf16(kf0.h, qf0.h, z, 0, 0, 0);
    f32x4 s10 = __builtin_amdgcn_mfma_f32_16x16x32_bf16(kf1.h, qf0.h, z, 0, 0, 0);
    f32x4 s01 = __builtin_amdgcn_mfma_f32_16x16x32_bf16(kf0.h, qf1.h, z, 0, 0, 0);
    f32x4 s11 = __builtin_amdgcn_mfma_f32_16x16x32_bf16(kf1.h, qf1.h, z, 0, 0, 0);

    float p00[4], p10[4], p01[4], p11[4];
#pragma unroll
    for (int r = 0; r < 4; ++r) {
      p00[r] = exp2f(s00[r]);
      p10[r] = exp2f(s10[r]);
      p01[r] = exp2f(s01[r]);
      p11[r] = exp2f(s11[r]);
      den0 += p00[r] + p10[r];
      den1 += p01[r] + p11[r];
    }
    fr pf0, pf1;
    pf0.i[0] = (int)cvt_pk(p00[0], p00[1]);
    pf0.i[1] = (int)cvt_pk(p00[2], p00[3]);
    pf0.i[2] = (int)cvt_pk(p10[0], p10[1]);
    pf0.i[3] = (int)cvt_pk(p10[2], p10[3]);
    pf1.i[0] = (int)cvt_pk(p01[0], p01[1]);
    pf1.i[1] = (int)cvt_pk(p01[2], p01[3]);
    pf1.i[2] = (int)cvt_pk(p11[0], p11[1]);
    pf1.i[3] = (int)cvt_pk(p11[2], p11[3]);

    // V_t ready: oldest of {V_t(2), K_{t+1}(2)} -> vmcnt(2); last iter: 0
    if (t + 1 < NT)
      asm volatile("s_waitcnt vmcnt(2)" ::: "memory");
    else
      asm volatile("s_waitcnt vmcnt(0)" ::: "memory");
    __builtin_amdgcn_sched_barrier(0);
    uint2 va0 = *reinterpret_cast<const uint2*>(vl + va0o);
    uint2 vb0 = *reinterpret_cast<const uint2*>(vl + vb0o);
    uint2 va1 = *reinterpret_cast<const uint2*>(vl + va1o);
    uint2 vb1 = *reinterpret_cast<const uint2*>(vl + vb1o);
    // pin V fragments before V half is overwritten
    asm volatile("" ::"v"(va0.x), "v"(va0.y), "v"(vb0.x), "v"(vb0.y),
                 "v"(va1.x), "v"(va1.y), "v"(vb1.x), "v"(vb1.y));
    asm volatile("s_waitcnt lgkmcnt(0)" ::: "memory");
    __builtin_amdgcn_sched_barrier(0);
    if (t + 1 < NT) {
      const u16* vs = vbase + (long)(kstart + (t + 1) * 32) * HD + lane * 8;
      u16* lk = (u16*)wbase;
      GLL16(vs, lk + 1024);
      GLL16(vs + 512, lk + 1536);
    }

    fr v0, v1;
    v0.i = (i32x4){(int)va0.x, (int)va0.y, (int)vb0.x, (int)vb0.y};
    v1.i = (i32x4){(int)va1.x, (int)va1.y, (int)vb1.x, (int)vb1.y};
    acc00 = __builtin_amdgcn_mfma_f32_16x16x32_bf16(v0.h, pf0.h, acc00, 0, 0, 0);
    acc01 = __builtin_amdgcn_mfma_f32_16x16x32_bf16(v0.h, pf1.h, acc01, 0, 0, 0);
    acc10 = __builtin_amdgcn_mfma_f32_16x16x32_bf16(v1.h, pf0.h, acc10, 0, 0, 0);
    acc11 = __builtin_amdgcn_mfma_f32_16x16x32_bf16(v1.h, pf1.h, acc11, 0, 0, 0);
  }

  den0 += __shfl_xor(den0, 16, 64);
  den0 += __shfl_xor(den0, 32, 64);
  den1 += __shfl_xor(den1, 16, 64);
  den1 += __shfl_xor(den1, 32, 64);

  __syncthreads();
  float(*accs)[32][33] = (float(*)[32][33])pool;
  float(*dsh)[32] = (float(*)[32])(pool + NSPLIT * 32 * 33 * 4);
#pragma unroll
  for (int r = 0; r < 4; ++r) {
    accs[w][g * 4 + r][li] = acc00[r];
    accs[w][g * 4 + r][16 + li] = acc01[r];
    accs[w][16 + g * 4 + r][li] = acc10[r];
    accs[w][16 + g * 4 + r][16 + li] = acc11[r];
  }
  if (g == 0) {
    dsh[w][li] = den0;
    dsh[w][16 + li] = den1;
  }
  __syncthreads();

  int q = tid >> 4, dp = tid & 15;
  float Den = 0.f, o0 = 0.f, o1 = 0.f;
#pragma unroll
  for (int ww = 0; ww < NSPLIT; ++ww) {
    Den += dsh[ww][q];
    o0 += accs[ww][2 * dp][q];
    o1 += accs[ww][2 * dp + 1][q];
  }
  float inv = 1.f / Den;
  int qrow = qt * 32 + q;
  if (qrow < Q_MAX) {
    unsigned pk = cvt_pk(o0 * inv, o1 * inv);
    *reinterpret_cast<unsigned*>(
        AO + ((long)(b * Q_MAX + qrow)) * D + h * HD + 2 * dp) = pk;
  }
}

// ---------------------------------------------------------------------------
// Merged head: for each (b,pos) row, input = q_stream[inv] if selected
// (refined stream), else enc row.
// ---------------------------------------------------------------------------
__global__ __launch_bounds__(256) void head_kernel(
    const float* __restrict__ enc, const float* __restrict__ q_stream,
    const int* __restrict__ inv, const float* __restrict__ hW,
    const float* __restrict__ hb, float* __restrict__ out) {
  int row = blockIdx.x * 4 + (threadIdx.x >> 6);
  int lane = threadIdx.x & 63;
  int slot = inv[row];
  const float* src =
      (slot >= 0) ? (q_stream + (long)slot * D) : (enc + (long)row * D);
  const float4 a = *reinterpret_cast<const float4*>(src + lane * 4);
  float c0 = 0.f, c1 = 0.f, c2 = 0.f;
  const float av[4] = {a.x, a.y, a.z, a.w};
#pragma unroll
  for (int i = 0; i < 4; ++i) {
    int k = lane * 4 + i;
    c0 += av[i] * hW[k * 3];
    c1 += av[i] * hW[k * 3 + 1];
    c2 += av[i] * hW[k * 3 + 2];
  }
#pragma unroll
  for (int off = 32; off; off >>= 1) {
    c0 += __shfl_down(c0, off, 64);
    c1 += __shfl_down(c1, off, 64);
    c2 += __shfl_down(c2, off, 64);
  }
  if (lane == 0) {
    out[(long)row * 3] = c0 + hb[0];
    out[(long)row * 3 + 1] = c1 + hb[1];
    out[(long)row * 3 + 2] = c2 + hb[2];
  }
}

// ---------------------------------------------------------------------------
extern "C" void kernel_launch(void* const* d_in, const int* in_sizes, int n_in,
                              void* d_out, int out_size, void* d_ws,
                              size_t ws_size, hipStream_t stream) {
  const float* enc = (const float*)d_in[0];
  const float* clog = (const float*)d_in[1];
  const float* ln_q_g = (const float*)d_in[2];
  const float* ln_q_b = (const float*)d_in[3];
  const float* ln_kv_g = (const float*)d_in[4];
  const float* ln_kv_b = (const float*)d_in[5];
  const float* Wq = (const float*)d_in[6];
  const float* bq = (const float*)d_in[7];
  const float* Wk = (const float*)d_in[8];
  const float* bk = (const float*)d_in[9];
  const float* Wv = (const float*)d_in[10];
  const float* bv = (const float*)d_in[11];
  const float* Wo = (const float*)d_in[12];
  const float* bo = (const float*)d_in[13];
  const float* ffn_g = (const float*)d_in[14];
  const float* ffn_b = (const float*)d_in[15];
  const float* W1 = (const float*)d_in[16];
  const float* b1 = (const float*)d_in[17];
  const float* W2 = (const float*)d_in[18];
  const float* b2 = (const float*)d_in[19];
  const float* head_W = (const float*)d_in[20];
  const float* head_b = (const float*)d_in[21];
  float* out = (float*)d_out;

  char* ws = (char*)d_ws;
  float* q_stream = (float*)ws;            ws += (long)QROWS * D * 4;
  u16* kvl0 = (u16*)ws;                    ws += (long)KVROWS * D * 2;
  u16* kvl1 = (u16*)ws;                    ws += (long)KVROWS * D * 2;
  u16* Khbuf = (u16*)ws;                   ws += (long)B * H * L * HD * 2;
  u16* Vhbuf = (u16*)ws;                   ws += (long)B * H * L * HD * 2;
  u16* q_ln = (u16*)ws;                    ws += (long)QROWS * D * 2;
  u16* Qbuf = (u16*)ws;                    ws += (long)QROWS * D * 2;
  u16* AObuf = (u16*)ws;                   ws += (long)QROWS * D * 2;
  u16* H1buf = (u16*)ws;                   ws += (long)QROWS * FF * 2;
  u16* WT = (u16*)ws;                      ws += (long)NL * (4 * D * D + 2 * D * FF) * 2;
  int* idxbuf = (int*)ws;                  ws += QROWS * 4;
  int* maskbuf = (int*)ws;                 ws += QROWS * 4;
  int* invbuf = (int*)ws;                  ws += (long)B * L * 4;

  const long DD = (long)D * D, DFF = (long)D * FF;
  const long LSTR = 4 * DD + 2 * DFF;

  setup_kernel<<<KVROWS + TRBLK + B, 256, 0, stream>>>(
      enc, clog, ln_kv_g, ln_kv_b, Wq, Wk, Wv, Wo, W1, W2, WT, kvl0, kvl1,
      idxbuf, maskbuf, invbuf);
  gather_ln<<<QROWS, 256, 0, stream>>>(enc, idxbuf, q_stream, q_ln, ln_q_g,
                                       ln_q_b);

  for (int l = 0; l < NL; ++l) {
    u16* base = WT + l * LSTR;
    u16* kv_ln = (l == 0) ? kvl0 : kvl1;

    if (l > 0)
      ln_bf16<<<QROWS, 256, 0, stream>>>(q_stream, q_ln, ln_q_g + l * D,
                                         ln_q_b + l * D);

    gemm_proj<<<KVBLK + QBLK, 256, 0, stream>>>(
        kv_ln, q_ln, base, bk + l * D, bv + l * D, bq + l * D, Khbuf, Vhbuf,
        Qbuf);

    attn_mfma<<<B * H * NQT, 512, 0, stream>>>(Qbuf, Khbuf, Vhbuf, AObuf);

    dim3 gQ(D / 64, (QROWS + 63) / 64);
    gemm_mfma<2><<<gQ, 256, 0, stream>>>(AObuf, base + 3 * DD, bo + l * D,
                                         (void*)q_stream, q_stream, maskbuf,
                                         QROWS, D, D);

    ln_bf16<<<QROWS, 256, 0, stream>>>(q_stream, q_ln, ffn_g + l * D, ffn_b + l * D);
    dim3 gF1(FF / 64, (QROWS + 63) / 64);
    gemm_mfma<1><<<gF1, 256, 0, stream>>>(q_ln, base + 4 * DD, b1 + l * FF,
                                          (void*)H1buf, nullptr, nullptr,
                                          QROWS, FF, D);
    dim3 gF2(D / 64, (QROWS + 63) / 64);
    gemm_mfma<2><<<gF2, 256, 0, stream>>>(H1buf, base + 4 * DD + DFF,
                                          b2 + l * D, (void*)q_stream,
                                          q_stream, maskbuf, QROWS, D, FF);
  }

  head_kernel<<<KVROWS / 4, 256, 0, stream>>>(enc, q_stream, invbuf, head_W,
                                              head_b, out);
}

// Round 17
// 216.668 us; speedup vs baseline: 1.3361x; 1.0120x over previous
//
#include <hip/hip_runtime.h>
#include <cmath>

constexpr int B = 2, L = 4096, D = 256, H = 8, NC = 3;
constexpr int TOP_N = 8, R = 32;
constexpr int LS = 1000, LE = 3000;
constexpr int NL = 2;
constexpr int FF = 4 * D;                        // 1024
constexpr int Q_MAX = 2 * TOP_N * (2 * R + 1);   // 1040
constexpr int HD = D / H;                        // 32
constexpr int QROWS = B * Q_MAX;                 // 2080
constexpr int KVROWS = B * L;                    // 8192
constexpr int NQT = (Q_MAX + 31) / 32;           // 33 q-tiles of 32
constexpr int NREG = LE - LS;                    // 2000
constexpr int NSPLIT = 8;                        // split-K waves per block
constexpr int KCHUNK = L / NSPLIT;               // 512 keys per wave
constexpr int NT = KCHUNK / 32;                  // 16 iterations
constexpr int KVBLK = 8 * (KVROWS / 64);         // 1024 blocks (KV part)
constexpr int QBLK = 4 * ((QROWS + 63) / 64);    // 132 blocks (Q part)
constexpr int TRBLK = NL * 192;                  // 384 transpose blocks
constexpr int MRB32 = QROWS / 32;                // 65 row-blocks of 32

typedef __attribute__((ext_vector_type(8))) short bf16x8;
typedef __attribute__((ext_vector_type(4))) float f32x4;
typedef __attribute__((ext_vector_type(4))) int i32x4;
typedef unsigned short u16;

union fr {
  bf16x8 h;
  i32x4 i;
};

__device__ __forceinline__ u16 f2bs(float f) {
  unsigned int u = __float_as_uint(f);
  unsigned int r = u + 0x7fffu + ((u >> 16) & 1u);
  return (u16)(r >> 16);
}
__device__ __forceinline__ float bs2f(u16 s) {
  return __uint_as_float(((unsigned int)s) << 16);
}
__device__ __forceinline__ float gelu_exact(float x) {
  return 0.5f * x * (1.f + erff(x * 0.70710678118654752440f));
}
__device__ __forceinline__ unsigned cvt_pk(float lo, float hi) {
  unsigned r;
  asm("v_cvt_pk_bf16_f32 %0, %1, %2" : "=v"(r) : "v"(lo), "v"(hi));
  return r;
}

#define GLL16(gsrc, ldst)                                                   \
  __builtin_amdgcn_global_load_lds(                                         \
      (const __attribute__((address_space(1))) unsigned int*)(gsrc),        \
      (__attribute__((address_space(3))) unsigned int*)(ldst), 16, 0, 0)

// ---------------------------------------------------------------------------
// Merged setup dispatch (256 threads/block):
//   blocks [0, KVROWS)            : dual-layer LayerNorm of enc -> kvl0/kvl1
//   blocks [KVROWS, KVROWS+TRBLK) : LDS-tiled weight transpose+bf16 -> WT
//   blocks [KVROWS+TRBLK, +B)     : vicinity selection (one block per batch)
//     also emits inv[b*L+pos] = global slot (or -1) for the merged head.
// ---------------------------------------------------------------------------
__global__ __launch_bounds__(256) void setup_kernel(
    const float* __restrict__ enc, const float* __restrict__ logits,
    const float* __restrict__ lnkvg, const float* __restrict__ lnkvb,
    const float* __restrict__ Wq_, const float* __restrict__ Wk_,
    const float* __restrict__ Wv_, const float* __restrict__ Wo_,
    const float* __restrict__ W1_, const float* __restrict__ W2_,
    u16* __restrict__ WT, u16* __restrict__ o0, u16* __restrict__ o1,
    int* __restrict__ idx_out, int* __restrict__ mask_out,
    int* __restrict__ inv_out) {
  int bid = blockIdx.x;
  int tid = threadIdx.x;
  const long DD = (long)D * D, DFF = (long)D * FF;
  const long LSTR = 4 * DD + 2 * DFF;

  if (bid < KVROWS) {
    long row = bid;
    float x = enc[row * D + tid];
    float s1 = x, s2 = x * x;
#pragma unroll
    for (int off = 32; off; off >>= 1) {
      s1 += __shfl_xor(s1, off, 64);
      s2 += __shfl_xor(s2, off, 64);
    }
    __shared__ float p1[4], p2[4];
    int w = tid >> 6;
    if ((tid & 63) == 0) { p1[w] = s1; p2[w] = s2; }
    __syncthreads();
    s1 = p1[0] + p1[1] + p1[2] + p1[3];
    s2 = p2[0] + p2[1] + p2[2] + p2[3];
    float mean = s1 * (1.f / D);
    float var = fmaxf(s2 * (1.f / D) - mean * mean, 0.f);
    float r = rsqrtf(var + 1e-5f);
    float xn = (x - mean) * r;
    o0[row * D + tid] = f2bs(xn * lnkvg[tid] + lnkvb[tid]);
    o1[row * D + tid] = f2bs(xn * lnkvg[D + tid] + lnkvb[D + tid]);
    return;
  }

  if (bid < KVROWS + TRBLK) {
    __shared__ u16 T[64][65];
    int t = bid - KVROWS;
    int l = t / 192, r = t % 192;
    const float* src;
    long dbase;
    int K_, N_, kt, nt;
    if (r < 64) {
      int which = r >> 4, sub = r & 15;
      kt = sub >> 2;
      nt = sub & 3;
      K_ = 256;
      N_ = 256;
      src = (which == 0 ? Wk_ : which == 1 ? Wv_ : which == 2 ? Wq_ : Wo_) +
            (long)l * DD;
      dbase = (long)l * LSTR + (long)which * DD;
    } else if (r < 128) {
      int sub = r - 64;
      kt = sub >> 4;
      nt = sub & 15;
      K_ = 256;
      N_ = 1024;
      src = W1_ + (long)l * DFF;
      dbase = (long)l * LSTR + 4 * DD;
    } else {
      int sub = r - 128;
      kt = sub >> 2;
      nt = sub & 3;
      K_ = 1024;
      N_ = 256;
      src = W2_ + (long)l * DFF;
      dbase = (long)l * LSTR + 4 * DD + DFF;
    }
    int k0 = kt * 64, n0 = nt * 64;
    {
      int kr = tid >> 2, c16 = (tid & 3) * 16;
      const float* sp = src + (long)(k0 + kr) * N_ + n0 + c16;
#pragma unroll
      for (int i = 0; i < 4; ++i) {
        float4 v = *reinterpret_cast<const float4*>(sp + 4 * i);
        T[kr][c16 + 4 * i + 0] = f2bs(v.x);
        T[kr][c16 + 4 * i + 1] = f2bs(v.y);
        T[kr][c16 + 4 * i + 2] = f2bs(v.z);
        T[kr][c16 + 4 * i + 3] = f2bs(v.w);
      }
    }
    __syncthreads();
    {
      int nr = tid >> 2, kc = (tid & 3) * 16;
      u16 tmp[16];
#pragma unroll
      for (int j = 0; j < 16; ++j) tmp[j] = T[kc + j][nr];
      u16* dp = WT + dbase + (long)(n0 + nr) * K_ + k0 + kc;
      *reinterpret_cast<bf16x8*>(dp) = *reinterpret_cast<const bf16x8*>(&tmp[0]);
      *reinterpret_cast<bf16x8*>(dp + 8) =
          *reinterpret_cast<const bf16x8*>(&tmp[8]);
    }
    return;
  }

  // ---- select part (one block per batch), 256 threads = 4 waves
  {
    int b = bid - KVROWS - TRBLK;
    int w = tid >> 6, lane = tid & 63;
    __shared__ float candv[4][8];
    __shared__ int candi[4][8];
    __shared__ int centers[2 * TOP_N];
    __shared__ unsigned present[L / 32];
    __shared__ int offs[128];
    __shared__ int wtot[2];

    float vd[8], va[8];
#pragma unroll
    for (int j = 0; j < 8; ++j) {
      int p = tid + j * 256;
      if (p < NREG) {
        const float* lg = logits + ((long)b * L + LS + p) * NC;
        float x0 = lg[0], x1 = lg[1], x2 = lg[2];
        float m = fmaxf(x0, fmaxf(x1, x2));
        float lse = m + logf(expf(x0 - m) + expf(x1 - m) + expf(x2 - m));
        vd[j] = x2 - lse;
        va[j] = x1 - lse;
      } else {
        vd[j] = -INFINITY;
        va[j] = -INFINITY;
      }
    }
    if (tid < 128) present[tid] = 0;
    for (int j = tid; j < L; j += 256) inv_out[(long)b * L + j] = -1;

    for (int sel = 0; sel < 2; ++sel) {
      float v[8];
#pragma unroll
      for (int j = 0; j < 8; ++j) v[j] = (sel == 0) ? vd[j] : va[j];
#pragma unroll
      for (int r = 0; r < TOP_N; ++r) {
        float mv = v[0];
        int mp = tid;
#pragma unroll
        for (int j = 1; j < 8; ++j) {
          int pj = tid + j * 256;
          if (v[j] > mv) { mv = v[j]; mp = pj; }
        }
#pragma unroll
        for (int off = 32; off; off >>= 1) {
          float ov = __shfl_xor(mv, off, 64);
          int oi = __shfl_xor(mp, off, 64);
          if (ov > mv || (ov == mv && oi < mp)) { mv = ov; mp = oi; }
        }
#pragma unroll
        for (int j = 0; j < 8; ++j)
          if (tid + j * 256 == mp) v[j] = -INFINITY;
        if (lane == 0) { candv[w][r] = mv; candi[w][r] = mp; }
      }
      __syncthreads();
      if (tid < 64) {
        float c = (tid < 32) ? candv[tid >> 3][tid & 7] : -INFINITY;
        int ci = (tid < 32) ? candi[tid >> 3][tid & 7] : 0x7fffffff;
#pragma unroll
        for (int r = 0; r < TOP_N; ++r) {
          float mv = c;
          int mi = ci;
#pragma unroll
          for (int off = 32; off; off >>= 1) {
            float ov = __shfl_xor(mv, off, 64);
            int oi = __shfl_xor(mi, off, 64);
            if (ov > mv || (ov == mv && oi < mi)) { mv = ov; mi = oi; }
          }
          if (ci == mi) c = -INFINITY;
          if (tid == 0) centers[sel * TOP_N + r] = LS + mi;
        }
      }
      __syncthreads();
    }

    for (int j = tid; j < Q_MAX; j += 256) {
      int c = centers[j / (2 * R + 1)];
      int off = j % (2 * R + 1) - R;
      int v2 = c + off;
      v2 = v2 < 0 ? 0 : (v2 > L - 1 ? L - 1 : v2);
      atomicOr(&present[v2 >> 5], 1u << (v2 & 31));
    }
    __syncthreads();

    int cnt = (tid < 128) ? __popc(present[tid]) : 0;
    if (tid < 128) {
      int x = cnt;
#pragma unroll
      for (int off = 1; off < 64; off <<= 1) {
        int o = __shfl_up(x, off, 64);
        if ((tid & 63) >= off) x += o;
      }
      if ((tid & 63) == 63) wtot[tid >> 6] = x;
      offs[tid] = x - cnt;
    }
    __syncthreads();
    int total = wtot[0] + wtot[1];
    if (tid < 128) {
      int base = offs[tid] + ((tid >= 64) ? wtot[0] : 0);
      unsigned mword = present[tid];
      while (mword) {
        int i = __ffs(mword) - 1;
        mword &= mword - 1;
        int pos = tid * 32 + i;
        idx_out[b * Q_MAX + base] = pos;
        mask_out[b * Q_MAX + base] = 1;
        inv_out[(long)b * L + pos] = b * Q_MAX + base;
        ++base;
      }
    }
    for (int j = total + tid; j < Q_MAX; j += 256) {
      idx_out[b * Q_MAX + j] = L;
      mask_out[b * Q_MAX + j] = 0;
    }
  }
}

// ---------------------------------------------------------------------------
// Gather + layer-0 Q-LayerNorm fused: writes fp32 q_stream AND bf16 q_ln.
// ---------------------------------------------------------------------------
__global__ __launch_bounds__(256) void gather_ln(
    const float* __restrict__ enc, const int* __restrict__ idx,
    float* __restrict__ q_stream, u16* __restrict__ q_ln,
    const float* __restrict__ gg, const float* __restrict__ bb) {
  int row = blockIdx.x;
  int b = row / Q_MAX;
  int p = idx[row];
  int tid = threadIdx.x;
  float x = 0.f;
  if (p < L) x = enc[((long)b * L + p) * D + tid];
  q_stream[(long)row * D + tid] = x;
  float s1 = x, s2 = x * x;
#pragma unroll
  for (int off = 32; off; off >>= 1) {
    s1 += __shfl_xor(s1, off, 64);
    s2 += __shfl_xor(s2, off, 64);
  }
  __shared__ float p1[4], p2[4];
  int w = tid >> 6;
  if ((tid & 63) == 0) { p1[w] = s1; p2[w] = s2; }
  __syncthreads();
  s1 = p1[0] + p1[1] + p1[2] + p1[3];
  s2 = p2[0] + p2[1] + p2[2] + p2[3];
  float mean = s1 * (1.f / D);
  float var = fmaxf(s2 * (1.f / D) - mean * mean, 0.f);
  float r = rsqrtf(var + 1e-5f);
  q_ln[(long)row * D + tid] = f2bs((x - mean) * r * gg[tid] + bb[tid]);
}

// ---------------------------------------------------------------------------
__global__ __launch_bounds__(256) void ln_bf16(
    const float* __restrict__ in, u16* __restrict__ out,
    const float* __restrict__ gg, const float* __restrict__ bb) {
  long row = blockIdx.x;
  int tid = threadIdx.x;
  float x = in[row * D + tid];
  float s1 = x, s2 = x * x;
#pragma unroll
  for (int off = 32; off; off >>= 1) {
    s1 += __shfl_xor(s1, off, 64);
    s2 += __shfl_xor(s2, off, 64);
  }
  __shared__ float p1[4], p2[4];
  int w = tid >> 6;
  if ((tid & 63) == 0) { p1[w] = s1; p2[w] = s2; }
  __syncthreads();
  s1 = p1[0] + p1[1] + p1[2] + p1[3];
  s2 = p2[0] + p2[1] + p2[2] + p2[3];
  float mean = s1 * (1.f / D);
  float var = fmaxf(s2 * (1.f / D) - mean * mean, 0.f);
  float r = rsqrtf(var + 1e-5f);
  out[row * D + tid] = f2bs((x - mean) * r * gg[tid] + bb[tid]);
}

// ---------------------------------------------------------------------------
// bf16 MFMA GEMM (64x64 tile, BK=32, 4 waves). EPI 1: gelu->bf16.
// ---------------------------------------------------------------------------
template <int EPI>
__global__ __launch_bounds__(256) void gemm_mfma(
    const u16* __restrict__ A, const u16* __restrict__ BT,
    const float* __restrict__ bias, void* __restrict__ Cv,
    const float* __restrict__ resid, const int* __restrict__ mask, int M,
    int N, int K) {
  __shared__ short As[64][40];
  __shared__ short Bs[64][40];
  int bm = blockIdx.y * 64, bn = blockIdx.x * 64;
  int tid = threadIdx.x;
  int lane = tid & 63, w = tid >> 6;
  int g = lane >> 4, li = lane & 15;
  int wr = w >> 1, wc = w & 1;
  f32x4 acc[2][2] = {};

  int srow = tid >> 2, skc = (tid & 3) * 8;
  for (int k0 = 0; k0 < K; k0 += 32) {
    {
      int grow = bm + srow;
      bf16x8 av = {};
      if (grow < M)
        av = *reinterpret_cast<const bf16x8*>(A + (long)grow * K + k0 + skc);
      *reinterpret_cast<bf16x8*>(&As[srow][skc]) = av;
      bf16x8 bv = *reinterpret_cast<const bf16x8*>(
          BT + (long)(bn + srow) * K + k0 + skc);
      *reinterpret_cast<bf16x8*>(&Bs[srow][skc]) = bv;
    }
    __syncthreads();
    bf16x8 a0 = *reinterpret_cast<const bf16x8*>(&As[wr * 32 + li][g * 8]);
    bf16x8 a1 = *reinterpret_cast<const bf16x8*>(&As[wr * 32 + 16 + li][g * 8]);
    bf16x8 b0 = *reinterpret_cast<const bf16x8*>(&Bs[wc * 32 + li][g * 8]);
    bf16x8 b1 = *reinterpret_cast<const bf16x8*>(&Bs[wc * 32 + 16 + li][g * 8]);
    acc[0][0] = __builtin_amdgcn_mfma_f32_16x16x32_bf16(a0, b0, acc[0][0], 0, 0, 0);
    acc[0][1] = __builtin_amdgcn_mfma_f32_16x16x32_bf16(a0, b1, acc[0][1], 0, 0, 0);
    acc[1][0] = __builtin_amdgcn_mfma_f32_16x16x32_bf16(a1, b0, acc[1][0], 0, 0, 0);
    acc[1][1] = __builtin_amdgcn_mfma_f32_16x16x32_bf16(a1, b1, acc[1][1], 0, 0, 0);
    __syncthreads();
  }

#pragma unroll
  for (int mr = 0; mr < 2; ++mr)
#pragma unroll
    for (int nr = 0; nr < 2; ++nr)
#pragma unroll
      for (int r = 0; r < 4; ++r) {
        int row = bm + wr * 32 + mr * 16 + g * 4 + r;
        int col = bn + wc * 32 + nr * 16 + li;
        if (row >= M) continue;
        float v = acc[mr][nr][r] + bias[col];
        if (EPI == 1) v = gelu_exact(v);
        if (EPI == 2) {
          v += resid[(long)row * N + col];
          v = mask[row] ? v : 0.f;
          ((float*)Cv)[(long)row * N + col] = v;
        } else {
          ((u16*)Cv)[(long)row * N + col] = f2bs(v);
        }
      }
}

// ---------------------------------------------------------------------------
// 32-row-tile bf16 MFMA GEMM for M=2080 resid+mask GEMMs (O-proj, FFN2):
// 128 threads = 2 waves; block tile 32 rows x 64 cols (wave w owns cols
// w*32..w*32+31). Grid (N/64, 65) = 260 blocks -> all CUs active (vs 132).
// Same 16x16x32 MFMA micro-kernel and fragment math as gemm_mfma.
// EPI2 epilogue: C = mask[row] ? resid + x + bias : 0 (f32 out).
// ---------------------------------------------------------------------------
__global__ __launch_bounds__(128) void gemm_mfma32(
    const u16* __restrict__ A, const u16* __restrict__ BT,
    const float* __restrict__ bias, float* __restrict__ Cv,
    const float* __restrict__ resid, const int* __restrict__ mask, int M,
    int N, int K) {
  __shared__ short As[32][40];
  __shared__ short Bs[64][40];
  int bm = blockIdx.y * 32, bn = blockIdx.x * 64;
  int tid = threadIdx.x;
  int lane = tid & 63, w = tid >> 6;
  int g = lane >> 4, li = lane & 15;
  f32x4 acc[2][2] = {};

  int srow = tid >> 2, skc = (tid & 3) * 8;  // srow 0..31
  for (int k0 = 0; k0 < K; k0 += 32) {
    {
      // A: 32 rows x 32 k (1 vector per thread)
      bf16x8 av = *reinterpret_cast<const bf16x8*>(
          A + (long)(bm + srow) * K + k0 + skc);
      *reinterpret_cast<bf16x8*>(&As[srow][skc]) = av;
      // B: 64 rows x 32 k (2 vectors per thread)
      bf16x8 bv0 = *reinterpret_cast<const bf16x8*>(
          BT + (long)(bn + srow) * K + k0 + skc);
      *reinterpret_cast<bf16x8*>(&Bs[srow][skc]) = bv0;
      bf16x8 bv1 = *reinterpret_cast<const bf16x8*>(
          BT + (long)(bn + 32 + srow) * K + k0 + skc);
      *reinterpret_cast<bf16x8*>(&Bs[32 + srow][skc]) = bv1;
    }
    __syncthreads();
    bf16x8 a0 = *reinterpret_cast<const bf16x8*>(&As[li][g * 8]);
    bf16x8 a1 = *reinterpret_cast<const bf16x8*>(&As[16 + li][g * 8]);
    bf16x8 b0 = *reinterpret_cast<const bf16x8*>(&Bs[w * 32 + li][g * 8]);
    bf16x8 b1 = *reinterpret_cast<const bf16x8*>(&Bs[w * 32 + 16 + li][g * 8]);
    acc[0][0] = __builtin_amdgcn_mfma_f32_16x16x32_bf16(a0, b0, acc[0][0], 0, 0, 0);
    acc[0][1] = __builtin_amdgcn_mfma_f32_16x16x32_bf16(a0, b1, acc[0][1], 0, 0, 0);
    acc[1][0] = __builtin_amdgcn_mfma_f32_16x16x32_bf16(a1, b0, acc[1][0], 0, 0, 0);
    acc[1][1] = __builtin_amdgcn_mfma_f32_16x16x32_bf16(a1, b1, acc[1][1], 0, 0, 0);
    __syncthreads();
  }

#pragma unroll
  for (int mr = 0; mr < 2; ++mr)
#pragma unroll
    for (int nr = 0; nr < 2; ++nr)
#pragma unroll
      for (int r = 0; r < 4; ++r) {
        int row = bm + mr * 16 + g * 4 + r;
        int col = bn + w * 32 + nr * 16 + li;
        if (row >= M) continue;
        float v = acc[mr][nr][r] + bias[col] + resid[(long)row * N + col];
        v = mask[row] ? v : 0.f;
        Cv[(long)row * N + col] = v;
      }
}

// ---------------------------------------------------------------------------
// Combined projection dispatch (R12-proven): KV tiles + Q tiles, bf16 A.
// ---------------------------------------------------------------------------
__global__ __launch_bounds__(256) void gemm_proj(
    const u16* __restrict__ Akv, const u16* __restrict__ Aq,
    const u16* __restrict__ WTbase, const float* __restrict__ biasK,
    const float* __restrict__ biasV, const float* __restrict__ biasQ,
    u16* __restrict__ Kh, u16* __restrict__ Vh, u16* __restrict__ Qb) {
  __shared__ short As[64][40];
  __shared__ short Bs[64][40];
  __shared__ u16 Ct[64][72];
  int bid = blockIdx.x;
  int tid = threadIdx.x;
  int lane = tid & 63, w = tid >> 6;
  int g = lane >> 4, li = lane & 15;
  int wr = w >> 1, wc = w & 1;
  f32x4 acc[2][2] = {};
  const long DD = (long)D * D;

  bool isKV = bid < KVBLK;
  int bm, bn, M;
  const u16* A;
  const u16* BT;
  if (isKV) {
    bn = (bid & 7) * 64;
    bm = (bid >> 3) * 64;
    M = KVROWS;
    A = Akv;
    BT = WTbase;
  } else {
    int qb = bid - KVBLK;
    bn = (qb & 3) * 64;
    bm = (qb >> 2) * 64;
    M = QROWS;
    A = Aq;
    BT = WTbase + 2 * DD;
  }

  int srow = tid >> 2, skc = (tid & 3) * 8;
  for (int k0 = 0; k0 < D; k0 += 32) {
    {
      int grow = bm + srow;
      bf16x8 av = {};
      if (grow < M)
        av = *reinterpret_cast<const bf16x8*>(A + (long)grow * D + k0 + skc);
      *reinterpret_cast<bf16x8*>(&As[srow][skc]) = av;
      bf16x8 bv = *reinterpret_cast<const bf16x8*>(
          BT + (long)(bn + srow) * D + k0 + skc);
      *reinterpret_cast<bf16x8*>(&Bs[srow][skc]) = bv;
    }
    __syncthreads();
    bf16x8 a0 = *reinterpret_cast<const bf16x8*>(&As[wr * 32 + li][g * 8]);
    bf16x8 a1 = *reinterpret_cast<const bf16x8*>(&As[wr * 32 + 16 + li][g * 8]);
    bf16x8 b0 = *reinterpret_cast<const bf16x8*>(&Bs[wc * 32 + li][g * 8]);
    bf16x8 b1 = *reinterpret_cast<const bf16x8*>(&Bs[wc * 32 + 16 + li][g * 8]);
    acc[0][0] = __builtin_amdgcn_mfma_f32_16x16x32_bf16(a0, b0, acc[0][0], 0, 0, 0);
    acc[0][1] = __builtin_amdgcn_mfma_f32_16x16x32_bf16(a0, b1, acc[0][1], 0, 0, 0);
    acc[1][0] = __builtin_amdgcn_mfma_f32_16x16x32_bf16(a1, b0, acc[1][0], 0, 0, 0);
    acc[1][1] = __builtin_amdgcn_mfma_f32_16x16x32_bf16(a1, b1, acc[1][1], 0, 0, 0);
    __syncthreads();
  }

  if (!isKV) {
#pragma unroll
    for (int mr = 0; mr < 2; ++mr)
#pragma unroll
      for (int nr = 0; nr < 2; ++nr)
#pragma unroll
        for (int r = 0; r < 4; ++r) {
          int row = bm + wr * 32 + mr * 16 + g * 4 + r;
          int col = bn + wc * 32 + nr * 16 + li;
          if (row >= M) continue;
          Qb[(long)row * D + col] = f2bs(acc[mr][nr][r] + biasQ[col]);
        }
  } else if (bn < 256) {
#pragma unroll
    for (int mr = 0; mr < 2; ++mr)
#pragma unroll
      for (int nr = 0; nr < 2; ++nr)
#pragma unroll
        for (int r = 0; r < 4; ++r) {
          int rowL = wr * 32 + mr * 16 + g * 4 + r;
          int colL = wc * 32 + nr * 16 + li;
          Ct[rowL][colL] = f2bs(acc[mr][nr][r] + biasK[bn + colL]);
        }
    __syncthreads();
#pragma unroll
    for (int p = 0; p < 2; ++p) {
      int rowL = (tid >> 3) + p * 32;
      int c8 = (tid & 7) * 8;
      int grow = bm + rowL;
      int b2 = grow >> 12, key = grow & (L - 1);
      int gcol = bn + c8;
      int hh = gcol >> 5, dd = gcol & (HD - 1);
      int cst = (dd >> 3) ^ ((key >> 1) & 3);
      u16* dst = Kh + (((long)(b2 * H + hh) * L + key) * 32 + (cst << 3));
      *reinterpret_cast<bf16x8*>(dst) =
          *reinterpret_cast<const bf16x8*>(&Ct[rowL][c8]);
    }
  } else {
    int vbn = bn - 256;
#pragma unroll
    for (int mr = 0; mr < 2; ++mr)
#pragma unroll
      for (int nr = 0; nr < 2; ++nr)
#pragma unroll
        for (int r = 0; r < 4; ++r) {
          int rowL = wr * 32 + mr * 16 + g * 4 + r;
          int colL = wc * 32 + nr * 16 + li;
          Ct[colL][rowL] = f2bs(acc[mr][nr][r] + biasV[vbn + colL]);
        }
    __syncthreads();
    int b2 = bm >> 12;
#pragma unroll
    for (int p = 0; p < 2; ++p) {
      int colL = (tid >> 3) + p * 32;
      int rem = tid & 7;
      int kb = rem >> 2, k8 = (rem & 3) * 8;
      int gcol = vbn + colL;
      int hh = gcol >> 5, dd = gcol & (HD - 1);
      int kb32 = ((bm & (L - 1)) >> 5) + kb;
      int j = (k8 >> 2) ^ ((dd >> 1) & 6);
      u16* dst = Vh + (((long)(b2 * H + hh) * (L / 32) + kb32) * 1024 +
                       dd * 32 + (j << 2));
      *reinterpret_cast<bf16x8*>(dst) =
          *reinterpret_cast<const bf16x8*>(&Ct[colL][kb * 32 + k8]);
    }
  }
}

// ---------------------------------------------------------------------------
// Fused flash attention with zero-extra-LDS software pipelining (1.5-buffer):
// 512 threads = 8 split-K waves per (b,h,32-q tile). K half reloaded for
// t+1 after K_t fragments consumed; V half after V_t. Counted vmcnt.
// Kh/Vh XOR-swizzled in global. No-max exp2 softmax. XCD swizzle.
// ---------------------------------------------------------------------------
constexpr int POOLSZ = NSPLIT * 32 * 33 * 4 + NSPLIT * 32 * 4;  // 34816

__global__ __launch_bounds__(512) void attn_mfma(
    const u16* __restrict__ Qb, const u16* __restrict__ Kh,
    const u16* __restrict__ Vh, u16* __restrict__ AO) {
  __shared__ alignas(16) char pool[POOLSZ];
  int i = blockIdx.x;
  int xcd = i & 7, slot = i >> 3;          // 66 slots per XCD
  int bh = (xcd << 1) | (slot >= NQT ? 1 : 0);
  int qt = (slot >= NQT) ? slot - NQT : slot;
  int h = bh & 7;
  int b = bh >> 3;
  int tid = threadIdx.x, w = tid >> 6, lane = tid & 63;
  int g = lane >> 4, li = lane & 15;

  fr qf0, qf1;
  {
    const float QSC = 0.25509836048f;  // (1/sqrt(32)) * log2(e)
#pragma unroll
    for (int qb = 0; qb < 2; ++qb) {
      int qrow = qt * 32 + qb * 16 + li;
      if (qrow >= Q_MAX) qrow = Q_MAX - 1;
      bf16x8 raw = *reinterpret_cast<const bf16x8*>(
          Qb + ((long)(b * Q_MAX + qrow)) * D + h * HD + g * 8);
      fr& qf = qb ? qf1 : qf0;
#pragma unroll
      for (int j = 0; j < 4; ++j)
        qf.i[j] = (int)cvt_pk(bs2f((u16)raw[2 * j]) * QSC,
                              bs2f((u16)raw[2 * j + 1]) * QSC);
    }
  }

  f32x4 acc00 = {}, acc01 = {}, acc10 = {}, acc11 = {};
  float den0 = 0.f, den1 = 0.f;
  const f32x4 z = {};

  const u16* kbase = Kh + ((long)(b * H + h) * L) * HD;
  const u16* vbase = Vh + ((long)(b * H + h) * L) * HD;
  int kstart = w * KCHUNK;
  char* wbase = pool + w * 4096;  // wave-private single buffer (2KB K + 2KB V)

  int s_li = (li >> 1) & 3;
  int t_li = (li >> 1) & 6;
  int kof0 = li * 32 + ((g ^ s_li) << 3);
  int kof1 = (16 + li) * 32 + ((g ^ s_li) << 3);
  int va0o = li * 32 + ((g ^ t_li) << 2);
  int vb0o = li * 32 + (((4 + g) ^ t_li) << 2);
  int va1o = (16 + li) * 32 + ((g ^ t_li) << 2);
  int vb1o = (16 + li) * 32 + (((4 + g) ^ t_li) << 2);

  // prologue: issue K0 (2 loads) then V0 (2 loads)
  {
    const u16* ks = kbase + (long)kstart * HD + lane * 8;
    const u16* vs = vbase + (long)kstart * HD + lane * 8;
    u16* lk = (u16*)wbase;
    GLL16(ks, lk);
    GLL16(ks + 512, lk + 512);
    GLL16(vs, lk + 1024);
    GLL16(vs + 512, lk + 1536);
  }

  for (int t = 0; t < NT; ++t) {
    const u16* kl = (const u16*)wbase;
    const u16* vl = kl + 1024;

    asm volatile("s_waitcnt vmcnt(2)" ::: "memory");
    __builtin_amdgcn_sched_barrier(0);
    fr kf0, kf1;
    kf0.h = *reinterpret_cast<const bf16x8*>(kl + kof0);
    kf1.h = *reinterpret_cast<const bf16x8*>(kl + kof1);
    asm volatile("" ::"v"(kf0.i[0]), "v"(kf0.i[1]), "v"(kf0.i[2]),
                 "v"(kf0.i[3]), "v"(kf1.i[0]), "v"(kf1.i[1]), "v"(kf1.i[2]),
                 "v"(kf1.i[3]));
    asm volatile("s_waitcnt lgkmcnt(0)" ::: "memory");
    __builtin_amdgcn_sched_barrier(0);
    if (t + 1 < NT) {
      const u16* ks = kbase + (long)(kstart + (t + 1) * 32) * HD + lane * 8;
      u16* lk = (u16*)wbase;
      GLL16(ks, lk);
      GLL16(ks + 512, lk + 512);
    }

    f32x4 s00 = __builtin_amdgcn_mfma_f32_16x16x32_bf16(kf0.h, qf0.h, z, 0, 0, 0);
    f32x4 s10 = __builtin_amdgcn_mfma_f32_16x16x32_bf16(kf1.h, qf0.h, z, 0, 0, 0);
    f32x4 s01 = __builtin_amdgcn_mfma_f32_16x16x32_bf16(kf0.h, qf1.h, z, 0, 0, 0);
    f32x4 s11 = __builtin_amdgcn_mfma_f32_16x16x32_bf16(kf1.h, qf1.h, z, 0, 0, 0);

    float p00[4], p10[4], p01[4], p11[4];
#pragma unroll
    for (int r = 0; r < 4; ++r) {
      p00[r] = exp2f(s00[r]);
      p10[r] = exp2f(s10[r]);
      p01[r] = exp2f(s01[r]);
      p11[r] = exp2f(s11[r]);
      den0 += p00[r] + p10[r];
      den1 += p01[r] + p11[r];
    }
    fr pf0, pf1;
    pf0.i[0] = (int)cvt_pk(p00[0], p00[1]);
    pf0.i[1] = (int)cvt_pk(p00[2], p00[3]);
    pf0.i[2] = (int)cvt_pk(p10[0], p10[1]);
    pf0.i[3] = (int)cvt_pk(p10[2], p10[3]);
    pf1.i[0] = (int)cvt_pk(p01[0], p01[1]);
    pf1.i[1] = (int)cvt_pk(p01[2], p01[3]);
    pf1.i[2] = (int)cvt_pk(p11[0], p11[1]);
    pf1.i[3] = (int)cvt_pk(p11[2], p11[3]);

    if (t + 1 < NT)
      asm volatile("s_waitcnt vmcnt(2)" ::: "memory");
    else
      asm volatile("s_waitcnt vmcnt(0)" ::: "memory");
    __builtin_amdgcn_sched_barrier(0);
    uint2 va0 = *reinterpret_cast<const uint2*>(vl + va0o);
    uint2 vb0 = *reinterpret_cast<const uint2*>(vl + vb0o);
    uint2 va1 = *reinterpret_cast<const uint2*>(vl + va1o);
    uint2 vb1 = *reinterpret_cast<const uint2*>(vl + vb1o);
    asm volatile("" ::"v"(va0.x), "v"(va0.y), "v"(vb0.x), "v"(vb0.y),
                 "v"(va1.x), "v"(va1.y), "v"(vb1.x), "v"(vb1.y));
    asm volatile("s_waitcnt lgkmcnt(0)" ::: "memory");
    __builtin_amdgcn_sched_barrier(0);
    if (t + 1 < NT) {
      const u16* vs = vbase + (long)(kstart + (t + 1) * 32) * HD + lane * 8;
      u16* lk = (u16*)wbase;
      GLL16(vs, lk + 1024);
      GLL16(vs + 512, lk + 1536);
    }

    fr v0, v1;
    v0.i = (i32x4){(int)va0.x, (int)va0.y, (int)vb0.x, (int)vb0.y};
    v1.i = (i32x4){(int)va1.x, (int)va1.y, (int)vb1.x, (int)vb1.y};
    acc00 = __builtin_amdgcn_mfma_f32_16x16x32_bf16(v0.h, pf0.h, acc00, 0, 0, 0);
    acc01 = __builtin_amdgcn_mfma_f32_16x16x32_bf16(v0.h, pf1.h, acc01, 0, 0, 0);
    acc10 = __builtin_amdgcn_mfma_f32_16x16x32_bf16(v1.h, pf0.h, acc10, 0, 0, 0);
    acc11 = __builtin_amdgcn_mfma_f32_16x16x32_bf16(v1.h, pf1.h, acc11, 0, 0, 0);
  }

  den0 += __shfl_xor(den0, 16, 64);
  den0 += __shfl_xor(den0, 32, 64);
  den1 += __shfl_xor(den1, 16, 64);
  den1 += __shfl_xor(den1, 32, 64);

  __syncthreads();
  float(*accs)[32][33] = (float(*)[32][33])pool;
  float(*dsh)[32] = (float(*)[32])(pool + NSPLIT * 32 * 33 * 4);
#pragma unroll
  for (int r = 0; r < 4; ++r) {
    accs[w][g * 4 + r][li] = acc00[r];
    accs[w][g * 4 + r][16 + li] = acc01[r];
    accs[w][16 + g * 4 + r][li] = acc10[r];
    accs[w][16 + g * 4 + r][16 + li] = acc11[r];
  }
  if (g == 0) {
    dsh[w][li] = den0;
    dsh[w][16 + li] = den1;
  }
  __syncthreads();

  int q = tid >> 4, dp = tid & 15;
  float Den = 0.f, o0 = 0.f, o1 = 0.f;
#pragma unroll
  for (int ww = 0; ww < NSPLIT; ++ww) {
    Den += dsh[ww][q];
    o0 += accs[ww][2 * dp][q];
    o1 += accs[ww][2 * dp + 1][q];
  }
  float inv = 1.f / Den;
  int qrow = qt * 32 + q;
  if (qrow < Q_MAX) {
    unsigned pk = cvt_pk(o0 * inv, o1 * inv);
    *reinterpret_cast<unsigned*>(
        AO + ((long)(b * Q_MAX + qrow)) * D + h * HD + 2 * dp) = pk;
  }
}

// ---------------------------------------------------------------------------
// Merged head: input = q_stream[inv] if selected else enc row.
// ---------------------------------------------------------------------------
__global__ __launch_bounds__(256) void head_kernel(
    const float* __restrict__ enc, const float* __restrict__ q_stream,
    const int* __restrict__ inv, const float* __restrict__ hW,
    const float* __restrict__ hb, float* __restrict__ out) {
  int row = blockIdx.x * 4 + (threadIdx.x >> 6);
  int lane = threadIdx.x & 63;
  int slot = inv[row];
  const float* src =
      (slot >= 0) ? (q_stream + (long)slot * D) : (enc + (long)row * D);
  const float4 a = *reinterpret_cast<const float4*>(src + lane * 4);
  float c0 = 0.f, c1 = 0.f, c2 = 0.f;
  const float av[4] = {a.x, a.y, a.z, a.w};
#pragma unroll
  for (int i = 0; i < 4; ++i) {
    int k = lane * 4 + i;
    c0 += av[i] * hW[k * 3];
    c1 += av[i] * hW[k * 3 + 1];
    c2 += av[i] * hW[k * 3 + 2];
  }
#pragma unroll
  for (int off = 32; off; off >>= 1) {
    c0 += __shfl_down(c0, off, 64);
    c1 += __shfl_down(c1, off, 64);
    c2 += __shfl_down(c2, off, 64);
  }
  if (lane == 0) {
    out[(long)row * 3] = c0 + hb[0];
    out[(long)row * 3 + 1] = c1 + hb[1];
    out[(long)row * 3 + 2] = c2 + hb[2];
  }
}

// ---------------------------------------------------------------------------
extern "C" void kernel_launch(void* const* d_in, const int* in_sizes, int n_in,
                              void* d_out, int out_size, void* d_ws,
                              size_t ws_size, hipStream_t stream) {
  const float* enc = (const float*)d_in[0];
  const float* clog = (const float*)d_in[1];
  const float* ln_q_g = (const float*)d_in[2];
  const float* ln_q_b = (const float*)d_in[3];
  const float* ln_kv_g = (const float*)d_in[4];
  const float* ln_kv_b = (const float*)d_in[5];
  const float* Wq = (const float*)d_in[6];
  const float* bq = (const float*)d_in[7];
  const float* Wk = (const float*)d_in[8];
  const float* bk = (const float*)d_in[9];
  const float* Wv = (const float*)d_in[10];
  const float* bv = (const float*)d_in[11];
  const float* Wo = (const float*)d_in[12];
  const float* bo = (const float*)d_in[13];
  const float* ffn_g = (const float*)d_in[14];
  const float* ffn_b = (const float*)d_in[15];
  const float* W1 = (const float*)d_in[16];
  const float* b1 = (const float*)d_in[17];
  const float* W2 = (const float*)d_in[18];
  const float* b2 = (const float*)d_in[19];
  const float* head_W = (const float*)d_in[20];
  const float* head_b = (const float*)d_in[21];
  float* out = (float*)d_out;

  char* ws = (char*)d_ws;
  float* q_stream = (float*)ws;            ws += (long)QROWS * D * 4;
  u16* kvl0 = (u16*)ws;                    ws += (long)KVROWS * D * 2;
  u16* kvl1 = (u16*)ws;                    ws += (long)KVROWS * D * 2;
  u16* Khbuf = (u16*)ws;                   ws += (long)B * H * L * HD * 2;
  u16* Vhbuf = (u16*)ws;                   ws += (long)B * H * L * HD * 2;
  u16* q_ln = (u16*)ws;                    ws += (long)QROWS * D * 2;
  u16* Qbuf = (u16*)ws;                    ws += (long)QROWS * D * 2;
  u16* AObuf = (u16*)ws;                   ws += (long)QROWS * D * 2;
  u16* H1buf = (u16*)ws;                   ws += (long)QROWS * FF * 2;
  u16* WT = (u16*)ws;                      ws += (long)NL * (4 * D * D + 2 * D * FF) * 2;
  int* idxbuf = (int*)ws;                  ws += QROWS * 4;
  int* maskbuf = (int*)ws;                 ws += QROWS * 4;
  int* invbuf = (int*)ws;                  ws += (long)B * L * 4;

  const long DD = (long)D * D, DFF = (long)D * FF;
  const long LSTR = 4 * DD + 2 * DFF;

  setup_kernel<<<KVROWS + TRBLK + B, 256, 0, stream>>>(
      enc, clog, ln_kv_g, ln_kv_b, Wq, Wk, Wv, Wo, W1, W2, WT, kvl0, kvl1,
      idxbuf, maskbuf, invbuf);
  gather_ln<<<QROWS, 256, 0, stream>>>(enc, idxbuf, q_stream, q_ln, ln_q_g,
                                       ln_q_b);

  for (int l = 0; l < NL; ++l) {
    u16* base = WT + l * LSTR;
    u16* kv_ln = (l == 0) ? kvl0 : kvl1;

    if (l > 0)
      ln_bf16<<<QROWS, 256, 0, stream>>>(q_stream, q_ln, ln_q_g + l * D,
                                         ln_q_b + l * D);

    gemm_proj<<<KVBLK + QBLK, 256, 0, stream>>>(
        kv_ln, q_ln, base, bk + l * D, bv + l * D, bq + l * D, Khbuf, Vhbuf,
        Qbuf);

    attn_mfma<<<B * H * NQT, 512, 0, stream>>>(Qbuf, Khbuf, Vhbuf, AObuf);

    // O-proj: 32-row tiles, grid (4,65)=260 blocks (full-GPU occupancy)
    gemm_mfma32<<<dim3(D / 64, MRB32), 128, 0, stream>>>(
        AObuf, base + 3 * DD, bo + l * D, q_stream, q_stream, maskbuf, QROWS,
        D, D);

    ln_bf16<<<QROWS, 256, 0, stream>>>(q_stream, q_ln, ffn_g + l * D, ffn_b + l * D);
    dim3 gF1(FF / 64, (QROWS + 63) / 64);
    gemm_mfma<1><<<gF1, 256, 0, stream>>>(q_ln, base + 4 * DD, b1 + l * FF,
                                          (void*)H1buf, nullptr, nullptr,
                                          QROWS, FF, D);
    // FFN2: 32-row tiles, grid (4,65)=260 blocks
    gemm_mfma32<<<dim3(D / 64, MRB32), 128, 0, stream>>>(
        H1buf, base + 4 * DD + DFF, b2 + l * D, q_stream, q_stream, maskbuf,
        QROWS, D, FF);
  }

  head_kernel<<<KVROWS / 4, 256, 0, stream>>>(enc, q_stream, invbuf, head_W,
                                              head_b, out);
}

// Round 18
// 210.092 us; speedup vs baseline: 1.3779x; 1.0313x over previous
//
#include <hip/hip_runtime.h>
#include <cmath>

constexpr int B = 2, L = 4096, D = 256, H = 8, NC = 3;
constexpr int TOP_N = 8, R = 32;
constexpr int LS = 1000, LE = 3000;
constexpr int NL = 2;
constexpr int FF = 4 * D;                        // 1024
constexpr int Q_MAX = 2 * TOP_N * (2 * R + 1);   // 1040
constexpr int HD = D / H;                        // 32
constexpr int QROWS = B * Q_MAX;                 // 2080
constexpr int KVROWS = B * L;                    // 8192
constexpr int NQT = (Q_MAX + 31) / 32;           // 33 q-tiles of 32
constexpr int NREG = LE - LS;                    // 2000
constexpr int NSPLIT = 8;                        // split-K waves per block
constexpr int KCHUNK = L / NSPLIT;               // 512 keys per wave
constexpr int NT = KCHUNK / 32;                  // 16 iterations
constexpr int KVBLK = 8 * (KVROWS / 64);         // 1024 blocks (KV part)
constexpr int QBLK = 4 * ((QROWS + 63) / 64);    // 132 blocks (Q part)
constexpr int TRBLK = NL * 192;                  // 384 transpose blocks
constexpr int LNBLK = KVROWS / 4;                // 2048 LN blocks (4 rows ea)
constexpr int MRB32 = QROWS / 32;                // 65 row-blocks of 32

typedef __attribute__((ext_vector_type(8))) short bf16x8;
typedef __attribute__((ext_vector_type(4))) float f32x4;
typedef __attribute__((ext_vector_type(4))) int i32x4;
typedef unsigned short u16;

union fr {
  bf16x8 h;
  i32x4 i;
};

__device__ __forceinline__ u16 f2bs(float f) {
  unsigned int u = __float_as_uint(f);
  unsigned int r = u + 0x7fffu + ((u >> 16) & 1u);
  return (u16)(r >> 16);
}
__device__ __forceinline__ float bs2f(u16 s) {
  return __uint_as_float(((unsigned int)s) << 16);
}
__device__ __forceinline__ float gelu_exact(float x) {
  return 0.5f * x * (1.f + erff(x * 0.70710678118654752440f));
}
__device__ __forceinline__ unsigned cvt_pk(float lo, float hi) {
  unsigned r;
  asm("v_cvt_pk_bf16_f32 %0, %1, %2" : "=v"(r) : "v"(lo), "v"(hi));
  return r;
}

#define GLL16(gsrc, ldst)                                                   \
  __builtin_amdgcn_global_load_lds(                                         \
      (const __attribute__((address_space(1))) unsigned int*)(gsrc),        \
      (__attribute__((address_space(3))) unsigned int*)(ldst), 16, 0, 0)

// Wave-level row LayerNorm helper: lane holds float4 (cols lane*4..lane*4+3).
// Returns mean and rstd via pure-shfl reduction (no LDS, no barriers).
__device__ __forceinline__ void wave_ln_stats(float4 v, float& mean,
                                              float& rstd) {
  float s1 = v.x + v.y + v.z + v.w;
  float s2 = v.x * v.x + v.y * v.y + v.z * v.z + v.w * v.w;
#pragma unroll
  for (int off = 32; off; off >>= 1) {
    s1 += __shfl_xor(s1, off, 64);
    s2 += __shfl_xor(s2, off, 64);
  }
  mean = s1 * (1.f / D);
  float var = fmaxf(s2 * (1.f / D) - mean * mean, 0.f);
  rstd = rsqrtf(var + 1e-5f);
}

// ---------------------------------------------------------------------------
// Merged setup dispatch (256 threads/block):
//   blocks [0, LNBLK)             : dual-layer LayerNorm of enc (4 rows/blk,
//                                   wave-per-row, float4 loads) -> kvl0/kvl1
//   blocks [LNBLK, LNBLK+TRBLK)   : LDS-tiled weight transpose+bf16 -> WT
//   blocks [LNBLK+TRBLK, +B)      : vicinity selection (one block per batch)
//     also emits inv[b*L+pos] = global slot (or -1) for the merged head.
// ---------------------------------------------------------------------------
__global__ __launch_bounds__(256) void setup_kernel(
    const float* __restrict__ enc, const float* __restrict__ logits,
    const float* __restrict__ lnkvg, const float* __restrict__ lnkvb,
    const float* __restrict__ Wq_, const float* __restrict__ Wk_,
    const float* __restrict__ Wv_, const float* __restrict__ Wo_,
    const float* __restrict__ W1_, const float* __restrict__ W2_,
    u16* __restrict__ WT, u16* __restrict__ o0, u16* __restrict__ o1,
    int* __restrict__ idx_out, int* __restrict__ mask_out,
    int* __restrict__ inv_out) {
  int bid = blockIdx.x;
  int tid = threadIdx.x;
  const long DD = (long)D * D, DFF = (long)D * FF;
  const long LSTR = 4 * DD + 2 * DFF;

  if (bid < LNBLK) {
    long row = (long)bid * 4 + (tid >> 6);
    int lane = tid & 63;
    float4 v = *reinterpret_cast<const float4*>(enc + row * D + lane * 4);
    float mean, rstd;
    wave_ln_stats(v, mean, rstd);
    float n0 = (v.x - mean) * rstd, n1 = (v.y - mean) * rstd,
          n2 = (v.z - mean) * rstd, n3 = (v.w - mean) * rstd;
    int c = lane * 4;
    float4 g0 = *reinterpret_cast<const float4*>(lnkvg + c);
    float4 b0v = *reinterpret_cast<const float4*>(lnkvb + c);
    float4 g1 = *reinterpret_cast<const float4*>(lnkvg + D + c);
    float4 b1v = *reinterpret_cast<const float4*>(lnkvb + D + c);
    uint2 w0 = {cvt_pk(n0 * g0.x + b0v.x, n1 * g0.y + b0v.y),
                cvt_pk(n2 * g0.z + b0v.z, n3 * g0.w + b0v.w)};
    uint2 w1 = {cvt_pk(n0 * g1.x + b1v.x, n1 * g1.y + b1v.y),
                cvt_pk(n2 * g1.z + b1v.z, n3 * g1.w + b1v.w)};
    *reinterpret_cast<uint2*>(o0 + row * D + c) = w0;
    *reinterpret_cast<uint2*>(o1 + row * D + c) = w1;
    return;
  }

  if (bid < LNBLK + TRBLK) {
    __shared__ u16 T[64][65];
    int t = bid - LNBLK;
    int l = t / 192, r = t % 192;
    const float* src;
    long dbase;
    int K_, N_, kt, nt;
    if (r < 64) {
      int which = r >> 4, sub = r & 15;
      kt = sub >> 2;
      nt = sub & 3;
      K_ = 256;
      N_ = 256;
      src = (which == 0 ? Wk_ : which == 1 ? Wv_ : which == 2 ? Wq_ : Wo_) +
            (long)l * DD;
      dbase = (long)l * LSTR + (long)which * DD;
    } else if (r < 128) {
      int sub = r - 64;
      kt = sub >> 4;
      nt = sub & 15;
      K_ = 256;
      N_ = 1024;
      src = W1_ + (long)l * DFF;
      dbase = (long)l * LSTR + 4 * DD;
    } else {
      int sub = r - 128;
      kt = sub >> 2;
      nt = sub & 3;
      K_ = 1024;
      N_ = 256;
      src = W2_ + (long)l * DFF;
      dbase = (long)l * LSTR + 4 * DD + DFF;
    }
    int k0 = kt * 64, n0 = nt * 64;
    {
      int kr = tid >> 2, c16 = (tid & 3) * 16;
      const float* sp = src + (long)(k0 + kr) * N_ + n0 + c16;
#pragma unroll
      for (int i = 0; i < 4; ++i) {
        float4 v = *reinterpret_cast<const float4*>(sp + 4 * i);
        T[kr][c16 + 4 * i + 0] = f2bs(v.x);
        T[kr][c16 + 4 * i + 1] = f2bs(v.y);
        T[kr][c16 + 4 * i + 2] = f2bs(v.z);
        T[kr][c16 + 4 * i + 3] = f2bs(v.w);
      }
    }
    __syncthreads();
    {
      int nr = tid >> 2, kc = (tid & 3) * 16;
      u16 tmp[16];
#pragma unroll
      for (int j = 0; j < 16; ++j) tmp[j] = T[kc + j][nr];
      u16* dp = WT + dbase + (long)(n0 + nr) * K_ + k0 + kc;
      *reinterpret_cast<bf16x8*>(dp) = *reinterpret_cast<const bf16x8*>(&tmp[0]);
      *reinterpret_cast<bf16x8*>(dp + 8) =
          *reinterpret_cast<const bf16x8*>(&tmp[8]);
    }
    return;
  }

  // ---- select part (one block per batch), 256 threads = 4 waves
  {
    int b = bid - LNBLK - TRBLK;
    int w = tid >> 6, lane = tid & 63;
    __shared__ float candv[4][8];
    __shared__ int candi[4][8];
    __shared__ int centers[2 * TOP_N];
    __shared__ unsigned present[L / 32];
    __shared__ int offs[128];
    __shared__ int wtot[2];

    float vd[8], va[8];
#pragma unroll
    for (int j = 0; j < 8; ++j) {
      int p = tid + j * 256;
      if (p < NREG) {
        const float* lg = logits + ((long)b * L + LS + p) * NC;
        float x0 = lg[0], x1 = lg[1], x2 = lg[2];
        float m = fmaxf(x0, fmaxf(x1, x2));
        float lse = m + logf(expf(x0 - m) + expf(x1 - m) + expf(x2 - m));
        vd[j] = x2 - lse;
        va[j] = x1 - lse;
      } else {
        vd[j] = -INFINITY;
        va[j] = -INFINITY;
      }
    }
    if (tid < 128) present[tid] = 0;
    for (int j = tid; j < L; j += 256) inv_out[(long)b * L + j] = -1;

    for (int sel = 0; sel < 2; ++sel) {
      float v[8];
#pragma unroll
      for (int j = 0; j < 8; ++j) v[j] = (sel == 0) ? vd[j] : va[j];
#pragma unroll
      for (int r = 0; r < TOP_N; ++r) {
        float mv = v[0];
        int mp = tid;
#pragma unroll
        for (int j = 1; j < 8; ++j) {
          int pj = tid + j * 256;
          if (v[j] > mv) { mv = v[j]; mp = pj; }
        }
#pragma unroll
        for (int off = 32; off; off >>= 1) {
          float ov = __shfl_xor(mv, off, 64);
          int oi = __shfl_xor(mp, off, 64);
          if (ov > mv || (ov == mv && oi < mp)) { mv = ov; mp = oi; }
        }
#pragma unroll
        for (int j = 0; j < 8; ++j)
          if (tid + j * 256 == mp) v[j] = -INFINITY;
        if (lane == 0) { candv[w][r] = mv; candi[w][r] = mp; }
      }
      __syncthreads();
      if (tid < 64) {
        float c = (tid < 32) ? candv[tid >> 3][tid & 7] : -INFINITY;
        int ci = (tid < 32) ? candi[tid >> 3][tid & 7] : 0x7fffffff;
#pragma unroll
        for (int r = 0; r < TOP_N; ++r) {
          float mv = c;
          int mi = ci;
#pragma unroll
          for (int off = 32; off; off >>= 1) {
            float ov = __shfl_xor(mv, off, 64);
            int oi = __shfl_xor(mi, off, 64);
            if (ov > mv || (ov == mv && oi < mi)) { mv = ov; mi = oi; }
          }
          if (ci == mi) c = -INFINITY;
          if (tid == 0) centers[sel * TOP_N + r] = LS + mi;
        }
      }
      __syncthreads();
    }

    for (int j = tid; j < Q_MAX; j += 256) {
      int c = centers[j / (2 * R + 1)];
      int off = j % (2 * R + 1) - R;
      int v2 = c + off;
      v2 = v2 < 0 ? 0 : (v2 > L - 1 ? L - 1 : v2);
      atomicOr(&present[v2 >> 5], 1u << (v2 & 31));
    }
    __syncthreads();

    int cnt = (tid < 128) ? __popc(present[tid]) : 0;
    if (tid < 128) {
      int x = cnt;
#pragma unroll
      for (int off = 1; off < 64; off <<= 1) {
        int o = __shfl_up(x, off, 64);
        if ((tid & 63) >= off) x += o;
      }
      if ((tid & 63) == 63) wtot[tid >> 6] = x;
      offs[tid] = x - cnt;
    }
    __syncthreads();
    int total = wtot[0] + wtot[1];
    if (tid < 128) {
      int base = offs[tid] + ((tid >= 64) ? wtot[0] : 0);
      unsigned mword = present[tid];
      while (mword) {
        int i = __ffs(mword) - 1;
        mword &= mword - 1;
        int pos = tid * 32 + i;
        idx_out[b * Q_MAX + base] = pos;
        mask_out[b * Q_MAX + base] = 1;
        inv_out[(long)b * L + pos] = b * Q_MAX + base;
        ++base;
      }
    }
    for (int j = total + tid; j < Q_MAX; j += 256) {
      idx_out[b * Q_MAX + j] = L;
      mask_out[b * Q_MAX + j] = 0;
    }
  }
}

// ---------------------------------------------------------------------------
// Gather + layer-0 Q-LN fused, wave-per-row: 4 rows/block, float4 loads,
// shfl-only reduction. Writes fp32 q_stream AND bf16 q_ln. Grid QROWS/4.
// ---------------------------------------------------------------------------
__global__ __launch_bounds__(256) void gather_ln(
    const float* __restrict__ enc, const int* __restrict__ idx,
    float* __restrict__ q_stream, u16* __restrict__ q_ln,
    const float* __restrict__ gg, const float* __restrict__ bb) {
  int row = blockIdx.x * 4 + (threadIdx.x >> 6);
  int lane = threadIdx.x & 63;
  int b = row / Q_MAX;
  int p = idx[row];
  int c = lane * 4;
  float4 v = {0.f, 0.f, 0.f, 0.f};
  if (p < L) v = *reinterpret_cast<const float4*>(enc + ((long)b * L + p) * D + c);
  *reinterpret_cast<float4*>(q_stream + (long)row * D + c) = v;
  float mean, rstd;
  wave_ln_stats(v, mean, rstd);
  float4 g = *reinterpret_cast<const float4*>(gg + c);
  float4 bt = *reinterpret_cast<const float4*>(bb + c);
  uint2 w = {cvt_pk((v.x - mean) * rstd * g.x + bt.x,
                    (v.y - mean) * rstd * g.y + bt.y),
             cvt_pk((v.z - mean) * rstd * g.z + bt.z,
                    (v.w - mean) * rstd * g.w + bt.w)};
  *reinterpret_cast<uint2*>(q_ln + (long)row * D + c) = w;
}

// ---------------------------------------------------------------------------
// Wave-per-row LayerNorm fp32 -> bf16: 4 rows/block, float4 loads. Grid M/4.
// ---------------------------------------------------------------------------
__global__ __launch_bounds__(256) void ln_bf16(
    const float* __restrict__ in, u16* __restrict__ out,
    const float* __restrict__ gg, const float* __restrict__ bb) {
  long row = (long)blockIdx.x * 4 + (threadIdx.x >> 6);
  int lane = threadIdx.x & 63;
  int c = lane * 4;
  float4 v = *reinterpret_cast<const float4*>(in + row * D + c);
  float mean, rstd;
  wave_ln_stats(v, mean, rstd);
  float4 g = *reinterpret_cast<const float4*>(gg + c);
  float4 bt = *reinterpret_cast<const float4*>(bb + c);
  uint2 w = {cvt_pk((v.x - mean) * rstd * g.x + bt.x,
                    (v.y - mean) * rstd * g.y + bt.y),
             cvt_pk((v.z - mean) * rstd * g.z + bt.z,
                    (v.w - mean) * rstd * g.w + bt.w)};
  *reinterpret_cast<uint2*>(out + row * D + c) = w;
}

// ---------------------------------------------------------------------------
// bf16 MFMA GEMM (64x64 tile, BK=32, 4 waves). EPI 1: gelu->bf16.
// ---------------------------------------------------------------------------
template <int EPI>
__global__ __launch_bounds__(256) void gemm_mfma(
    const u16* __restrict__ A, const u16* __restrict__ BT,
    const float* __restrict__ bias, void* __restrict__ Cv,
    const float* __restrict__ resid, const int* __restrict__ mask, int M,
    int N, int K) {
  __shared__ short As[64][40];
  __shared__ short Bs[64][40];
  int bm = blockIdx.y * 64, bn = blockIdx.x * 64;
  int tid = threadIdx.x;
  int lane = tid & 63, w = tid >> 6;
  int g = lane >> 4, li = lane & 15;
  int wr = w >> 1, wc = w & 1;
  f32x4 acc[2][2] = {};

  int srow = tid >> 2, skc = (tid & 3) * 8;
  for (int k0 = 0; k0 < K; k0 += 32) {
    {
      int grow = bm + srow;
      bf16x8 av = {};
      if (grow < M)
        av = *reinterpret_cast<const bf16x8*>(A + (long)grow * K + k0 + skc);
      *reinterpret_cast<bf16x8*>(&As[srow][skc]) = av;
      bf16x8 bv = *reinterpret_cast<const bf16x8*>(
          BT + (long)(bn + srow) * K + k0 + skc);
      *reinterpret_cast<bf16x8*>(&Bs[srow][skc]) = bv;
    }
    __syncthreads();
    bf16x8 a0 = *reinterpret_cast<const bf16x8*>(&As[wr * 32 + li][g * 8]);
    bf16x8 a1 = *reinterpret_cast<const bf16x8*>(&As[wr * 32 + 16 + li][g * 8]);
    bf16x8 b0 = *reinterpret_cast<const bf16x8*>(&Bs[wc * 32 + li][g * 8]);
    bf16x8 b1 = *reinterpret_cast<const bf16x8*>(&Bs[wc * 32 + 16 + li][g * 8]);
    acc[0][0] = __builtin_amdgcn_mfma_f32_16x16x32_bf16(a0, b0, acc[0][0], 0, 0, 0);
    acc[0][1] = __builtin_amdgcn_mfma_f32_16x16x32_bf16(a0, b1, acc[0][1], 0, 0, 0);
    acc[1][0] = __builtin_amdgcn_mfma_f32_16x16x32_bf16(a1, b0, acc[1][0], 0, 0, 0);
    acc[1][1] = __builtin_amdgcn_mfma_f32_16x16x32_bf16(a1, b1, acc[1][1], 0, 0, 0);
    __syncthreads();
  }

#pragma unroll
  for (int mr = 0; mr < 2; ++mr)
#pragma unroll
    for (int nr = 0; nr < 2; ++nr)
#pragma unroll
      for (int r = 0; r < 4; ++r) {
        int row = bm + wr * 32 + mr * 16 + g * 4 + r;
        int col = bn + wc * 32 + nr * 16 + li;
        if (row >= M) continue;
        float v = acc[mr][nr][r] + bias[col];
        if (EPI == 1) v = gelu_exact(v);
        if (EPI == 2) {
          v += resid[(long)row * N + col];
          v = mask[row] ? v : 0.f;
          ((float*)Cv)[(long)row * N + col] = v;
        } else {
          ((u16*)Cv)[(long)row * N + col] = f2bs(v);
        }
      }
}

// ---------------------------------------------------------------------------
// 32-row-tile bf16 MFMA GEMM (O-proj, FFN2): 128 threads = 2 waves, grid
// (N/64, 65) = 260 blocks. EPI2: C = mask ? resid + x + bias : 0 (f32).
// ---------------------------------------------------------------------------
__global__ __launch_bounds__(128) void gemm_mfma32(
    const u16* __restrict__ A, const u16* __restrict__ BT,
    const float* __restrict__ bias, float* __restrict__ Cv,
    const float* __restrict__ resid, const int* __restrict__ mask, int M,
    int N, int K) {
  __shared__ short As[32][40];
  __shared__ short Bs[64][40];
  int bm = blockIdx.y * 32, bn = blockIdx.x * 64;
  int tid = threadIdx.x;
  int lane = tid & 63, w = tid >> 6;
  int g = lane >> 4, li = lane & 15;
  f32x4 acc[2][2] = {};

  int srow = tid >> 2, skc = (tid & 3) * 8;  // srow 0..31
  for (int k0 = 0; k0 < K; k0 += 32) {
    {
      bf16x8 av = *reinterpret_cast<const bf16x8*>(
          A + (long)(bm + srow) * K + k0 + skc);
      *reinterpret_cast<bf16x8*>(&As[srow][skc]) = av;
      bf16x8 bv0 = *reinterpret_cast<const bf16x8*>(
          BT + (long)(bn + srow) * K + k0 + skc);
      *reinterpret_cast<bf16x8*>(&Bs[srow][skc]) = bv0;
      bf16x8 bv1 = *reinterpret_cast<const bf16x8*>(
          BT + (long)(bn + 32 + srow) * K + k0 + skc);
      *reinterpret_cast<bf16x8*>(&Bs[32 + srow][skc]) = bv1;
    }
    __syncthreads();
    bf16x8 a0 = *reinterpret_cast<const bf16x8*>(&As[li][g * 8]);
    bf16x8 a1 = *reinterpret_cast<const bf16x8*>(&As[16 + li][g * 8]);
    bf16x8 b0 = *reinterpret_cast<const bf16x8*>(&Bs[w * 32 + li][g * 8]);
    bf16x8 b1 = *reinterpret_cast<const bf16x8*>(&Bs[w * 32 + 16 + li][g * 8]);
    acc[0][0] = __builtin_amdgcn_mfma_f32_16x16x32_bf16(a0, b0, acc[0][0], 0, 0, 0);
    acc[0][1] = __builtin_amdgcn_mfma_f32_16x16x32_bf16(a0, b1, acc[0][1], 0, 0, 0);
    acc[1][0] = __builtin_amdgcn_mfma_f32_16x16x32_bf16(a1, b0, acc[1][0], 0, 0, 0);
    acc[1][1] = __builtin_amdgcn_mfma_f32_16x16x32_bf16(a1, b1, acc[1][1], 0, 0, 0);
    __syncthreads();
  }

#pragma unroll
  for (int mr = 0; mr < 2; ++mr)
#pragma unroll
    for (int nr = 0; nr < 2; ++nr)
#pragma unroll
      for (int r = 0; r < 4; ++r) {
        int row = bm + mr * 16 + g * 4 + r;
        int col = bn + w * 32 + nr * 16 + li;
        if (row >= M) continue;
        float v = acc[mr][nr][r] + bias[col] + resid[(long)row * N + col];
        v = mask[row] ? v : 0.f;
        Cv[(long)row * N + col] = v;
      }
}

// ---------------------------------------------------------------------------
// Combined projection dispatch (R12-proven): KV tiles + Q tiles, bf16 A.
// ---------------------------------------------------------------------------
__global__ __launch_bounds__(256) void gemm_proj(
    const u16* __restrict__ Akv, const u16* __restrict__ Aq,
    const u16* __restrict__ WTbase, const float* __restrict__ biasK,
    const float* __restrict__ biasV, const float* __restrict__ biasQ,
    u16* __restrict__ Kh, u16* __restrict__ Vh, u16* __restrict__ Qb) {
  __shared__ short As[64][40];
  __shared__ short Bs[64][40];
  __shared__ u16 Ct[64][72];
  int bid = blockIdx.x;
  int tid = threadIdx.x;
  int lane = tid & 63, w = tid >> 6;
  int g = lane >> 4, li = lane & 15;
  int wr = w >> 1, wc = w & 1;
  f32x4 acc[2][2] = {};
  const long DD = (long)D * D;

  bool isKV = bid < KVBLK;
  int bm, bn, M;
  const u16* A;
  const u16* BT;
  if (isKV) {
    bn = (bid & 7) * 64;
    bm = (bid >> 3) * 64;
    M = KVROWS;
    A = Akv;
    BT = WTbase;
  } else {
    int qb = bid - KVBLK;
    bn = (qb & 3) * 64;
    bm = (qb >> 2) * 64;
    M = QROWS;
    A = Aq;
    BT = WTbase + 2 * DD;
  }

  int srow = tid >> 2, skc = (tid & 3) * 8;
  for (int k0 = 0; k0 < D; k0 += 32) {
    {
      int grow = bm + srow;
      bf16x8 av = {};
      if (grow < M)
        av = *reinterpret_cast<const bf16x8*>(A + (long)grow * D + k0 + skc);
      *reinterpret_cast<bf16x8*>(&As[srow][skc]) = av;
      bf16x8 bv = *reinterpret_cast<const bf16x8*>(
          BT + (long)(bn + srow) * D + k0 + skc);
      *reinterpret_cast<bf16x8*>(&Bs[srow][skc]) = bv;
    }
    __syncthreads();
    bf16x8 a0 = *reinterpret_cast<const bf16x8*>(&As[wr * 32 + li][g * 8]);
    bf16x8 a1 = *reinterpret_cast<const bf16x8*>(&As[wr * 32 + 16 + li][g * 8]);
    bf16x8 b0 = *reinterpret_cast<const bf16x8*>(&Bs[wc * 32 + li][g * 8]);
    bf16x8 b1 = *reinterpret_cast<const bf16x8*>(&Bs[wc * 32 + 16 + li][g * 8]);
    acc[0][0] = __builtin_amdgcn_mfma_f32_16x16x32_bf16(a0, b0, acc[0][0], 0, 0, 0);
    acc[0][1] = __builtin_amdgcn_mfma_f32_16x16x32_bf16(a0, b1, acc[0][1], 0, 0, 0);
    acc[1][0] = __builtin_amdgcn_mfma_f32_16x16x32_bf16(a1, b0, acc[1][0], 0, 0, 0);
    acc[1][1] = __builtin_amdgcn_mfma_f32_16x16x32_bf16(a1, b1, acc[1][1], 0, 0, 0);
    __syncthreads();
  }

  if (!isKV) {
#pragma unroll
    for (int mr = 0; mr < 2; ++mr)
#pragma unroll
      for (int nr = 0; nr < 2; ++nr)
#pragma unroll
        for (int r = 0; r < 4; ++r) {
          int row = bm + wr * 32 + mr * 16 + g * 4 + r;
          int col = bn + wc * 32 + nr * 16 + li;
          if (row >= M) continue;
          Qb[(long)row * D + col] = f2bs(acc[mr][nr][r] + biasQ[col]);
        }
  } else if (bn < 256) {
#pragma unroll
    for (int mr = 0; mr < 2; ++mr)
#pragma unroll
      for (int nr = 0; nr < 2; ++nr)
#pragma unroll
        for (int r = 0; r < 4; ++r) {
          int rowL = wr * 32 + mr * 16 + g * 4 + r;
          int colL = wc * 32 + nr * 16 + li;
          Ct[rowL][colL] = f2bs(acc[mr][nr][r] + biasK[bn + colL]);
        }
    __syncthreads();
#pragma unroll
    for (int p = 0; p < 2; ++p) {
      int rowL = (tid >> 3) + p * 32;
      int c8 = (tid & 7) * 8;
      int grow = bm + rowL;
      int b2 = grow >> 12, key = grow & (L - 1);
      int gcol = bn + c8;
      int hh = gcol >> 5, dd = gcol & (HD - 1);
      int cst = (dd >> 3) ^ ((key >> 1) & 3);
      u16* dst = Kh + (((long)(b2 * H + hh) * L + key) * 32 + (cst << 3));
      *reinterpret_cast<bf16x8*>(dst) =
          *reinterpret_cast<const bf16x8*>(&Ct[rowL][c8]);
    }
  } else {
    int vbn = bn - 256;
#pragma unroll
    for (int mr = 0; mr < 2; ++mr)
#pragma unroll
      for (int nr = 0; nr < 2; ++nr)
#pragma unroll
        for (int r = 0; r < 4; ++r) {
          int rowL = wr * 32 + mr * 16 + g * 4 + r;
          int colL = wc * 32 + nr * 16 + li;
          Ct[colL][rowL] = f2bs(acc[mr][nr][r] + biasV[vbn + colL]);
        }
    __syncthreads();
    int b2 = bm >> 12;
#pragma unroll
    for (int p = 0; p < 2; ++p) {
      int colL = (tid >> 3) + p * 32;
      int rem = tid & 7;
      int kb = rem >> 2, k8 = (rem & 3) * 8;
      int gcol = vbn + colL;
      int hh = gcol >> 5, dd = gcol & (HD - 1);
      int kb32 = ((bm & (L - 1)) >> 5) + kb;
      int j = (k8 >> 2) ^ ((dd >> 1) & 6);
      u16* dst = Vh + (((long)(b2 * H + hh) * (L / 32) + kb32) * 1024 +
                       dd * 32 + (j << 2));
      *reinterpret_cast<bf16x8*>(dst) =
          *reinterpret_cast<const bf16x8*>(&Ct[colL][kb * 32 + k8]);
    }
  }
}

// ---------------------------------------------------------------------------
// Fused flash attention (R16-proven 1.5-buffer pipeline) + T5 setprio around
// the MFMA clusters. 512 threads = 8 split-K waves per (b,h,32-q tile).
// ---------------------------------------------------------------------------
constexpr int POOLSZ = NSPLIT * 32 * 33 * 4 + NSPLIT * 32 * 4;  // 34816

__global__ __launch_bounds__(512) void attn_mfma(
    const u16* __restrict__ Qb, const u16* __restrict__ Kh,
    const u16* __restrict__ Vh, u16* __restrict__ AO) {
  __shared__ alignas(16) char pool[POOLSZ];
  int i = blockIdx.x;
  int xcd = i & 7, slot = i >> 3;          // 66 slots per XCD
  int bh = (xcd << 1) | (slot >= NQT ? 1 : 0);
  int qt = (slot >= NQT) ? slot - NQT : slot;
  int h = bh & 7;
  int b = bh >> 3;
  int tid = threadIdx.x, w = tid >> 6, lane = tid & 63;
  int g = lane >> 4, li = lane & 15;

  fr qf0, qf1;
  {
    const float QSC = 0.25509836048f;  // (1/sqrt(32)) * log2(e)
#pragma unroll
    for (int qb = 0; qb < 2; ++qb) {
      int qrow = qt * 32 + qb * 16 + li;
      if (qrow >= Q_MAX) qrow = Q_MAX - 1;
      bf16x8 raw = *reinterpret_cast<const bf16x8*>(
          Qb + ((long)(b * Q_MAX + qrow)) * D + h * HD + g * 8);
      fr& qf = qb ? qf1 : qf0;
#pragma unroll
      for (int j = 0; j < 4; ++j)
        qf.i[j] = (int)cvt_pk(bs2f((u16)raw[2 * j]) * QSC,
                              bs2f((u16)raw[2 * j + 1]) * QSC);
    }
  }

  f32x4 acc00 = {}, acc01 = {}, acc10 = {}, acc11 = {};
  float den0 = 0.f, den1 = 0.f;
  const f32x4 z = {};

  const u16* kbase = Kh + ((long)(b * H + h) * L) * HD;
  const u16* vbase = Vh + ((long)(b * H + h) * L) * HD;
  int kstart = w * KCHUNK;
  char* wbase = pool + w * 4096;  // wave-private single buffer (2KB K + 2KB V)

  int s_li = (li >> 1) & 3;
  int t_li = (li >> 1) & 6;
  int kof0 = li * 32 + ((g ^ s_li) << 3);
  int kof1 = (16 + li) * 32 + ((g ^ s_li) << 3);
  int va0o = li * 32 + ((g ^ t_li) << 2);
  int vb0o = li * 32 + (((4 + g) ^ t_li) << 2);
  int va1o = (16 + li) * 32 + ((g ^ t_li) << 2);
  int vb1o = (16 + li) * 32 + (((4 + g) ^ t_li) << 2);

  // prologue: issue K0 (2 loads) then V0 (2 loads)
  {
    const u16* ks = kbase + (long)kstart * HD + lane * 8;
    const u16* vs = vbase + (long)kstart * HD + lane * 8;
    u16* lk = (u16*)wbase;
    GLL16(ks, lk);
    GLL16(ks + 512, lk + 512);
    GLL16(vs, lk + 1024);
    GLL16(vs + 512, lk + 1536);
  }

  for (int t = 0; t < NT; ++t) {
    const u16* kl = (const u16*)wbase;
    const u16* vl = kl + 1024;

    asm volatile("s_waitcnt vmcnt(2)" ::: "memory");
    __builtin_amdgcn_sched_barrier(0);
    fr kf0, kf1;
    kf0.h = *reinterpret_cast<const bf16x8*>(kl + kof0);
    kf1.h = *reinterpret_cast<const bf16x8*>(kl + kof1);
    asm volatile("" ::"v"(kf0.i[0]), "v"(kf0.i[1]), "v"(kf0.i[2]),
                 "v"(kf0.i[3]), "v"(kf1.i[0]), "v"(kf1.i[1]), "v"(kf1.i[2]),
                 "v"(kf1.i[3]));
    asm volatile("s_waitcnt lgkmcnt(0)" ::: "memory");
    __builtin_amdgcn_sched_barrier(0);
    if (t + 1 < NT) {
      const u16* ks = kbase + (long)(kstart + (t + 1) * 32) * HD + lane * 8;
      u16* lk = (u16*)wbase;
      GLL16(ks, lk);
      GLL16(ks + 512, lk + 512);
    }

    __builtin_amdgcn_s_setprio(1);
    f32x4 s00 = __builtin_amdgcn_mfma_f32_16x16x32_bf16(kf0.h, qf0.h, z, 0, 0, 0);
    f32x4 s10 = __builtin_amdgcn_mfma_f32_16x16x32_bf16(kf1.h, qf0.h, z, 0, 0, 0);
    f32x4 s01 = __builtin_amdgcn_mfma_f32_16x16x32_bf16(kf0.h, qf1.h, z, 0, 0, 0);
    f32x4 s11 = __builtin_amdgcn_mfma_f32_16x16x32_bf16(kf1.h, qf1.h, z, 0, 0, 0);
    __builtin_amdgcn_s_setprio(0);

    float p00[4], p10[4], p01[4], p11[4];
#pragma unroll
    for (int r = 0; r < 4; ++r) {
      p00[r] = exp2f(s00[r]);
      p10[r] = exp2f(s10[r]);
      p01[r] = exp2f(s01[r]);
      p11[r] = exp2f(s11[r]);
      den0 += p00[r] + p10[r];
      den1 += p01[r] + p11[r];
    }
    fr pf0, pf1;
    pf0.i[0] = (int)cvt_pk(p00[0], p00[1]);
    pf0.i[1] = (int)cvt_pk(p00[2], p00[3]);
    pf0.i[2] = (int)cvt_pk(p10[0], p10[1]);
    pf0.i[3] = (int)cvt_pk(p10[2], p10[3]);
    pf1.i[0] = (int)cvt_pk(p01[0], p01[1]);
    pf1.i[1] = (int)cvt_pk(p01[2], p01[3]);
    pf1.i[2] = (int)cvt_pk(p11[0], p11[1]);
    pf1.i[3] = (int)cvt_pk(p11[2], p11[3]);

    if (t + 1 < NT)
      asm volatile("s_waitcnt vmcnt(2)" ::: "memory");
    else
      asm volatile("s_waitcnt vmcnt(0)" ::: "memory");
    __builtin_amdgcn_sched_barrier(0);
    uint2 va0 = *reinterpret_cast<const uint2*>(vl + va0o);
    uint2 vb0 = *reinterpret_cast<const uint2*>(vl + vb0o);
    uint2 va1 = *reinterpret_cast<const uint2*>(vl + va1o);
    uint2 vb1 = *reinterpret_cast<const uint2*>(vl + vb1o);
    asm volatile("" ::"v"(va0.x), "v"(va0.y), "v"(vb0.x), "v"(vb0.y),
                 "v"(va1.x), "v"(va1.y), "v"(vb1.x), "v"(vb1.y));
    asm volatile("s_waitcnt lgkmcnt(0)" ::: "memory");
    __builtin_amdgcn_sched_barrier(0);
    if (t + 1 < NT) {
      const u16* vs = vbase + (long)(kstart + (t + 1) * 32) * HD + lane * 8;
      u16* lk = (u16*)wbase;
      GLL16(vs, lk + 1024);
      GLL16(vs + 512, lk + 1536);
    }

    fr v0, v1;
    v0.i = (i32x4){(int)va0.x, (int)va0.y, (int)vb0.x, (int)vb0.y};
    v1.i = (i32x4){(int)va1.x, (int)va1.y, (int)vb1.x, (int)vb1.y};
    __builtin_amdgcn_s_setprio(1);
    acc00 = __builtin_amdgcn_mfma_f32_16x16x32_bf16(v0.h, pf0.h, acc00, 0, 0, 0);
    acc01 = __builtin_amdgcn_mfma_f32_16x16x32_bf16(v0.h, pf1.h, acc01, 0, 0, 0);
    acc10 = __builtin_amdgcn_mfma_f32_16x16x32_bf16(v1.h, pf0.h, acc10, 0, 0, 0);
    acc11 = __builtin_amdgcn_mfma_f32_16x16x32_bf16(v1.h, pf1.h, acc11, 0, 0, 0);
    __builtin_amdgcn_s_setprio(0);
  }

  den0 += __shfl_xor(den0, 16, 64);
  den0 += __shfl_xor(den0, 32, 64);
  den1 += __shfl_xor(den1, 16, 64);
  den1 += __shfl_xor(den1, 32, 64);

  __syncthreads();
  float(*accs)[32][33] = (float(*)[32][33])pool;
  float(*dsh)[32] = (float(*)[32])(pool + NSPLIT * 32 * 33 * 4);
#pragma unroll
  for (int r = 0; r < 4; ++r) {
    accs[w][g * 4 + r][li] = acc00[r];
    accs[w][g * 4 + r][16 + li] = acc01[r];
    accs[w][16 + g * 4 + r][li] = acc10[r];
    accs[w][16 + g * 4 + r][16 + li] = acc11[r];
  }
  if (g == 0) {
    dsh[w][li] = den0;
    dsh[w][16 + li] = den1;
  }
  __syncthreads();

  int q = tid >> 4, dp = tid & 15;
  float Den = 0.f, o0 = 0.f, o1 = 0.f;
#pragma unroll
  for (int ww = 0; ww < NSPLIT; ++ww) {
    Den += dsh[ww][q];
    o0 += accs[ww][2 * dp][q];
    o1 += accs[ww][2 * dp + 1][q];
  }
  float inv = 1.f / Den;
  int qrow = qt * 32 + q;
  if (qrow < Q_MAX) {
    unsigned pk = cvt_pk(o0 * inv, o1 * inv);
    *reinterpret_cast<unsigned*>(
        AO + ((long)(b * Q_MAX + qrow)) * D + h * HD + 2 * dp) = pk;
  }
}

// ---------------------------------------------------------------------------
// Merged head: input = q_stream[inv] if selected else enc row.
// ---------------------------------------------------------------------------
__global__ __launch_bounds__(256) void head_kernel(
    const float* __restrict__ enc, const float* __restrict__ q_stream,
    const int* __restrict__ inv, const float* __restrict__ hW,
    const float* __restrict__ hb, float* __restrict__ out) {
  int row = blockIdx.x * 4 + (threadIdx.x >> 6);
  int lane = threadIdx.x & 63;
  int slot = inv[row];
  const float* src =
      (slot >= 0) ? (q_stream + (long)slot * D) : (enc + (long)row * D);
  const float4 a = *reinterpret_cast<const float4*>(src + lane * 4);
  float c0 = 0.f, c1 = 0.f, c2 = 0.f;
  const float av[4] = {a.x, a.y, a.z, a.w};
#pragma unroll
  for (int i = 0; i < 4; ++i) {
    int k = lane * 4 + i;
    c0 += av[i] * hW[k * 3];
    c1 += av[i] * hW[k * 3 + 1];
    c2 += av[i] * hW[k * 3 + 2];
  }
#pragma unroll
  for (int off = 32; off; off >>= 1) {
    c0 += __shfl_down(c0, off, 64);
    c1 += __shfl_down(c1, off, 64);
    c2 += __shfl_down(c2, off, 64);
  }
  if (lane == 0) {
    out[(long)row * 3] = c0 + hb[0];
    out[(long)row * 3 + 1] = c1 + hb[1];
    out[(long)row * 3 + 2] = c2 + hb[2];
  }
}

// ---------------------------------------------------------------------------
extern "C" void kernel_launch(void* const* d_in, const int* in_sizes, int n_in,
                              void* d_out, int out_size, void* d_ws,
                              size_t ws_size, hipStream_t stream) {
  const float* enc = (const float*)d_in[0];
  const float* clog = (const float*)d_in[1];
  const float* ln_q_g = (const float*)d_in[2];
  const float* ln_q_b = (const float*)d_in[3];
  const float* ln_kv_g = (const float*)d_in[4];
  const float* ln_kv_b = (const float*)d_in[5];
  const float* Wq = (const float*)d_in[6];
  const float* bq = (const float*)d_in[7];
  const float* Wk = (const float*)d_in[8];
  const float* bk = (const float*)d_in[9];
  const float* Wv = (const float*)d_in[10];
  const float* bv = (const float*)d_in[11];
  const float* Wo = (const float*)d_in[12];
  const float* bo = (const float*)d_in[13];
  const float* ffn_g = (const float*)d_in[14];
  const float* ffn_b = (const float*)d_in[15];
  const float* W1 = (const float*)d_in[16];
  const float* b1 = (const float*)d_in[17];
  const float* W2 = (const float*)d_in[18];
  const float* b2 = (const float*)d_in[19];
  const float* head_W = (const float*)d_in[20];
  const float* head_b = (const float*)d_in[21];
  float* out = (float*)d_out;

  char* ws = (char*)d_ws;
  float* q_stream = (float*)ws;            ws += (long)QROWS * D * 4;
  u16* kvl0 = (u16*)ws;                    ws += (long)KVROWS * D * 2;
  u16* kvl1 = (u16*)ws;                    ws += (long)KVROWS * D * 2;
  u16* Khbuf = (u16*)ws;                   ws += (long)B * H * L * HD * 2;
  u16* Vhbuf = (u16*)ws;                   ws += (long)B * H * L * HD * 2;
  u16* q_ln = (u16*)ws;                    ws += (long)QROWS * D * 2;
  u16* Qbuf = (u16*)ws;                    ws += (long)QROWS * D * 2;
  u16* AObuf = (u16*)ws;                   ws += (long)QROWS * D * 2;
  u16* H1buf = (u16*)ws;                   ws += (long)QROWS * FF * 2;
  u16* WT = (u16*)ws;                      ws += (long)NL * (4 * D * D + 2 * D * FF) * 2;
  int* idxbuf = (int*)ws;                  ws += QROWS * 4;
  int* maskbuf = (int*)ws;                 ws += QROWS * 4;
  int* invbuf = (int*)ws;                  ws += (long)B * L * 4;

  const long DD = (long)D * D, DFF = (long)D * FF;
  const long LSTR = 4 * DD + 2 * DFF;

  setup_kernel<<<LNBLK + TRBLK + B, 256, 0, stream>>>(
      enc, clog, ln_kv_g, ln_kv_b, Wq, Wk, Wv, Wo, W1, W2, WT, kvl0, kvl1,
      idxbuf, maskbuf, invbuf);
  gather_ln<<<QROWS / 4, 256, 0, stream>>>(enc, idxbuf, q_stream, q_ln,
                                           ln_q_g, ln_q_b);

  for (int l = 0; l < NL; ++l) {
    u16* base = WT + l * LSTR;
    u16* kv_ln = (l == 0) ? kvl0 : kvl1;

    if (l > 0)
      ln_bf16<<<QROWS / 4, 256, 0, stream>>>(q_stream, q_ln, ln_q_g + l * D,
                                             ln_q_b + l * D);

    gemm_proj<<<KVBLK + QBLK, 256, 0, stream>>>(
        kv_ln, q_ln, base, bk + l * D, bv + l * D, bq + l * D, Khbuf, Vhbuf,
        Qbuf);

    attn_mfma<<<B * H * NQT, 512, 0, stream>>>(Qbuf, Khbuf, Vhbuf, AObuf);

    // O-proj: 32-row tiles, grid (4,65)=260 blocks (full-GPU occupancy)
    gemm_mfma32<<<dim3(D / 64, MRB32), 128, 0, stream>>>(
        AObuf, base + 3 * DD, bo + l * D, q_stream, q_stream, maskbuf, QROWS,
        D, D);

    ln_bf16<<<QROWS / 4, 256, 0, stream>>>(q_stream, q_ln, ffn_g + l * D,
                                           ffn_b + l * D);
    dim3 gF1(FF / 64, (QROWS + 63) / 64);
    gemm_mfma<1><<<gF1, 256, 0, stream>>>(q_ln, base + 4 * DD, b1 + l * FF,
                                          (void*)H1buf, nullptr, nullptr,
                                          QROWS, FF, D);
    // FFN2: 32-row tiles, grid (4,65)=260 blocks
    gemm_mfma32<<<dim3(D / 64, MRB32), 128, 0, stream>>>(
        H1buf, base + 4 * DD + DFF, b2 + l * D, q_stream, q_stream, maskbuf,
        QROWS, D, FF);
  }

  head_kernel<<<KVROWS / 4, 256, 0, stream>>>(enc, q_stream, invbuf, head_W,
                                              head_b, out);
}

// Round 20
// 207.515 us; speedup vs baseline: 1.3950x; 1.0124x over previous
//
#include <hip/hip_runtime.h>
#include <cmath>

constexpr int B = 2, L = 4096, D = 256, H = 8, NC = 3;
constexpr int TOP_N = 8, R = 32;
constexpr int LS = 1000, LE = 3000;
constexpr int NL = 2;
constexpr int FF = 4 * D;                        // 1024
constexpr int Q_MAX = 2 * TOP_N * (2 * R + 1);   // 1040
constexpr int HD = D / H;                        // 32
constexpr int QROWS = B * Q_MAX;                 // 2080
constexpr int KVROWS = B * L;                    // 8192
constexpr int NQT = (Q_MAX + 31) / 32;           // 33 q-tiles of 32
constexpr int NREG = LE - LS;                    // 2000
constexpr int NSPLIT = 8;                        // split-K waves per block
constexpr int KCHUNK = L / NSPLIT;               // 512 keys per wave
constexpr int NT = KCHUNK / 32;                  // 16 iterations
constexpr int KVBLK = 8 * (KVROWS / 64);         // 1024 blocks (KV part)
constexpr int QBLK = 4 * ((QROWS + 63) / 64);    // 132 blocks (Q part)
constexpr int TRBLK = NL * 192;                  // 384 transpose blocks
constexpr int LNBLK = KVROWS / 4;                // 2048 LN blocks (4 rows ea)
constexpr int MRB32 = QROWS / 32;                // 65 row-blocks of 32

typedef __attribute__((ext_vector_type(8))) short bf16x8;
typedef __attribute__((ext_vector_type(4))) float f32x4;
typedef __attribute__((ext_vector_type(4))) int i32x4;
typedef unsigned short u16;

union fr {
  bf16x8 h;
  i32x4 i;
};

__device__ __forceinline__ u16 f2bs(float f) {
  unsigned int u = __float_as_uint(f);
  unsigned int r = u + 0x7fffu + ((u >> 16) & 1u);
  return (u16)(r >> 16);
}
__device__ __forceinline__ float bs2f(u16 s) {
  return __uint_as_float(((unsigned int)s) << 16);
}
__device__ __forceinline__ float gelu_exact(float x) {
  return 0.5f * x * (1.f + erff(x * 0.70710678118654752440f));
}
__device__ __forceinline__ unsigned cvt_pk(float lo, float hi) {
  unsigned r;
  asm("v_cvt_pk_bf16_f32 %0, %1, %2" : "=v"(r) : "v"(lo), "v"(hi));
  return r;
}

#define GLL16(gsrc, ldst)                                                   \
  __builtin_amdgcn_global_load_lds(                                         \
      (const __attribute__((address_space(1))) unsigned int*)(gsrc),        \
      (__attribute__((address_space(3))) unsigned int*)(ldst), 16, 0, 0)

// Wave-level row LayerNorm helper: lane holds float4 (cols lane*4..lane*4+3).
__device__ __forceinline__ void wave_ln_stats(float4 v, float& mean,
                                              float& rstd) {
  float s1 = v.x + v.y + v.z + v.w;
  float s2 = v.x * v.x + v.y * v.y + v.z * v.z + v.w * v.w;
#pragma unroll
  for (int off = 32; off; off >>= 1) {
    s1 += __shfl_xor(s1, off, 64);
    s2 += __shfl_xor(s2, off, 64);
  }
  mean = s1 * (1.f / D);
  float var = fmaxf(s2 * (1.f / D) - mean * mean, 0.f);
  rstd = rsqrtf(var + 1e-5f);
}

// ---------------------------------------------------------------------------
// Merged setup dispatch (256 threads/block): LN(enc) x2 | W transpose | select
// ---------------------------------------------------------------------------
__global__ __launch_bounds__(256) void setup_kernel(
    const float* __restrict__ enc, const float* __restrict__ logits,
    const float* __restrict__ lnkvg, const float* __restrict__ lnkvb,
    const float* __restrict__ Wq_, const float* __restrict__ Wk_,
    const float* __restrict__ Wv_, const float* __restrict__ Wo_,
    const float* __restrict__ W1_, const float* __restrict__ W2_,
    u16* __restrict__ WT, u16* __restrict__ o0, u16* __restrict__ o1,
    int* __restrict__ idx_out, int* __restrict__ mask_out,
    int* __restrict__ inv_out) {
  int bid = blockIdx.x;
  int tid = threadIdx.x;
  const long DD = (long)D * D, DFF = (long)D * FF;
  const long LSTR = 4 * DD + 2 * DFF;

  if (bid < LNBLK) {
    long row = (long)bid * 4 + (tid >> 6);
    int lane = tid & 63;
    float4 v = *reinterpret_cast<const float4*>(enc + row * D + lane * 4);
    float mean, rstd;
    wave_ln_stats(v, mean, rstd);
    float n0 = (v.x - mean) * rstd, n1 = (v.y - mean) * rstd,
          n2 = (v.z - mean) * rstd, n3 = (v.w - mean) * rstd;
    int c = lane * 4;
    float4 g0 = *reinterpret_cast<const float4*>(lnkvg + c);
    float4 b0v = *reinterpret_cast<const float4*>(lnkvb + c);
    float4 g1 = *reinterpret_cast<const float4*>(lnkvg + D + c);
    float4 b1v = *reinterpret_cast<const float4*>(lnkvb + D + c);
    uint2 w0 = {cvt_pk(n0 * g0.x + b0v.x, n1 * g0.y + b0v.y),
                cvt_pk(n2 * g0.z + b0v.z, n3 * g0.w + b0v.w)};
    uint2 w1 = {cvt_pk(n0 * g1.x + b1v.x, n1 * g1.y + b1v.y),
                cvt_pk(n2 * g1.z + b1v.z, n3 * g1.w + b1v.w)};
    *reinterpret_cast<uint2*>(o0 + row * D + c) = w0;
    *reinterpret_cast<uint2*>(o1 + row * D + c) = w1;
    return;
  }

  if (bid < LNBLK + TRBLK) {
    __shared__ u16 T[64][65];
    int t = bid - LNBLK;
    int l = t / 192, r = t % 192;
    const float* src;
    long dbase;
    int K_, N_, kt, nt;
    if (r < 64) {
      int which = r >> 4, sub = r & 15;
      kt = sub >> 2;
      nt = sub & 3;
      K_ = 256;
      N_ = 256;
      src = (which == 0 ? Wk_ : which == 1 ? Wv_ : which == 2 ? Wq_ : Wo_) +
            (long)l * DD;
      dbase = (long)l * LSTR + (long)which * DD;
    } else if (r < 128) {
      int sub = r - 64;
      kt = sub >> 4;
      nt = sub & 15;
      K_ = 256;
      N_ = 1024;
      src = W1_ + (long)l * DFF;
      dbase = (long)l * LSTR + 4 * DD;
    } else {
      int sub = r - 128;
      kt = sub >> 2;
      nt = sub & 3;
      K_ = 1024;
      N_ = 256;
      src = W2_ + (long)l * DFF;
      dbase = (long)l * LSTR + 4 * DD + DFF;
    }
    int k0 = kt * 64, n0 = nt * 64;
    {
      int kr = tid >> 2, c16 = (tid & 3) * 16;
      const float* sp = src + (long)(k0 + kr) * N_ + n0 + c16;
#pragma unroll
      for (int i = 0; i < 4; ++i) {
        float4 v = *reinterpret_cast<const float4*>(sp + 4 * i);
        T[kr][c16 + 4 * i + 0] = f2bs(v.x);
        T[kr][c16 + 4 * i + 1] = f2bs(v.y);
        T[kr][c16 + 4 * i + 2] = f2bs(v.z);
        T[kr][c16 + 4 * i + 3] = f2bs(v.w);
      }
    }
    __syncthreads();
    {
      int nr = tid >> 2, kc = (tid & 3) * 16;
      u16 tmp[16];
#pragma unroll
      for (int j = 0; j < 16; ++j) tmp[j] = T[kc + j][nr];
      u16* dp = WT + dbase + (long)(n0 + nr) * K_ + k0 + kc;
      *reinterpret_cast<bf16x8*>(dp) = *reinterpret_cast<const bf16x8*>(&tmp[0]);
      *reinterpret_cast<bf16x8*>(dp + 8) =
          *reinterpret_cast<const bf16x8*>(&tmp[8]);
    }
    return;
  }

  // ---- select part (one block per batch), 256 threads = 4 waves
  {
    int b = bid - LNBLK - TRBLK;
    int w = tid >> 6, lane = tid & 63;
    __shared__ float candv[4][8];
    __shared__ int candi[4][8];
    __shared__ int centers[2 * TOP_N];
    __shared__ unsigned present[L / 32];
    __shared__ int offs[128];
    __shared__ int wtot[2];

    float vd[8], va[8];
#pragma unroll
    for (int j = 0; j < 8; ++j) {
      int p = tid + j * 256;
      if (p < NREG) {
        const float* lg = logits + ((long)b * L + LS + p) * NC;
        float x0 = lg[0], x1 = lg[1], x2 = lg[2];
        float m = fmaxf(x0, fmaxf(x1, x2));
        float lse = m + logf(expf(x0 - m) + expf(x1 - m) + expf(x2 - m));
        vd[j] = x2 - lse;
        va[j] = x1 - lse;
      } else {
        vd[j] = -INFINITY;
        va[j] = -INFINITY;
      }
    }
    if (tid < 128) present[tid] = 0;
    for (int j = tid; j < L; j += 256) inv_out[(long)b * L + j] = -1;

    for (int sel = 0; sel < 2; ++sel) {
      float v[8];
#pragma unroll
      for (int j = 0; j < 8; ++j) v[j] = (sel == 0) ? vd[j] : va[j];
#pragma unroll
      for (int r = 0; r < TOP_N; ++r) {
        float mv = v[0];
        int mp = tid;
#pragma unroll
        for (int j = 1; j < 8; ++j) {
          int pj = tid + j * 256;
          if (v[j] > mv) { mv = v[j]; mp = pj; }
        }
#pragma unroll
        for (int off = 32; off; off >>= 1) {
          float ov = __shfl_xor(mv, off, 64);
          int oi = __shfl_xor(mp, off, 64);
          if (ov > mv || (ov == mv && oi < mp)) { mv = ov; mp = oi; }
        }
#pragma unroll
        for (int j = 0; j < 8; ++j)
          if (tid + j * 256 == mp) v[j] = -INFINITY;
        if (lane == 0) { candv[w][r] = mv; candi[w][r] = mp; }
      }
      __syncthreads();
      if (tid < 64) {
        float c = (tid < 32) ? candv[tid >> 3][tid & 7] : -INFINITY;
        int ci = (tid < 32) ? candi[tid >> 3][tid & 7] : 0x7fffffff;
#pragma unroll
        for (int r = 0; r < TOP_N; ++r) {
          float mv = c;
          int mi = ci;
#pragma unroll
          for (int off = 32; off; off >>= 1) {
            float ov = __shfl_xor(mv, off, 64);
            int oi = __shfl_xor(mi, off, 64);
            if (ov > mv || (ov == mv && oi < mi)) { mv = ov; mi = oi; }
          }
          if (ci == mi) c = -INFINITY;
          if (tid == 0) centers[sel * TOP_N + r] = LS + mi;
        }
      }
      __syncthreads();
    }

    for (int j = tid; j < Q_MAX; j += 256) {
      int c = centers[j / (2 * R + 1)];
      int off = j % (2 * R + 1) - R;
      int v2 = c + off;
      v2 = v2 < 0 ? 0 : (v2 > L - 1 ? L - 1 : v2);
      atomicOr(&present[v2 >> 5], 1u << (v2 & 31));
    }
    __syncthreads();

    int cnt = (tid < 128) ? __popc(present[tid]) : 0;
    if (tid < 128) {
      int x = cnt;
#pragma unroll
      for (int off = 1; off < 64; off <<= 1) {
        int o = __shfl_up(x, off, 64);
        if ((tid & 63) >= off) x += o;
      }
      if ((tid & 63) == 63) wtot[tid >> 6] = x;
      offs[tid] = x - cnt;
    }
    __syncthreads();
    int total = wtot[0] + wtot[1];
    if (tid < 128) {
      int base = offs[tid] + ((tid >= 64) ? wtot[0] : 0);
      unsigned mword = present[tid];
      while (mword) {
        int i = __ffs(mword) - 1;
        mword &= mword - 1;
        int pos = tid * 32 + i;
        idx_out[b * Q_MAX + base] = pos;
        mask_out[b * Q_MAX + base] = 1;
        inv_out[(long)b * L + pos] = b * Q_MAX + base;
        ++base;
      }
    }
    for (int j = total + tid; j < Q_MAX; j += 256) {
      idx_out[b * Q_MAX + j] = L;
      mask_out[b * Q_MAX + j] = 0;
    }
  }
}

// ---------------------------------------------------------------------------
// Gather + layer-0 Q-LN fused, wave-per-row. Grid QROWS/4.
// ---------------------------------------------------------------------------
__global__ __launch_bounds__(256) void gather_ln(
    const float* __restrict__ enc, const int* __restrict__ idx,
    float* __restrict__ q_stream, u16* __restrict__ q_ln,
    const float* __restrict__ gg, const float* __restrict__ bb) {
  int row = blockIdx.x * 4 + (threadIdx.x >> 6);
  int lane = threadIdx.x & 63;
  int b = row / Q_MAX;
  int p = idx[row];
  int c = lane * 4;
  float4 v = {0.f, 0.f, 0.f, 0.f};
  if (p < L) v = *reinterpret_cast<const float4*>(enc + ((long)b * L + p) * D + c);
  *reinterpret_cast<float4*>(q_stream + (long)row * D + c) = v;
  float mean, rstd;
  wave_ln_stats(v, mean, rstd);
  float4 g = *reinterpret_cast<const float4*>(gg + c);
  float4 bt = *reinterpret_cast<const float4*>(bb + c);
  uint2 w = {cvt_pk((v.x - mean) * rstd * g.x + bt.x,
                    (v.y - mean) * rstd * g.y + bt.y),
             cvt_pk((v.z - mean) * rstd * g.z + bt.z,
                    (v.w - mean) * rstd * g.w + bt.w)};
  *reinterpret_cast<uint2*>(q_ln + (long)row * D + c) = w;
}

// ---------------------------------------------------------------------------
// Wave-per-row LayerNorm fp32 -> bf16. Grid M/4.
// ---------------------------------------------------------------------------
__global__ __launch_bounds__(256) void ln_bf16(
    const float* __restrict__ in, u16* __restrict__ out,
    const float* __restrict__ gg, const float* __restrict__ bb) {
  long row = (long)blockIdx.x * 4 + (threadIdx.x >> 6);
  int lane = threadIdx.x & 63;
  int c = lane * 4;
  float4 v = *reinterpret_cast<const float4*>(in + row * D + c);
  float mean, rstd;
  wave_ln_stats(v, mean, rstd);
  float4 g = *reinterpret_cast<const float4*>(gg + c);
  float4 bt = *reinterpret_cast<const float4*>(bb + c);
  uint2 w = {cvt_pk((v.x - mean) * rstd * g.x + bt.x,
                    (v.y - mean) * rstd * g.y + bt.y),
             cvt_pk((v.z - mean) * rstd * g.z + bt.z,
                    (v.w - mean) * rstd * g.w + bt.w)};
  *reinterpret_cast<uint2*>(out + row * D + c) = w;
}

// ---------------------------------------------------------------------------
// bf16 MFMA GEMM (64x64 tile, BK=32, 4 waves). EPI 1: gelu->bf16.
// ---------------------------------------------------------------------------
template <int EPI>
__global__ __launch_bounds__(256) void gemm_mfma(
    const u16* __restrict__ A, const u16* __restrict__ BT,
    const float* __restrict__ bias, void* __restrict__ Cv,
    const float* __restrict__ resid, const int* __restrict__ mask, int M,
    int N, int K) {
  __shared__ short As[64][40];
  __shared__ short Bs[64][40];
  int bm = blockIdx.y * 64, bn = blockIdx.x * 64;
  int tid = threadIdx.x;
  int lane = tid & 63, w = tid >> 6;
  int g = lane >> 4, li = lane & 15;
  int wr = w >> 1, wc = w & 1;
  f32x4 acc[2][2] = {};

  int srow = tid >> 2, skc = (tid & 3) * 8;
  for (int k0 = 0; k0 < K; k0 += 32) {
    {
      int grow = bm + srow;
      bf16x8 av = {};
      if (grow < M)
        av = *reinterpret_cast<const bf16x8*>(A + (long)grow * K + k0 + skc);
      *reinterpret_cast<bf16x8*>(&As[srow][skc]) = av;
      bf16x8 bv = *reinterpret_cast<const bf16x8*>(
          BT + (long)(bn + srow) * K + k0 + skc);
      *reinterpret_cast<bf16x8*>(&Bs[srow][skc]) = bv;
    }
    __syncthreads();
    bf16x8 a0 = *reinterpret_cast<const bf16x8*>(&As[wr * 32 + li][g * 8]);
    bf16x8 a1 = *reinterpret_cast<const bf16x8*>(&As[wr * 32 + 16 + li][g * 8]);
    bf16x8 b0 = *reinterpret_cast<const bf16x8*>(&Bs[wc * 32 + li][g * 8]);
    bf16x8 b1 = *reinterpret_cast<const bf16x8*>(&Bs[wc * 32 + 16 + li][g * 8]);
    acc[0][0] = __builtin_amdgcn_mfma_f32_16x16x32_bf16(a0, b0, acc[0][0], 0, 0, 0);
    acc[0][1] = __builtin_amdgcn_mfma_f32_16x16x32_bf16(a0, b1, acc[0][1], 0, 0, 0);
    acc[1][0] = __builtin_amdgcn_mfma_f32_16x16x32_bf16(a1, b0, acc[1][0], 0, 0, 0);
    acc[1][1] = __builtin_amdgcn_mfma_f32_16x16x32_bf16(a1, b1, acc[1][1], 0, 0, 0);
    __syncthreads();
  }

#pragma unroll
  for (int mr = 0; mr < 2; ++mr)
#pragma unroll
    for (int nr = 0; nr < 2; ++nr)
#pragma unroll
      for (int r = 0; r < 4; ++r) {
        int row = bm + wr * 32 + mr * 16 + g * 4 + r;
        int col = bn + wc * 32 + nr * 16 + li;
        if (row >= M) continue;
        float v = acc[mr][nr][r] + bias[col];
        if (EPI == 1) v = gelu_exact(v);
        if (EPI == 2) {
          v += resid[(long)row * N + col];
          v = mask[row] ? v : 0.f;
          ((float*)Cv)[(long)row * N + col] = v;
        } else {
          ((u16*)Cv)[(long)row * N + col] = f2bs(v);
        }
      }
}

// ---------------------------------------------------------------------------
// 32-row-tile bf16 MFMA GEMM (O-proj, FFN2): 128 threads = 2 waves, grid
// (N/64, 65) = 260 blocks. EPI2: C = mask ? resid + x + bias : 0 (f32).
// ---------------------------------------------------------------------------
__global__ __launch_bounds__(128) void gemm_mfma32(
    const u16* __restrict__ A, const u16* __restrict__ BT,
    const float* __restrict__ bias, float* __restrict__ Cv,
    const float* __restrict__ resid, const int* __restrict__ mask, int M,
    int N, int K) {
  __shared__ short As[32][40];
  __shared__ short Bs[64][40];
  int bm = blockIdx.y * 32, bn = blockIdx.x * 64;
  int tid = threadIdx.x;
  int lane = tid & 63, w = tid >> 6;
  int g = lane >> 4, li = lane & 15;
  f32x4 acc[2][2] = {};

  int srow = tid >> 2, skc = (tid & 3) * 8;  // srow 0..31
  for (int k0 = 0; k0 < K; k0 += 32) {
    {
      bf16x8 av = *reinterpret_cast<const bf16x8*>(
          A + (long)(bm + srow) * K + k0 + skc);
      *reinterpret_cast<bf16x8*>(&As[srow][skc]) = av;
      bf16x8 bv0 = *reinterpret_cast<const bf16x8*>(
          BT + (long)(bn + srow) * K + k0 + skc);
      *reinterpret_cast<bf16x8*>(&Bs[srow][skc]) = bv0;
      bf16x8 bv1 = *reinterpret_cast<const bf16x8*>(
          BT + (long)(bn + 32 + srow) * K + k0 + skc);
      *reinterpret_cast<bf16x8*>(&Bs[32 + srow][skc]) = bv1;
    }
    __syncthreads();
    bf16x8 a0 = *reinterpret_cast<const bf16x8*>(&As[li][g * 8]);
    bf16x8 a1 = *reinterpret_cast<const bf16x8*>(&As[16 + li][g * 8]);
    bf16x8 b0 = *reinterpret_cast<const bf16x8*>(&Bs[w * 32 + li][g * 8]);
    bf16x8 b1 = *reinterpret_cast<const bf16x8*>(&Bs[w * 32 + 16 + li][g * 8]);
    acc[0][0] = __builtin_amdgcn_mfma_f32_16x16x32_bf16(a0, b0, acc[0][0], 0, 0, 0);
    acc[0][1] = __builtin_amdgcn_mfma_f32_16x16x32_bf16(a0, b1, acc[0][1], 0, 0, 0);
    acc[1][0] = __builtin_amdgcn_mfma_f32_16x16x32_bf16(a1, b0, acc[1][0], 0, 0, 0);
    acc[1][1] = __builtin_amdgcn_mfma_f32_16x16x32_bf16(a1, b1, acc[1][1], 0, 0, 0);
    __syncthreads();
  }

#pragma unroll
  for (int mr = 0; mr < 2; ++mr)
#pragma unroll
    for (int nr = 0; nr < 2; ++nr)
#pragma unroll
      for (int r = 0; r < 4; ++r) {
        int row = bm + mr * 16 + g * 4 + r;
        int col = bn + w * 32 + nr * 16 + li;
        if (row >= M) continue;
        float v = acc[mr][nr][r] + bias[col] + resid[(long)row * N + col];
        v = mask[row] ? v : 0.f;
        Cv[(long)row * N + col] = v;
      }
}

// ---------------------------------------------------------------------------
// Combined projection dispatch, DMA-staged + XOR-swizzled + double-buffered:
//   - A/B tiles staged via global_load_lds width-16 (1 DMA of 4KB per tile).
//   - LDS slot [row][c] holds global chunk c ^ ((row>>1)&3); DMA dest linear,
//     swizzle applied to global source address + ds_read offsets (rule #21).
//   - K-loop double-buffered: lgkmcnt(0)+vmcnt(0)+barrier, issue next tile,
//     then ds_read+MFMA on current (DMA latency hidden under MFMA phase).
// ---------------------------------------------------------------------------
__global__ __launch_bounds__(256) void gemm_proj(
    const u16* __restrict__ Akv, const u16* __restrict__ Aq,
    const u16* __restrict__ WTbase, const float* __restrict__ biasK,
    const float* __restrict__ biasV, const float* __restrict__ biasQ,
    u16* __restrict__ Kh, u16* __restrict__ Vh, u16* __restrict__ Qb) {
  __shared__ alignas(16) u16 Asb[2][2048];  // 8 KB
  __shared__ alignas(16) u16 Bsb[2][2048];  // 8 KB
  __shared__ u16 Ct[64][72];                // 9.2 KB
  int bid = blockIdx.x;
  int tid = threadIdx.x;
  int lane = tid & 63, w = tid >> 6;
  int g = lane >> 4, li = lane & 15;
  int wr = w >> 1, wc = w & 1;
  f32x4 acc[2][2] = {};
  const long DD = (long)D * D;

  bool isKV = bid < KVBLK;
  int bm, bn, M;
  const u16* A;
  const u16* BT;
  if (isKV) {
    bn = (bid & 7) * 64;
    bm = (bid >> 3) * 64;
    M = KVROWS;
    A = Akv;
    BT = WTbase;
  } else {
    int qb = bid - KVBLK;
    bn = (qb & 3) * 64;
    bm = (qb >> 2) * 64;
    M = QROWS;
    A = Aq;
    BT = WTbase + 2 * DD;
  }

  // staging: thread covers LDS slot (row = w*16 + (lane>>2), c = lane&3);
  // global chunk fetched = c ^ ((row>>1)&3); LDS dest = wave base + lane*16B.
  int srow = w * 16 + (lane >> 2);
  int sgo = (((lane & 3) ^ ((srow >> 1) & 3)) << 3);  // u16 units
  const u16* aRow = A + (long)(bm + srow) * D + sgo;
  const u16* bRow = BT + (long)(bn + srow) * D + sgo;

  // fragment read offsets (u16 units); (row+16)>>1 & 3 == row>>1 & 3 (+8≡0)
  int ra = wr * 32 + li;
  int ofA0 = ra * 32 + ((g ^ ((ra >> 1) & 3)) << 3);
  int ofA1 = ofA0 + 16 * 32;
  int rb = wc * 32 + li;
  int ofB0 = rb * 32 + ((g ^ ((rb >> 1) & 3)) << 3);
  int ofB1 = ofB0 + 16 * 32;

  // prologue: stage k-step 0 into buffer 0
  GLL16(aRow, Asb[0] + w * 512);
  GLL16(bRow, Bsb[0] + w * 512);

#pragma unroll 1
  for (int ks = 0; ks < D / 32; ++ks) {
    asm volatile("s_waitcnt lgkmcnt(0)" ::: "memory");
    asm volatile("s_waitcnt vmcnt(0)" ::: "memory");
    __builtin_amdgcn_sched_barrier(0);
    __builtin_amdgcn_s_barrier();
    if (ks + 1 < D / 32) {
      GLL16(aRow + (ks + 1) * 32, Asb[(ks + 1) & 1] + w * 512);
      GLL16(bRow + (ks + 1) * 32, Bsb[(ks + 1) & 1] + w * 512);
    }
    const u16* Ab = Asb[ks & 1];
    const u16* Bb = Bsb[ks & 1];
    bf16x8 a0 = *reinterpret_cast<const bf16x8*>(Ab + ofA0);
    bf16x8 a1 = *reinterpret_cast<const bf16x8*>(Ab + ofA1);
    bf16x8 b0 = *reinterpret_cast<const bf16x8*>(Bb + ofB0);
    bf16x8 b1 = *reinterpret_cast<const bf16x8*>(Bb + ofB1);
    __builtin_amdgcn_s_setprio(1);
    acc[0][0] = __builtin_amdgcn_mfma_f32_16x16x32_bf16(a0, b0, acc[0][0], 0, 0, 0);
    acc[0][1] = __builtin_amdgcn_mfma_f32_16x16x32_bf16(a0, b1, acc[0][1], 0, 0, 0);
    acc[1][0] = __builtin_amdgcn_mfma_f32_16x16x32_bf16(a1, b0, acc[1][0], 0, 0, 0);
    acc[1][1] = __builtin_amdgcn_mfma_f32_16x16x32_bf16(a1, b1, acc[1][1], 0, 0, 0);
    __builtin_amdgcn_s_setprio(0);
  }
  // all waves' last ds_reads complete before Ct reuse / exit
  asm volatile("s_waitcnt lgkmcnt(0)" ::: "memory");
  __builtin_amdgcn_s_barrier();

  if (!isKV) {
#pragma unroll
    for (int mr = 0; mr < 2; ++mr)
#pragma unroll
      for (int nr = 0; nr < 2; ++nr)
#pragma unroll
        for (int r = 0; r < 4; ++r) {
          int row = bm + wr * 32 + mr * 16 + g * 4 + r;
          int col = bn + wc * 32 + nr * 16 + li;
          if (row >= M) continue;
          Qb[(long)row * D + col] = f2bs(acc[mr][nr][r] + biasQ[col]);
        }
  } else if (bn < 256) {
#pragma unroll
    for (int mr = 0; mr < 2; ++mr)
#pragma unroll
      for (int nr = 0; nr < 2; ++nr)
#pragma unroll
        for (int r = 0; r < 4; ++r) {
          int rowL = wr * 32 + mr * 16 + g * 4 + r;
          int colL = wc * 32 + nr * 16 + li;
          Ct[rowL][colL] = f2bs(acc[mr][nr][r] + biasK[bn + colL]);
        }
    __syncthreads();
#pragma unroll
    for (int p = 0; p < 2; ++p) {
      int rowL = (tid >> 3) + p * 32;
      int c8 = (tid & 7) * 8;
      int grow = bm + rowL;
      int b2 = grow >> 12, key = grow & (L - 1);
      int gcol = bn + c8;
      int hh = gcol >> 5, dd = gcol & (HD - 1);
      int cst = (dd >> 3) ^ ((key >> 1) & 3);
      u16* dst = Kh + (((long)(b2 * H + hh) * L + key) * 32 + (cst << 3));
      *reinterpret_cast<bf16x8*>(dst) =
          *reinterpret_cast<const bf16x8*>(&Ct[rowL][c8]);
    }
  } else {
    int vbn = bn - 256;
#pragma unroll
    for (int mr = 0; mr < 2; ++mr)
#pragma unroll
      for (int nr = 0; nr < 2; ++nr)
#pragma unroll
        for (int r = 0; r < 4; ++r) {
          int rowL = wr * 32 + mr * 16 + g * 4 + r;
          int colL = wc * 32 + nr * 16 + li;
          Ct[colL][rowL] = f2bs(acc[mr][nr][r] + biasV[vbn + colL]);
        }
    __syncthreads();
    int b2 = bm >> 12;
#pragma unroll
    for (int p = 0; p < 2; ++p) {
      int colL = (tid >> 3) + p * 32;
      int rem = tid & 7;
      int kb = rem >> 2, k8 = (rem & 3) * 8;
      int gcol = vbn + colL;
      int hh = gcol >> 5, dd = gcol & (HD - 1);
      int kb32 = ((bm & (L - 1)) >> 5) + kb;
      int j = (k8 >> 2) ^ ((dd >> 1) & 6);
      u16* dst = Vh + (((long)(b2 * H + hh) * (L / 32) + kb32) * 1024 +
                       dd * 32 + (j << 2));
      *reinterpret_cast<bf16x8*>(dst) =
          *reinterpret_cast<const bf16x8*>(&Ct[colL][kb * 32 + k8]);
    }
  }
}

// ---------------------------------------------------------------------------
// Fused flash attention (R18-proven 1.5-buffer pipeline + setprio).
// ---------------------------------------------------------------------------
constexpr int POOLSZ = NSPLIT * 32 * 33 * 4 + NSPLIT * 32 * 4;  // 34816

__global__ __launch_bounds__(512) void attn_mfma(
    const u16* __restrict__ Qb, const u16* __restrict__ Kh,
    const u16* __restrict__ Vh, u16* __restrict__ AO) {
  __shared__ alignas(16) char pool[POOLSZ];
  int i = blockIdx.x;
  int xcd = i & 7, slot = i >> 3;          // 66 slots per XCD
  int bh = (xcd << 1) | (slot >= NQT ? 1 : 0);
  int qt = (slot >= NQT) ? slot - NQT : slot;
  int h = bh & 7;
  int b = bh >> 3;
  int tid = threadIdx.x, w = tid >> 6, lane = tid & 63;
  int g = lane >> 4, li = lane & 15;

  fr qf0, qf1;
  {
    const float QSC = 0.25509836048f;  // (1/sqrt(32)) * log2(e)
#pragma unroll
    for (int qb = 0; qb < 2; ++qb) {
      int qrow = qt * 32 + qb * 16 + li;
      if (qrow >= Q_MAX) qrow = Q_MAX - 1;
      bf16x8 raw = *reinterpret_cast<const bf16x8*>(
          Qb + ((long)(b * Q_MAX + qrow)) * D + h * HD + g * 8);
      fr& qf = qb ? qf1 : qf0;
#pragma unroll
      for (int j = 0; j < 4; ++j)
        qf.i[j] = (int)cvt_pk(bs2f((u16)raw[2 * j]) * QSC,
                              bs2f((u16)raw[2 * j + 1]) * QSC);
    }
  }

  f32x4 acc00 = {}, acc01 = {}, acc10 = {}, acc11 = {};
  float den0 = 0.f, den1 = 0.f;
  const f32x4 z = {};

  const u16* kbase = Kh + ((long)(b * H + h) * L) * HD;
  const u16* vbase = Vh + ((long)(b * H + h) * L) * HD;
  int kstart = w * KCHUNK;
  char* wbase = pool + w * 4096;  // wave-private single buffer (2KB K + 2KB V)

  int s_li = (li >> 1) & 3;
  int t_li = (li >> 1) & 6;
  int kof0 = li * 32 + ((g ^ s_li) << 3);
  int kof1 = (16 + li) * 32 + ((g ^ s_li) << 3);
  int va0o = li * 32 + ((g ^ t_li) << 2);
  int vb0o = li * 32 + (((4 + g) ^ t_li) << 2);
  int va1o = (16 + li) * 32 + ((g ^ t_li) << 2);
  int vb1o = (16 + li) * 32 + (((4 + g) ^ t_li) << 2);

  // prologue: issue K0 (2 loads) then V0 (2 loads)
  {
    const u16* ks = kbase + (long)kstart * HD + lane * 8;
    const u16* vs = vbase + (long)kstart * HD + lane * 8;
    u16* lk = (u16*)wbase;
    GLL16(ks, lk);
    GLL16(ks + 512, lk + 512);
    GLL16(vs, lk + 1024);
    GLL16(vs + 512, lk + 1536);
  }

  for (int t = 0; t < NT; ++t) {
    const u16* kl = (const u16*)wbase;
    const u16* vl = kl + 1024;

    asm volatile("s_waitcnt vmcnt(2)" ::: "memory");
    __builtin_amdgcn_sched_barrier(0);
    fr kf0, kf1;
    kf0.h = *reinterpret_cast<const bf16x8*>(kl + kof0);
    kf1.h = *reinterpret_cast<const bf16x8*>(kl + kof1);
    asm volatile("" ::"v"(kf0.i[0]), "v"(kf0.i[1]), "v"(kf0.i[2]),
                 "v"(kf0.i[3]), "v"(kf1.i[0]), "v"(kf1.i[1]), "v"(kf1.i[2]),
                 "v"(kf1.i[3]));
    asm volatile("s_waitcnt lgkmcnt(0)" ::: "memory");
    __builtin_amdgcn_sched_barrier(0);
    if (t + 1 < NT) {
      const u16* ks = kbase + (long)(kstart + (t + 1) * 32) * HD + lane * 8;
      u16* lk = (u16*)wbase;
      GLL16(ks, lk);
      GLL16(ks + 512, lk + 512);
    }

    __builtin_amdgcn_s_setprio(1);
    f32x4 s00 = __builtin_amdgcn_mfma_f32_16x16x32_bf16(kf0.h, qf0.h, z, 0, 0, 0);
    f32x4 s10 = __builtin_amdgcn_mfma_f32_16x16x32_bf16(kf1.h, qf0.h, z, 0, 0, 0);
    f32x4 s01 = __builtin_amdgcn_mfma_f32_16x16x32_bf16(kf0.h, qf1.h, z, 0, 0, 0);
    f32x4 s11 = __builtin_amdgcn_mfma_f32_16x16x32_bf16(kf1.h, qf1.h, z, 0, 0, 0);
    __builtin_amdgcn_s_setprio(0);

    float p00[4], p10[4], p01[4], p11[4];
#pragma unroll
    for (int r = 0; r < 4; ++r) {
      p00[r] = exp2f(s00[r]);
      p10[r] = exp2f(s10[r]);
      p01[r] = exp2f(s01[r]);
      p11[r] = exp2f(s11[r]);
      den0 += p00[r] + p10[r];
      den1 += p01[r] + p11[r];
    }
    fr pf0, pf1;
    pf0.i[0] = (int)cvt_pk(p00[0], p00[1]);
    pf0.i[1] = (int)cvt_pk(p00[2], p00[3]);
    pf0.i[2] = (int)cvt_pk(p10[0], p10[1]);
    pf0.i[3] = (int)cvt_pk(p10[2], p10[3]);
    pf1.i[0] = (int)cvt_pk(p01[0], p01[1]);
    pf1.i[1] = (int)cvt_pk(p01[2], p01[3]);
    pf1.i[2] = (int)cvt_pk(p11[0], p11[1]);
    pf1.i[3] = (int)cvt_pk(p11[2], p11[3]);

    if (t + 1 < NT)
      asm volatile("s_waitcnt vmcnt(2)" ::: "memory");
    else
      asm volatile("s_waitcnt vmcnt(0)" ::: "memory");
    __builtin_amdgcn_sched_barrier(0);
    uint2 va0 = *reinterpret_cast<const uint2*>(vl + va0o);
    uint2 vb0 = *reinterpret_cast<const uint2*>(vl + vb0o);
    uint2 va1 = *reinterpret_cast<const uint2*>(vl + va1o);
    uint2 vb1 = *reinterpret_cast<const uint2*>(vl + vb1o);
    asm volatile("" ::"v"(va0.x), "v"(va0.y), "v"(vb0.x), "v"(vb0.y),
                 "v"(va1.x), "v"(va1.y), "v"(vb1.x), "v"(vb1.y));
    asm volatile("s_waitcnt lgkmcnt(0)" ::: "memory");
    __builtin_amdgcn_sched_barrier(0);
    if (t + 1 < NT) {
      const u16* vs = vbase + (long)(kstart + (t + 1) * 32) * HD + lane * 8;
      u16* lk = (u16*)wbase;
      GLL16(vs, lk + 1024);
      GLL16(vs + 512, lk + 1536);
    }

    fr v0, v1;
    v0.i = (i32x4){(int)va0.x, (int)va0.y, (int)vb0.x, (int)vb0.y};
    v1.i = (i32x4){(int)va1.x, (int)va1.y, (int)vb1.x, (int)vb1.y};
    __builtin_amdgcn_s_setprio(1);
    acc00 = __builtin_amdgcn_mfma_f32_16x16x32_bf16(v0.h, pf0.h, acc00, 0, 0, 0);
    acc01 = __builtin_amdgcn_mfma_f32_16x16x32_bf16(v0.h, pf1.h, acc01, 0, 0, 0);
    acc10 = __builtin_amdgcn_mfma_f32_16x16x32_bf16(v1.h, pf0.h, acc10, 0, 0, 0);
    acc11 = __builtin_amdgcn_mfma_f32_16x16x32_bf16(v1.h, pf1.h, acc11, 0, 0, 0);
    __builtin_amdgcn_s_setprio(0);
  }

  den0 += __shfl_xor(den0, 16, 64);
  den0 += __shfl_xor(den0, 32, 64);
  den1 += __shfl_xor(den1, 16, 64);
  den1 += __shfl_xor(den1, 32, 64);

  __syncthreads();
  float(*accs)[32][33] = (float(*)[32][33])pool;
  float(*dsh)[32] = (float(*)[32])(pool + NSPLIT * 32 * 33 * 4);
#pragma unroll
  for (int r = 0; r < 4; ++r) {
    accs[w][g * 4 + r][li] = acc00[r];
    accs[w][g * 4 + r][16 + li] = acc01[r];
    accs[w][16 + g * 4 + r][li] = acc10[r];
    accs[w][16 + g * 4 + r][16 + li] = acc11[r];
  }
  if (g == 0) {
    dsh[w][li] = den0;
    dsh[w][16 + li] = den1;
  }
  __syncthreads();

  int q = tid >> 4, dp = tid & 15;
  float Den = 0.f, o0 = 0.f, o1 = 0.f;
#pragma unroll
  for (int ww = 0; ww < NSPLIT; ++ww) {
    Den += dsh[ww][q];
    o0 += accs[ww][2 * dp][q];
    o1 += accs[ww][2 * dp + 1][q];
  }
  float inv = 1.f / Den;
  int qrow = qt * 32 + q;
  if (qrow < Q_MAX) {
    unsigned pk = cvt_pk(o0 * inv, o1 * inv);
    *reinterpret_cast<unsigned*>(
        AO + ((long)(b * Q_MAX + qrow)) * D + h * HD + 2 * dp) = pk;
  }
}

// ---------------------------------------------------------------------------
// Merged head: input = q_stream[inv] if selected else enc row.
// ---------------------------------------------------------------------------
__global__ __launch_bounds__(256) void head_kernel(
    const float* __restrict__ enc, const float* __restrict__ q_stream,
    const int* __restrict__ inv, const float* __restrict__ hW,
    const float* __restrict__ hb, float* __restrict__ out) {
  int row = blockIdx.x * 4 + (threadIdx.x >> 6);
  int lane = threadIdx.x & 63;
  int slot = inv[row];
  const float* src =
      (slot >= 0) ? (q_stream + (long)slot * D) : (enc + (long)row * D);
  const float4 a = *reinterpret_cast<const float4*>(src + lane * 4);
  float c0 = 0.f, c1 = 0.f, c2 = 0.f;
  const float av[4] = {a.x, a.y, a.z, a.w};
#pragma unroll
  for (int i = 0; i < 4; ++i) {
    int k = lane * 4 + i;
    c0 += av[i] * hW[k * 3];
    c1 += av[i] * hW[k * 3 + 1];
    c2 += av[i] * hW[k * 3 + 2];
  }
#pragma unroll
  for (int off = 32; off; off >>= 1) {
    c0 += __shfl_down(c0, off, 64);
    c1 += __shfl_down(c1, off, 64);
    c2 += __shfl_down(c2, off, 64);
  }
  if (lane == 0) {
    out[(long)row * 3] = c0 + hb[0];
    out[(long)row * 3 + 1] = c1 + hb[1];
    out[(long)row * 3 + 2] = c2 + hb[2];
  }
}

// ---------------------------------------------------------------------------
extern "C" void kernel_launch(void* const* d_in, const int* in_sizes, int n_in,
                              void* d_out, int out_size, void* d_ws,
                              size_t ws_size, hipStream_t stream) {
  const float* enc = (const float*)d_in[0];
  const float* clog = (const float*)d_in[1];
  const float* ln_q_g = (const float*)d_in[2];
  const float* ln_q_b = (const float*)d_in[3];
  const float* ln_kv_g = (const float*)d_in[4];
  const float* ln_kv_b = (const float*)d_in[5];
  const float* Wq = (const float*)d_in[6];
  const float* bq = (const float*)d_in[7];
  const float* Wk = (const float*)d_in[8];
  const float* bk = (const float*)d_in[9];
  const float* Wv = (const float*)d_in[10];
  const float* bv = (const float*)d_in[11];
  const float* Wo = (const float*)d_in[12];
  const float* bo = (const float*)d_in[13];
  const float* ffn_g = (const float*)d_in[14];
  const float* ffn_b = (const float*)d_in[15];
  const float* W1 = (const float*)d_in[16];
  const float* b1 = (const float*)d_in[17];
  const float* W2 = (const float*)d_in[18];
  const float* b2 = (const float*)d_in[19];
  const float* head_W = (const float*)d_in[20];
  const float* head_b = (const float*)d_in[21];
  float* out = (float*)d_out;

  char* ws = (char*)d_ws;
  float* q_stream = (float*)ws;            ws += (long)QROWS * D * 4;
  u16* kvl0 = (u16*)ws;                    ws += (long)KVROWS * D * 2;
  u16* kvl1 = (u16*)ws;                    ws += (long)KVROWS * D * 2;
  u16* Khbuf = (u16*)ws;                   ws += (long)B * H * L * HD * 2;
  u16* Vhbuf = (u16*)ws;                   ws += (long)B * H * L * HD * 2;
  u16* q_ln = (u16*)ws;                    ws += (long)QROWS * D * 2;
  u16* Qbuf = (u16*)ws;                    ws += (long)QROWS * D * 2;
  u16* AObuf = (u16*)ws;                   ws += (long)QROWS * D * 2;
  u16* H1buf = (u16*)ws;                   ws += (long)QROWS * FF * 2;
  u16* WT = (u16*)ws;                      ws += (long)NL * (4 * D * D + 2 * D * FF) * 2;
  int* idxbuf = (int*)ws;                  ws += QROWS * 4;
  int* maskbuf = (int*)ws;                 ws += QROWS * 4;
  int* invbuf = (int*)ws;                  ws += (long)B * L * 4;

  const long DD = (long)D * D, DFF = (long)D * FF;
  const long LSTR = 4 * DD + 2 * DFF;

  setup_kernel<<<LNBLK + TRBLK + B, 256, 0, stream>>>(
      enc, clog, ln_kv_g, ln_kv_b, Wq, Wk, Wv, Wo, W1, W2, WT, kvl0, kvl1,
      idxbuf, maskbuf, invbuf);
  gather_ln<<<QROWS / 4, 256, 0, stream>>>(enc, idxbuf, q_stream, q_ln,
                                           ln_q_g, ln_q_b);

  for (int l = 0; l < NL; ++l) {
    u16* base = WT + l * LSTR;
    u16* kv_ln = (l == 0) ? kvl0 : kvl1;

    if (l > 0)
      ln_bf16<<<QROWS / 4, 256, 0, stream>>>(q_stream, q_ln, ln_q_g + l * D,
                                             ln_q_b + l * D);

    gemm_proj<<<KVBLK + QBLK, 256, 0, stream>>>(
        kv_ln, q_ln, base, bk + l * D, bv + l * D, bq + l * D, Khbuf, Vhbuf,
        Qbuf);

    attn_mfma<<<B * H * NQT, 512, 0, stream>>>(Qbuf, Khbuf, Vhbuf, AObuf);

    // O-proj: 32-row tiles, grid (4,65)=260 blocks (full-GPU occupancy)
    gemm_mfma32<<<dim3(D / 64, MRB32), 128, 0, stream>>>(
        AObuf, base + 3 * DD, bo + l * D, q_stream, q_stream, maskbuf, QROWS,
        D, D);

    ln_bf16<<<QROWS / 4, 256, 0, stream>>>(q_stream, q_ln, ffn_g + l * D,
                                           ffn_b + l * D);
    dim3 gF1(FF / 64, (QROWS + 63) / 64);
    gemm_mfma<1><<<gF1, 256, 0, stream>>>(q_ln, base + 4 * DD, b1 + l * FF,
                                          (void*)H1buf, nullptr, nullptr,
                                          QROWS, FF, D);
    // FFN2: 32-row tiles, grid (4,65)=260 blocks
    gemm_mfma32<<<dim3(D / 64, MRB32), 128, 0, stream>>>(
        H1buf, base + 4 * DD + DFF, b2 + l * D, q_stream, q_stream, maskbuf,
        QROWS, D, FF);
  }

  head_kernel<<<KVROWS / 4, 256, 0, stream>>>(enc, q_stream, invbuf, head_W,
                                              head_b, out);
}

// Round 21
// 206.373 us; speedup vs baseline: 1.4027x; 1.0055x over previous
//
#include <hip/hip_runtime.h>
#include <cmath>

constexpr int B = 2, L = 4096, D = 256, H = 8, NC = 3;
constexpr int TOP_N = 8, R = 32;
constexpr int LS = 1000, LE = 3000;
constexpr int NL = 2;
constexpr int FF = 4 * D;                        // 1024
constexpr int Q_MAX = 2 * TOP_N * (2 * R + 1);   // 1040
constexpr int HD = D / H;                        // 32
constexpr int QROWS = B * Q_MAX;                 // 2080
constexpr int KVROWS = B * L;                    // 8192
constexpr int NQT = (Q_MAX + 31) / 32;           // 33 q-tiles of 32
constexpr int NREG = LE - LS;                    // 2000
constexpr int NSPLIT = 8;                        // split-K waves per block
constexpr int KCHUNK = L / NSPLIT;               // 512 keys per wave
constexpr int NT = KCHUNK / 32;                  // 16 iterations
constexpr int KVBLK = 8 * (KVROWS / 64);         // 1024 blocks (KV part)
constexpr int QBLK = 4 * ((QROWS + 63) / 64);    // 132 blocks (Q part)
constexpr int TRBLK = NL * 192;                  // 384 transpose blocks
constexpr int LNBLK = KVROWS / 4;                // 2048 LN blocks (4 rows ea)
constexpr int MRB32 = QROWS / 32;                // 65 row-blocks of 32
constexpr int MRB64 = (QROWS + 63) / 64;         // 33 row-blocks of 64

typedef __attribute__((ext_vector_type(8))) short bf16x8;
typedef __attribute__((ext_vector_type(4))) float f32x4;
typedef __attribute__((ext_vector_type(4))) int i32x4;
typedef unsigned short u16;

union fr {
  bf16x8 h;
  i32x4 i;
};

__device__ __forceinline__ u16 f2bs(float f) {
  unsigned int u = __float_as_uint(f);
  unsigned int r = u + 0x7fffu + ((u >> 16) & 1u);
  return (u16)(r >> 16);
}
__device__ __forceinline__ float bs2f(u16 s) {
  return __uint_as_float(((unsigned int)s) << 16);
}
__device__ __forceinline__ float gelu_exact(float x) {
  return 0.5f * x * (1.f + erff(x * 0.70710678118654752440f));
}
__device__ __forceinline__ unsigned cvt_pk(float lo, float hi) {
  unsigned r;
  asm("v_cvt_pk_bf16_f32 %0, %1, %2" : "=v"(r) : "v"(lo), "v"(hi));
  return r;
}

#define GLL16(gsrc, ldst)                                                   \
  __builtin_amdgcn_global_load_lds(                                         \
      (const __attribute__((address_space(1))) unsigned int*)(gsrc),        \
      (__attribute__((address_space(3))) unsigned int*)(ldst), 16, 0, 0)

// Wave-level row LayerNorm helper: lane holds float4 (cols lane*4..lane*4+3).
__device__ __forceinline__ void wave_ln_stats(float4 v, float& mean,
                                              float& rstd) {
  float s1 = v.x + v.y + v.z + v.w;
  float s2 = v.x * v.x + v.y * v.y + v.z * v.z + v.w * v.w;
#pragma unroll
  for (int off = 32; off; off >>= 1) {
    s1 += __shfl_xor(s1, off, 64);
    s2 += __shfl_xor(s2, off, 64);
  }
  mean = s1 * (1.f / D);
  float var = fmaxf(s2 * (1.f / D) - mean * mean, 0.f);
  rstd = rsqrtf(var + 1e-5f);
}

// ---------------------------------------------------------------------------
// Merged setup dispatch (256 threads/block): LN(enc) x2 | W transpose | select
// ---------------------------------------------------------------------------
__global__ __launch_bounds__(256) void setup_kernel(
    const float* __restrict__ enc, const float* __restrict__ logits,
    const float* __restrict__ lnkvg, const float* __restrict__ lnkvb,
    const float* __restrict__ Wq_, const float* __restrict__ Wk_,
    const float* __restrict__ Wv_, const float* __restrict__ Wo_,
    const float* __restrict__ W1_, const float* __restrict__ W2_,
    u16* __restrict__ WT, u16* __restrict__ o0, u16* __restrict__ o1,
    int* __restrict__ idx_out, int* __restrict__ mask_out,
    int* __restrict__ inv_out) {
  int bid = blockIdx.x;
  int tid = threadIdx.x;
  const long DD = (long)D * D, DFF = (long)D * FF;
  const long LSTR = 4 * DD + 2 * DFF;

  if (bid < LNBLK) {
    long row = (long)bid * 4 + (tid >> 6);
    int lane = tid & 63;
    float4 v = *reinterpret_cast<const float4*>(enc + row * D + lane * 4);
    float mean, rstd;
    wave_ln_stats(v, mean, rstd);
    float n0 = (v.x - mean) * rstd, n1 = (v.y - mean) * rstd,
          n2 = (v.z - mean) * rstd, n3 = (v.w - mean) * rstd;
    int c = lane * 4;
    float4 g0 = *reinterpret_cast<const float4*>(lnkvg + c);
    float4 b0v = *reinterpret_cast<const float4*>(lnkvb + c);
    float4 g1 = *reinterpret_cast<const float4*>(lnkvg + D + c);
    float4 b1v = *reinterpret_cast<const float4*>(lnkvb + D + c);
    uint2 w0 = {cvt_pk(n0 * g0.x + b0v.x, n1 * g0.y + b0v.y),
                cvt_pk(n2 * g0.z + b0v.z, n3 * g0.w + b0v.w)};
    uint2 w1 = {cvt_pk(n0 * g1.x + b1v.x, n1 * g1.y + b1v.y),
                cvt_pk(n2 * g1.z + b1v.z, n3 * g1.w + b1v.w)};
    *reinterpret_cast<uint2*>(o0 + row * D + c) = w0;
    *reinterpret_cast<uint2*>(o1 + row * D + c) = w1;
    return;
  }

  if (bid < LNBLK + TRBLK) {
    __shared__ u16 T[64][65];
    int t = bid - LNBLK;
    int l = t / 192, r = t % 192;
    const float* src;
    long dbase;
    int K_, N_, kt, nt;
    if (r < 64) {
      int which = r >> 4, sub = r & 15;
      kt = sub >> 2;
      nt = sub & 3;
      K_ = 256;
      N_ = 256;
      src = (which == 0 ? Wk_ : which == 1 ? Wv_ : which == 2 ? Wq_ : Wo_) +
            (long)l * DD;
      dbase = (long)l * LSTR + (long)which * DD;
    } else if (r < 128) {
      int sub = r - 64;
      kt = sub >> 4;
      nt = sub & 15;
      K_ = 256;
      N_ = 1024;
      src = W1_ + (long)l * DFF;
      dbase = (long)l * LSTR + 4 * DD;
    } else {
      int sub = r - 128;
      kt = sub >> 2;
      nt = sub & 3;
      K_ = 1024;
      N_ = 256;
      src = W2_ + (long)l * DFF;
      dbase = (long)l * LSTR + 4 * DD + DFF;
    }
    int k0 = kt * 64, n0 = nt * 64;
    {
      int kr = tid >> 2, c16 = (tid & 3) * 16;
      const float* sp = src + (long)(k0 + kr) * N_ + n0 + c16;
#pragma unroll
      for (int i = 0; i < 4; ++i) {
        float4 v = *reinterpret_cast<const float4*>(sp + 4 * i);
        T[kr][c16 + 4 * i + 0] = f2bs(v.x);
        T[kr][c16 + 4 * i + 1] = f2bs(v.y);
        T[kr][c16 + 4 * i + 2] = f2bs(v.z);
        T[kr][c16 + 4 * i + 3] = f2bs(v.w);
      }
    }
    __syncthreads();
    {
      int nr = tid >> 2, kc = (tid & 3) * 16;
      u16 tmp[16];
#pragma unroll
      for (int j = 0; j < 16; ++j) tmp[j] = T[kc + j][nr];
      u16* dp = WT + dbase + (long)(n0 + nr) * K_ + k0 + kc;
      *reinterpret_cast<bf16x8*>(dp) = *reinterpret_cast<const bf16x8*>(&tmp[0]);
      *reinterpret_cast<bf16x8*>(dp + 8) =
          *reinterpret_cast<const bf16x8*>(&tmp[8]);
    }
    return;
  }

  // ---- select part (one block per batch), 256 threads = 4 waves
  {
    int b = bid - LNBLK - TRBLK;
    int w = tid >> 6, lane = tid & 63;
    __shared__ float candv[4][8];
    __shared__ int candi[4][8];
    __shared__ int centers[2 * TOP_N];
    __shared__ unsigned present[L / 32];
    __shared__ int offs[128];
    __shared__ int wtot[2];

    float vd[8], va[8];
#pragma unroll
    for (int j = 0; j < 8; ++j) {
      int p = tid + j * 256;
      if (p < NREG) {
        const float* lg = logits + ((long)b * L + LS + p) * NC;
        float x0 = lg[0], x1 = lg[1], x2 = lg[2];
        float m = fmaxf(x0, fmaxf(x1, x2));
        float lse = m + logf(expf(x0 - m) + expf(x1 - m) + expf(x2 - m));
        vd[j] = x2 - lse;
        va[j] = x1 - lse;
      } else {
        vd[j] = -INFINITY;
        va[j] = -INFINITY;
      }
    }
    if (tid < 128) present[tid] = 0;
    for (int j = tid; j < L; j += 256) inv_out[(long)b * L + j] = -1;

    for (int sel = 0; sel < 2; ++sel) {
      float v[8];
#pragma unroll
      for (int j = 0; j < 8; ++j) v[j] = (sel == 0) ? vd[j] : va[j];
#pragma unroll
      for (int r = 0; r < TOP_N; ++r) {
        float mv = v[0];
        int mp = tid;
#pragma unroll
        for (int j = 1; j < 8; ++j) {
          int pj = tid + j * 256;
          if (v[j] > mv) { mv = v[j]; mp = pj; }
        }
#pragma unroll
        for (int off = 32; off; off >>= 1) {
          float ov = __shfl_xor(mv, off, 64);
          int oi = __shfl_xor(mp, off, 64);
          if (ov > mv || (ov == mv && oi < mp)) { mv = ov; mp = oi; }
        }
#pragma unroll
        for (int j = 0; j < 8; ++j)
          if (tid + j * 256 == mp) v[j] = -INFINITY;
        if (lane == 0) { candv[w][r] = mv; candi[w][r] = mp; }
      }
      __syncthreads();
      if (tid < 64) {
        float c = (tid < 32) ? candv[tid >> 3][tid & 7] : -INFINITY;
        int ci = (tid < 32) ? candi[tid >> 3][tid & 7] : 0x7fffffff;
#pragma unroll
        for (int r = 0; r < TOP_N; ++r) {
          float mv = c;
          int mi = ci;
#pragma unroll
          for (int off = 32; off; off >>= 1) {
            float ov = __shfl_xor(mv, off, 64);
            int oi = __shfl_xor(mi, off, 64);
            if (ov > mv || (ov == mv && oi < mi)) { mv = ov; mi = oi; }
          }
          if (ci == mi) c = -INFINITY;
          if (tid == 0) centers[sel * TOP_N + r] = LS + mi;
        }
      }
      __syncthreads();
    }

    for (int j = tid; j < Q_MAX; j += 256) {
      int c = centers[j / (2 * R + 1)];
      int off = j % (2 * R + 1) - R;
      int v2 = c + off;
      v2 = v2 < 0 ? 0 : (v2 > L - 1 ? L - 1 : v2);
      atomicOr(&present[v2 >> 5], 1u << (v2 & 31));
    }
    __syncthreads();

    int cnt = (tid < 128) ? __popc(present[tid]) : 0;
    if (tid < 128) {
      int x = cnt;
#pragma unroll
      for (int off = 1; off < 64; off <<= 1) {
        int o = __shfl_up(x, off, 64);
        if ((tid & 63) >= off) x += o;
      }
      if ((tid & 63) == 63) wtot[tid >> 6] = x;
      offs[tid] = x - cnt;
    }
    __syncthreads();
    int total = wtot[0] + wtot[1];
    if (tid < 128) {
      int base = offs[tid] + ((tid >= 64) ? wtot[0] : 0);
      unsigned mword = present[tid];
      while (mword) {
        int i = __ffs(mword) - 1;
        mword &= mword - 1;
        int pos = tid * 32 + i;
        idx_out[b * Q_MAX + base] = pos;
        mask_out[b * Q_MAX + base] = 1;
        inv_out[(long)b * L + pos] = b * Q_MAX + base;
        ++base;
      }
    }
    for (int j = total + tid; j < Q_MAX; j += 256) {
      idx_out[b * Q_MAX + j] = L;
      mask_out[b * Q_MAX + j] = 0;
    }
  }
}

// ---------------------------------------------------------------------------
// Gather + layer-0 Q-LN fused, wave-per-row. Grid QROWS/4.
// ---------------------------------------------------------------------------
__global__ __launch_bounds__(256) void gather_ln(
    const float* __restrict__ enc, const int* __restrict__ idx,
    float* __restrict__ q_stream, u16* __restrict__ q_ln,
    const float* __restrict__ gg, const float* __restrict__ bb) {
  int row = blockIdx.x * 4 + (threadIdx.x >> 6);
  int lane = threadIdx.x & 63;
  int b = row / Q_MAX;
  int p = idx[row];
  int c = lane * 4;
  float4 v = {0.f, 0.f, 0.f, 0.f};
  if (p < L) v = *reinterpret_cast<const float4*>(enc + ((long)b * L + p) * D + c);
  *reinterpret_cast<float4*>(q_stream + (long)row * D + c) = v;
  float mean, rstd;
  wave_ln_stats(v, mean, rstd);
  float4 g = *reinterpret_cast<const float4*>(gg + c);
  float4 bt = *reinterpret_cast<const float4*>(bb + c);
  uint2 w = {cvt_pk((v.x - mean) * rstd * g.x + bt.x,
                    (v.y - mean) * rstd * g.y + bt.y),
             cvt_pk((v.z - mean) * rstd * g.z + bt.z,
                    (v.w - mean) * rstd * g.w + bt.w)};
  *reinterpret_cast<uint2*>(q_ln + (long)row * D + c) = w;
}

// ---------------------------------------------------------------------------
// Wave-per-row LayerNorm fp32 -> bf16. Grid M/4.
// ---------------------------------------------------------------------------
__global__ __launch_bounds__(256) void ln_bf16(
    const float* __restrict__ in, u16* __restrict__ out,
    const float* __restrict__ gg, const float* __restrict__ bb) {
  long row = (long)blockIdx.x * 4 + (threadIdx.x >> 6);
  int lane = threadIdx.x & 63;
  int c = lane * 4;
  float4 v = *reinterpret_cast<const float4*>(in + row * D + c);
  float mean, rstd;
  wave_ln_stats(v, mean, rstd);
  float4 g = *reinterpret_cast<const float4*>(gg + c);
  float4 bt = *reinterpret_cast<const float4*>(bb + c);
  uint2 w = {cvt_pk((v.x - mean) * rstd * g.x + bt.x,
                    (v.y - mean) * rstd * g.y + bt.y),
             cvt_pk((v.z - mean) * rstd * g.z + bt.z,
                    (v.w - mean) * rstd * g.w + bt.w)};
  *reinterpret_cast<uint2*>(out + row * D + c) = w;
}

// ---------------------------------------------------------------------------
// 32-row-tile bf16 MFMA GEMM (O-proj, FFN2): 128 threads = 2 waves, grid
// (N/64, 65) = 260 blocks. EPI2: C = mask ? resid + x + bias : 0 (f32).
// ---------------------------------------------------------------------------
__global__ __launch_bounds__(128) void gemm_mfma32(
    const u16* __restrict__ A, const u16* __restrict__ BT,
    const float* __restrict__ bias, float* __restrict__ Cv,
    const float* __restrict__ resid, const int* __restrict__ mask, int M,
    int N, int K) {
  __shared__ short As[32][40];
  __shared__ short Bs[64][40];
  int bm = blockIdx.y * 32, bn = blockIdx.x * 64;
  int tid = threadIdx.x;
  int lane = tid & 63, w = tid >> 6;
  int g = lane >> 4, li = lane & 15;
  f32x4 acc[2][2] = {};

  int srow = tid >> 2, skc = (tid & 3) * 8;  // srow 0..31
  for (int k0 = 0; k0 < K; k0 += 32) {
    {
      bf16x8 av = *reinterpret_cast<const bf16x8*>(
          A + (long)(bm + srow) * K + k0 + skc);
      *reinterpret_cast<bf16x8*>(&As[srow][skc]) = av;
      bf16x8 bv0 = *reinterpret_cast<const bf16x8*>(
          BT + (long)(bn + srow) * K + k0 + skc);
      *reinterpret_cast<bf16x8*>(&Bs[srow][skc]) = bv0;
      bf16x8 bv1 = *reinterpret_cast<const bf16x8*>(
          BT + (long)(bn + 32 + srow) * K + k0 + skc);
      *reinterpret_cast<bf16x8*>(&Bs[32 + srow][skc]) = bv1;
    }
    __syncthreads();
    bf16x8 a0 = *reinterpret_cast<const bf16x8*>(&As[li][g * 8]);
    bf16x8 a1 = *reinterpret_cast<const bf16x8*>(&As[16 + li][g * 8]);
    bf16x8 b0 = *reinterpret_cast<const bf16x8*>(&Bs[w * 32 + li][g * 8]);
    bf16x8 b1 = *reinterpret_cast<const bf16x8*>(&Bs[w * 32 + 16 + li][g * 8]);
    acc[0][0] = __builtin_amdgcn_mfma_f32_16x16x32_bf16(a0, b0, acc[0][0], 0, 0, 0);
    acc[0][1] = __builtin_amdgcn_mfma_f32_16x16x32_bf16(a0, b1, acc[0][1], 0, 0, 0);
    acc[1][0] = __builtin_amdgcn_mfma_f32_16x16x32_bf16(a1, b0, acc[1][0], 0, 0, 0);
    acc[1][1] = __builtin_amdgcn_mfma_f32_16x16x32_bf16(a1, b1, acc[1][1], 0, 0, 0);
    __syncthreads();
  }

#pragma unroll
  for (int mr = 0; mr < 2; ++mr)
#pragma unroll
    for (int nr = 0; nr < 2; ++nr)
#pragma unroll
      for (int r = 0; r < 4; ++r) {
        int row = bm + mr * 16 + g * 4 + r;
        int col = bn + w * 32 + nr * 16 + li;
        if (row >= M) continue;
        float v = acc[mr][nr][r] + bias[col] + resid[(long)row * N + col];
        v = mask[row] ? v : 0.f;
        Cv[(long)row * N + col] = v;
      }
}

// ---------------------------------------------------------------------------
// Combined projection dispatch, DMA-staged + XOR-swizzled + double-buffered
// (R20-proven).
// ---------------------------------------------------------------------------
__global__ __launch_bounds__(256) void gemm_proj(
    const u16* __restrict__ Akv, const u16* __restrict__ Aq,
    const u16* __restrict__ WTbase, const float* __restrict__ biasK,
    const float* __restrict__ biasV, const float* __restrict__ biasQ,
    u16* __restrict__ Kh, u16* __restrict__ Vh, u16* __restrict__ Qb) {
  __shared__ alignas(16) u16 Asb[2][2048];  // 8 KB
  __shared__ alignas(16) u16 Bsb[2][2048];  // 8 KB
  __shared__ u16 Ct[64][72];                // 9.2 KB
  int bid = blockIdx.x;
  int tid = threadIdx.x;
  int lane = tid & 63, w = tid >> 6;
  int g = lane >> 4, li = lane & 15;
  int wr = w >> 1, wc = w & 1;
  f32x4 acc[2][2] = {};
  const long DD = (long)D * D;

  bool isKV = bid < KVBLK;
  int bm, bn, M;
  const u16* A;
  const u16* BT;
  if (isKV) {
    bn = (bid & 7) * 64;
    bm = (bid >> 3) * 64;
    M = KVROWS;
    A = Akv;
    BT = WTbase;
  } else {
    int qb = bid - KVBLK;
    bn = (qb & 3) * 64;
    bm = (qb >> 2) * 64;
    M = QROWS;
    A = Aq;
    BT = WTbase + 2 * DD;
  }

  int srow = w * 16 + (lane >> 2);
  int sgo = (((lane & 3) ^ ((srow >> 1) & 3)) << 3);  // u16 units
  const u16* aRow = A + (long)(bm + srow) * D + sgo;
  const u16* bRow = BT + (long)(bn + srow) * D + sgo;

  int ra = wr * 32 + li;
  int ofA0 = ra * 32 + ((g ^ ((ra >> 1) & 3)) << 3);
  int ofA1 = ofA0 + 16 * 32;
  int rb = wc * 32 + li;
  int ofB0 = rb * 32 + ((g ^ ((rb >> 1) & 3)) << 3);
  int ofB1 = ofB0 + 16 * 32;

  GLL16(aRow, Asb[0] + w * 512);
  GLL16(bRow, Bsb[0] + w * 512);

#pragma unroll 1
  for (int ks = 0; ks < D / 32; ++ks) {
    asm volatile("s_waitcnt lgkmcnt(0)" ::: "memory");
    asm volatile("s_waitcnt vmcnt(0)" ::: "memory");
    __builtin_amdgcn_sched_barrier(0);
    __builtin_amdgcn_s_barrier();
    if (ks + 1 < D / 32) {
      GLL16(aRow + (ks + 1) * 32, Asb[(ks + 1) & 1] + w * 512);
      GLL16(bRow + (ks + 1) * 32, Bsb[(ks + 1) & 1] + w * 512);
    }
    const u16* Ab = Asb[ks & 1];
    const u16* Bb = Bsb[ks & 1];
    bf16x8 a0 = *reinterpret_cast<const bf16x8*>(Ab + ofA0);
    bf16x8 a1 = *reinterpret_cast<const bf16x8*>(Ab + ofA1);
    bf16x8 b0 = *reinterpret_cast<const bf16x8*>(Bb + ofB0);
    bf16x8 b1 = *reinterpret_cast<const bf16x8*>(Bb + ofB1);
    __builtin_amdgcn_s_setprio(1);
    acc[0][0] = __builtin_amdgcn_mfma_f32_16x16x32_bf16(a0, b0, acc[0][0], 0, 0, 0);
    acc[0][1] = __builtin_amdgcn_mfma_f32_16x16x32_bf16(a0, b1, acc[0][1], 0, 0, 0);
    acc[1][0] = __builtin_amdgcn_mfma_f32_16x16x32_bf16(a1, b0, acc[1][0], 0, 0, 0);
    acc[1][1] = __builtin_amdgcn_mfma_f32_16x16x32_bf16(a1, b1, acc[1][1], 0, 0, 0);
    __builtin_amdgcn_s_setprio(0);
  }
  asm volatile("s_waitcnt lgkmcnt(0)" ::: "memory");
  __builtin_amdgcn_s_barrier();

  if (!isKV) {
#pragma unroll
    for (int mr = 0; mr < 2; ++mr)
#pragma unroll
      for (int nr = 0; nr < 2; ++nr)
#pragma unroll
        for (int r = 0; r < 4; ++r) {
          int row = bm + wr * 32 + mr * 16 + g * 4 + r;
          int col = bn + wc * 32 + nr * 16 + li;
          if (row >= M) continue;
          Qb[(long)row * D + col] = f2bs(acc[mr][nr][r] + biasQ[col]);
        }
  } else if (bn < 256) {
#pragma unroll
    for (int mr = 0; mr < 2; ++mr)
#pragma unroll
      for (int nr = 0; nr < 2; ++nr)
#pragma unroll
        for (int r = 0; r < 4; ++r) {
          int rowL = wr * 32 + mr * 16 + g * 4 + r;
          int colL = wc * 32 + nr * 16 + li;
          Ct[rowL][colL] = f2bs(acc[mr][nr][r] + biasK[bn + colL]);
        }
    __syncthreads();
#pragma unroll
    for (int p = 0; p < 2; ++p) {
      int rowL = (tid >> 3) + p * 32;
      int c8 = (tid & 7) * 8;
      int grow = bm + rowL;
      int b2 = grow >> 12, key = grow & (L - 1);
      int gcol = bn + c8;
      int hh = gcol >> 5, dd = gcol & (HD - 1);
      int cst = (dd >> 3) ^ ((key >> 1) & 3);
      u16* dst = Kh + (((long)(b2 * H + hh) * L + key) * 32 + (cst << 3));
      *reinterpret_cast<bf16x8*>(dst) =
          *reinterpret_cast<const bf16x8*>(&Ct[rowL][c8]);
    }
  } else {
    int vbn = bn - 256;
#pragma unroll
    for (int mr = 0; mr < 2; ++mr)
#pragma unroll
      for (int nr = 0; nr < 2; ++nr)
#pragma unroll
        for (int r = 0; r < 4; ++r) {
          int rowL = wr * 32 + mr * 16 + g * 4 + r;
          int colL = wc * 32 + nr * 16 + li;
          Ct[colL][rowL] = f2bs(acc[mr][nr][r] + biasV[vbn + colL]);
        }
    __syncthreads();
    int b2 = bm >> 12;
#pragma unroll
    for (int p = 0; p < 2; ++p) {
      int colL = (tid >> 3) + p * 32;
      int rem = tid & 7;
      int kb = rem >> 2, k8 = (rem & 3) * 8;
      int gcol = vbn + colL;
      int hh = gcol >> 5, dd = gcol & (HD - 1);
      int kb32 = ((bm & (L - 1)) >> 5) + kb;
      int j = (k8 >> 2) ^ ((dd >> 1) & 6);
      u16* dst = Vh + (((long)(b2 * H + hh) * (L / 32) + kb32) * 1024 +
                       dd * 32 + (j << 2));
      *reinterpret_cast<bf16x8*>(dst) =
          *reinterpret_cast<const bf16x8*>(&Ct[colL][kb * 32 + k8]);
    }
  }
}

// ---------------------------------------------------------------------------
// FFN1 GEMM, DMA-staged + XOR-swizzled + double-buffered (same template as
// gemm_proj): A = q_ln [QROWS x 256] bf16, BT = W1T [1024 x 256], out =
// gelu(x + b1) -> bf16 H1. Grid = 16 n-tiles x 33 row-tiles = 528 blocks.
// OOB A-rows (2080..2111) read into adjacent workspace (row-guarded output).
// ---------------------------------------------------------------------------
__global__ __launch_bounds__(256) void gemm_ffn1(
    const u16* __restrict__ A, const u16* __restrict__ BT,
    const float* __restrict__ bias, u16* __restrict__ H1) {
  __shared__ alignas(16) u16 Asb[2][2048];
  __shared__ alignas(16) u16 Bsb[2][2048];
  int bid = blockIdx.x;
  int tid = threadIdx.x;
  int lane = tid & 63, w = tid >> 6;
  int g = lane >> 4, li = lane & 15;
  int wr = w >> 1, wc = w & 1;
  f32x4 acc[2][2] = {};

  int bn = (bid & 15) * 64;
  int bm = (bid >> 4) * 64;

  int srow = w * 16 + (lane >> 2);
  int sgo = (((lane & 3) ^ ((srow >> 1) & 3)) << 3);
  const u16* aRow = A + (long)(bm + srow) * D + sgo;
  const u16* bRow = BT + (long)(bn + srow) * D + sgo;

  int ra = wr * 32 + li;
  int ofA0 = ra * 32 + ((g ^ ((ra >> 1) & 3)) << 3);
  int ofA1 = ofA0 + 16 * 32;
  int rb = wc * 32 + li;
  int ofB0 = rb * 32 + ((g ^ ((rb >> 1) & 3)) << 3);
  int ofB1 = ofB0 + 16 * 32;

  GLL16(aRow, Asb[0] + w * 512);
  GLL16(bRow, Bsb[0] + w * 512);

#pragma unroll 1
  for (int ks = 0; ks < D / 32; ++ks) {
    asm volatile("s_waitcnt lgkmcnt(0)" ::: "memory");
    asm volatile("s_waitcnt vmcnt(0)" ::: "memory");
    __builtin_amdgcn_sched_barrier(0);
    __builtin_amdgcn_s_barrier();
    if (ks + 1 < D / 32) {
      GLL16(aRow + (ks + 1) * 32, Asb[(ks + 1) & 1] + w * 512);
      GLL16(bRow + (ks + 1) * 32, Bsb[(ks + 1) & 1] + w * 512);
    }
    const u16* Ab = Asb[ks & 1];
    const u16* Bb = Bsb[ks & 1];
    bf16x8 a0 = *reinterpret_cast<const bf16x8*>(Ab + ofA0);
    bf16x8 a1 = *reinterpret_cast<const bf16x8*>(Ab + ofA1);
    bf16x8 b0 = *reinterpret_cast<const bf16x8*>(Bb + ofB0);
    bf16x8 b1 = *reinterpret_cast<const bf16x8*>(Bb + ofB1);
    __builtin_amdgcn_s_setprio(1);
    acc[0][0] = __builtin_amdgcn_mfma_f32_16x16x32_bf16(a0, b0, acc[0][0], 0, 0, 0);
    acc[0][1] = __builtin_amdgcn_mfma_f32_16x16x32_bf16(a0, b1, acc[0][1], 0, 0, 0);
    acc[1][0] = __builtin_amdgcn_mfma_f32_16x16x32_bf16(a1, b0, acc[1][0], 0, 0, 0);
    acc[1][1] = __builtin_amdgcn_mfma_f32_16x16x32_bf16(a1, b1, acc[1][1], 0, 0, 0);
    __builtin_amdgcn_s_setprio(0);
  }
  asm volatile("s_waitcnt lgkmcnt(0)" ::: "memory");

#pragma unroll
  for (int mr = 0; mr < 2; ++mr)
#pragma unroll
    for (int nr = 0; nr < 2; ++nr)
#pragma unroll
      for (int r = 0; r < 4; ++r) {
        int row = bm + wr * 32 + mr * 16 + g * 4 + r;
        int col = bn + wc * 32 + nr * 16 + li;
        if (row >= QROWS) continue;
        H1[(long)row * FF + col] =
            f2bs(gelu_exact(acc[mr][nr][r] + bias[col]));
      }
}

// ---------------------------------------------------------------------------
// Fused flash attention (R18-proven 1.5-buffer pipeline + setprio).
// ---------------------------------------------------------------------------
constexpr int POOLSZ = NSPLIT * 32 * 33 * 4 + NSPLIT * 32 * 4;  // 34816

__global__ __launch_bounds__(512) void attn_mfma(
    const u16* __restrict__ Qb, const u16* __restrict__ Kh,
    const u16* __restrict__ Vh, u16* __restrict__ AO) {
  __shared__ alignas(16) char pool[POOLSZ];
  int i = blockIdx.x;
  int xcd = i & 7, slot = i >> 3;          // 66 slots per XCD
  int bh = (xcd << 1) | (slot >= NQT ? 1 : 0);
  int qt = (slot >= NQT) ? slot - NQT : slot;
  int h = bh & 7;
  int b = bh >> 3;
  int tid = threadIdx.x, w = tid >> 6, lane = tid & 63;
  int g = lane >> 4, li = lane & 15;

  fr qf0, qf1;
  {
    const float QSC = 0.25509836048f;  // (1/sqrt(32)) * log2(e)
#pragma unroll
    for (int qb = 0; qb < 2; ++qb) {
      int qrow = qt * 32 + qb * 16 + li;
      if (qrow >= Q_MAX) qrow = Q_MAX - 1;
      bf16x8 raw = *reinterpret_cast<const bf16x8*>(
          Qb + ((long)(b * Q_MAX + qrow)) * D + h * HD + g * 8);
      fr& qf = qb ? qf1 : qf0;
#pragma unroll
      for (int j = 0; j < 4; ++j)
        qf.i[j] = (int)cvt_pk(bs2f((u16)raw[2 * j]) * QSC,
                              bs2f((u16)raw[2 * j + 1]) * QSC);
    }
  }

  f32x4 acc00 = {}, acc01 = {}, acc10 = {}, acc11 = {};
  float den0 = 0.f, den1 = 0.f;
  const f32x4 z = {};

  const u16* kbase = Kh + ((long)(b * H + h) * L) * HD;
  const u16* vbase = Vh + ((long)(b * H + h) * L) * HD;
  int kstart = w * KCHUNK;
  char* wbase = pool + w * 4096;  // wave-private single buffer (2KB K + 2KB V)

  int s_li = (li >> 1) & 3;
  int t_li = (li >> 1) & 6;
  int kof0 = li * 32 + ((g ^ s_li) << 3);
  int kof1 = (16 + li) * 32 + ((g ^ s_li) << 3);
  int va0o = li * 32 + ((g ^ t_li) << 2);
  int vb0o = li * 32 + (((4 + g) ^ t_li) << 2);
  int va1o = (16 + li) * 32 + ((g ^ t_li) << 2);
  int vb1o = (16 + li) * 32 + (((4 + g) ^ t_li) << 2);

  // prologue: issue K0 (2 loads) then V0 (2 loads)
  {
    const u16* ks = kbase + (long)kstart * HD + lane * 8;
    const u16* vs = vbase + (long)kstart * HD + lane * 8;
    u16* lk = (u16*)wbase;
    GLL16(ks, lk);
    GLL16(ks + 512, lk + 512);
    GLL16(vs, lk + 1024);
    GLL16(vs + 512, lk + 1536);
  }

  for (int t = 0; t < NT; ++t) {
    const u16* kl = (const u16*)wbase;
    const u16* vl = kl + 1024;

    asm volatile("s_waitcnt vmcnt(2)" ::: "memory");
    __builtin_amdgcn_sched_barrier(0);
    fr kf0, kf1;
    kf0.h = *reinterpret_cast<const bf16x8*>(kl + kof0);
    kf1.h = *reinterpret_cast<const bf16x8*>(kl + kof1);
    asm volatile("" ::"v"(kf0.i[0]), "v"(kf0.i[1]), "v"(kf0.i[2]),
                 "v"(kf0.i[3]), "v"(kf1.i[0]), "v"(kf1.i[1]), "v"(kf1.i[2]),
                 "v"(kf1.i[3]));
    asm volatile("s_waitcnt lgkmcnt(0)" ::: "memory");
    __builtin_amdgcn_sched_barrier(0);
    if (t + 1 < NT) {
      const u16* ks = kbase + (long)(kstart + (t + 1) * 32) * HD + lane * 8;
      u16* lk = (u16*)wbase;
      GLL16(ks, lk);
      GLL16(ks + 512, lk + 512);
    }

    __builtin_amdgcn_s_setprio(1);
    f32x4 s00 = __builtin_amdgcn_mfma_f32_16x16x32_bf16(kf0.h, qf0.h, z, 0, 0, 0);
    f32x4 s10 = __builtin_amdgcn_mfma_f32_16x16x32_bf16(kf1.h, qf0.h, z, 0, 0, 0);
    f32x4 s01 = __builtin_amdgcn_mfma_f32_16x16x32_bf16(kf0.h, qf1.h, z, 0, 0, 0);
    f32x4 s11 = __builtin_amdgcn_mfma_f32_16x16x32_bf16(kf1.h, qf1.h, z, 0, 0, 0);
    __builtin_amdgcn_s_setprio(0);

    float p00[4], p10[4], p01[4], p11[4];
#pragma unroll
    for (int r = 0; r < 4; ++r) {
      p00[r] = exp2f(s00[r]);
      p10[r] = exp2f(s10[r]);
      p01[r] = exp2f(s01[r]);
      p11[r] = exp2f(s11[r]);
      den0 += p00[r] + p10[r];
      den1 += p01[r] + p11[r];
    }
    fr pf0, pf1;
    pf0.i[0] = (int)cvt_pk(p00[0], p00[1]);
    pf0.i[1] = (int)cvt_pk(p00[2], p00[3]);
    pf0.i[2] = (int)cvt_pk(p10[0], p10[1]);
    pf0.i[3] = (int)cvt_pk(p10[2], p10[3]);
    pf1.i[0] = (int)cvt_pk(p01[0], p01[1]);
    pf1.i[1] = (int)cvt_pk(p01[2], p01[3]);
    pf1.i[2] = (int)cvt_pk(p11[0], p11[1]);
    pf1.i[3] = (int)cvt_pk(p11[2], p11[3]);

    if (t + 1 < NT)
      asm volatile("s_waitcnt vmcnt(2)" ::: "memory");
    else
      asm volatile("s_waitcnt vmcnt(0)" ::: "memory");
    __builtin_amdgcn_sched_barrier(0);
    uint2 va0 = *reinterpret_cast<const uint2*>(vl + va0o);
    uint2 vb0 = *reinterpret_cast<const uint2*>(vl + vb0o);
    uint2 va1 = *reinterpret_cast<const uint2*>(vl + va1o);
    uint2 vb1 = *reinterpret_cast<const uint2*>(vl + vb1o);
    asm volatile("" ::"v"(va0.x), "v"(va0.y), "v"(vb0.x), "v"(vb0.y),
                 "v"(va1.x), "v"(va1.y), "v"(vb1.x), "v"(vb1.y));
    asm volatile("s_waitcnt lgkmcnt(0)" ::: "memory");
    __builtin_amdgcn_sched_barrier(0);
    if (t + 1 < NT) {
      const u16* vs = vbase + (long)(kstart + (t + 1) * 32) * HD + lane * 8;
      u16* lk = (u16*)wbase;
      GLL16(vs, lk + 1024);
      GLL16(vs + 512, lk + 1536);
    }

    fr v0, v1;
    v0.i = (i32x4){(int)va0.x, (int)va0.y, (int)vb0.x, (int)vb0.y};
    v1.i = (i32x4){(int)va1.x, (int)va1.y, (int)vb1.x, (int)vb1.y};
    __builtin_amdgcn_s_setprio(1);
    acc00 = __builtin_amdgcn_mfma_f32_16x16x32_bf16(v0.h, pf0.h, acc00, 0, 0, 0);
    acc01 = __builtin_amdgcn_mfma_f32_16x16x32_bf16(v0.h, pf1.h, acc01, 0, 0, 0);
    acc10 = __builtin_amdgcn_mfma_f32_16x16x32_bf16(v1.h, pf0.h, acc10, 0, 0, 0);
    acc11 = __builtin_amdgcn_mfma_f32_16x16x32_bf16(v1.h, pf1.h, acc11, 0, 0, 0);
    __builtin_amdgcn_s_setprio(0);
  }

  den0 += __shfl_xor(den0, 16, 64);
  den0 += __shfl_xor(den0, 32, 64);
  den1 += __shfl_xor(den1, 16, 64);
  den1 += __shfl_xor(den1, 32, 64);

  __syncthreads();
  float(*accs)[32][33] = (float(*)[32][33])pool;
  float(*dsh)[32] = (float(*)[32])(pool + NSPLIT * 32 * 33 * 4);
#pragma unroll
  for (int r = 0; r < 4; ++r) {
    accs[w][g * 4 + r][li] = acc00[r];
    accs[w][g * 4 + r][16 + li] = acc01[r];
    accs[w][16 + g * 4 + r][li] = acc10[r];
    accs[w][16 + g * 4 + r][16 + li] = acc11[r];
  }
  if (g == 0) {
    dsh[w][li] = den0;
    dsh[w][16 + li] = den1;
  }
  __syncthreads();

  int q = tid >> 4, dp = tid & 15;
  float Den = 0.f, o0 = 0.f, o1 = 0.f;
#pragma unroll
  for (int ww = 0; ww < NSPLIT; ++ww) {
    Den += dsh[ww][q];
    o0 += accs[ww][2 * dp][q];
    o1 += accs[ww][2 * dp + 1][q];
  }
  float inv = 1.f / Den;
  int qrow = qt * 32 + q;
  if (qrow < Q_MAX) {
    unsigned pk = cvt_pk(o0 * inv, o1 * inv);
    *reinterpret_cast<unsigned*>(
        AO + ((long)(b * Q_MAX + qrow)) * D + h * HD + 2 * dp) = pk;
  }
}

// ---------------------------------------------------------------------------
// Merged head: input = q_stream[inv] if selected else enc row.
// ---------------------------------------------------------------------------
__global__ __launch_bounds__(256) void head_kernel(
    const float* __restrict__ enc, const float* __restrict__ q_stream,
    const int* __restrict__ inv, const float* __restrict__ hW,
    const float* __restrict__ hb, float* __restrict__ out) {
  int row = blockIdx.x * 4 + (threadIdx.x >> 6);
  int lane = threadIdx.x & 63;
  int slot = inv[row];
  const float* src =
      (slot >= 0) ? (q_stream + (long)slot * D) : (enc + (long)row * D);
  const float4 a = *reinterpret_cast<const float4*>(src + lane * 4);
  float c0 = 0.f, c1 = 0.f, c2 = 0.f;
  const float av[4] = {a.x, a.y, a.z, a.w};
#pragma unroll
  for (int i = 0; i < 4; ++i) {
    int k = lane * 4 + i;
    c0 += av[i] * hW[k * 3];
    c1 += av[i] * hW[k * 3 + 1];
    c2 += av[i] * hW[k * 3 + 2];
  }
#pragma unroll
  for (int off = 32; off; off >>= 1) {
    c0 += __shfl_down(c0, off, 64);
    c1 += __shfl_down(c1, off, 64);
    c2 += __shfl_down(c2, off, 64);
  }
  if (lane == 0) {
    out[(long)row * 3] = c0 + hb[0];
    out[(long)row * 3 + 1] = c1 + hb[1];
    out[(long)row * 3 + 2] = c2 + hb[2];
  }
}

// ---------------------------------------------------------------------------
extern "C" void kernel_launch(void* const* d_in, const int* in_sizes, int n_in,
                              void* d_out, int out_size, void* d_ws,
                              size_t ws_size, hipStream_t stream) {
  const float* enc = (const float*)d_in[0];
  const float* clog = (const float*)d_in[1];
  const float* ln_q_g = (const float*)d_in[2];
  const float* ln_q_b = (const float*)d_in[3];
  const float* ln_kv_g = (const float*)d_in[4];
  const float* ln_kv_b = (const float*)d_in[5];
  const float* Wq = (const float*)d_in[6];
  const float* bq = (const float*)d_in[7];
  const float* Wk = (const float*)d_in[8];
  const float* bk = (const float*)d_in[9];
  const float* Wv = (const float*)d_in[10];
  const float* bv = (const float*)d_in[11];
  const float* Wo = (const float*)d_in[12];
  const float* bo = (const float*)d_in[13];
  const float* ffn_g = (const float*)d_in[14];
  const float* ffn_b = (const float*)d_in[15];
  const float* W1 = (const float*)d_in[16];
  const float* b1 = (const float*)d_in[17];
  const float* W2 = (const float*)d_in[18];
  const float* b2 = (const float*)d_in[19];
  const float* head_W = (const float*)d_in[20];
  const float* head_b = (const float*)d_in[21];
  float* out = (float*)d_out;

  char* ws = (char*)d_ws;
  float* q_stream = (float*)ws;            ws += (long)QROWS * D * 4;
  u16* kvl0 = (u16*)ws;                    ws += (long)KVROWS * D * 2;
  u16* kvl1 = (u16*)ws;                    ws += (long)KVROWS * D * 2;
  u16* Khbuf = (u16*)ws;                   ws += (long)B * H * L * HD * 2;
  u16* Vhbuf = (u16*)ws;                   ws += (long)B * H * L * HD * 2;
  u16* q_ln = (u16*)ws;                    ws += (long)QROWS * D * 2;
  u16* Qbuf = (u16*)ws;                    ws += (long)QROWS * D * 2;
  u16* AObuf = (u16*)ws;                   ws += (long)QROWS * D * 2;
  u16* H1buf = (u16*)ws;                   ws += (long)QROWS * FF * 2;
  u16* WT = (u16*)ws;                      ws += (long)NL * (4 * D * D + 2 * D * FF) * 2;
  int* idxbuf = (int*)ws;                  ws += QROWS * 4;
  int* maskbuf = (int*)ws;                 ws += QROWS * 4;
  int* invbuf = (int*)ws;                  ws += (long)B * L * 4;

  const long DD = (long)D * D, DFF = (long)D * FF;
  const long LSTR = 4 * DD + 2 * DFF;

  setup_kernel<<<LNBLK + TRBLK + B, 256, 0, stream>>>(
      enc, clog, ln_kv_g, ln_kv_b, Wq, Wk, Wv, Wo, W1, W2, WT, kvl0, kvl1,
      idxbuf, maskbuf, invbuf);
  gather_ln<<<QROWS / 4, 256, 0, stream>>>(enc, idxbuf, q_stream, q_ln,
                                           ln_q_g, ln_q_b);

  for (int l = 0; l < NL; ++l) {
    u16* base = WT + l * LSTR;
    u16* kv_ln = (l == 0) ? kvl0 : kvl1;

    if (l > 0)
      ln_bf16<<<QROWS / 4, 256, 0, stream>>>(q_stream, q_ln, ln_q_g + l * D,
                                             ln_q_b + l * D);

    gemm_proj<<<KVBLK + QBLK, 256, 0, stream>>>(
        kv_ln, q_ln, base, bk + l * D, bv + l * D, bq + l * D, Khbuf, Vhbuf,
        Qbuf);

    attn_mfma<<<B * H * NQT, 512, 0, stream>>>(Qbuf, Khbuf, Vhbuf, AObuf);

    // O-proj: 32-row tiles, grid (4,65)=260 blocks (full-GPU occupancy)
    gemm_mfma32<<<dim3(D / 64, MRB32), 128, 0, stream>>>(
        AObuf, base + 3 * DD, bo + l * D, q_stream, q_stream, maskbuf, QROWS,
        D, D);

    ln_bf16<<<QROWS / 4, 256, 0, stream>>>(q_stream, q_ln, ffn_g + l * D,
                                           ffn_b + l * D);
    // FFN1: DMA-staged template, 16x33 = 528 blocks
    gemm_ffn1<<<16 * MRB64, 256, 0, stream>>>(q_ln, base + 4 * DD,
                                              b1 + l * FF, H1buf);
    // FFN2: 32-row tiles, grid (4,65)=260 blocks
    gemm_mfma32<<<dim3(D / 64, MRB32), 128, 0, stream>>>(
        H1buf, base + 4 * DD + DFF, b2 + l * D, q_stream, q_stream, maskbuf,
        QROWS, D, FF);
  }

  head_kernel<<<KVROWS / 4, 256, 0, stream>>>(enc, q_stream, invbuf, head_W,
                                              head_b, out);
}